// Round 2
// baseline (3045.572 us; speedup 1.0000x reference)
//
#include <hip/hip_runtime.h>
#include <hip/hip_bf16.h>

#define NB   65536
#define KD   10
#define NG   20
#define NH   200     // KD*NG
#define NH1  400
#define NIN  784

#define REPAIR_CAP (1 << 20)
#define TAU 1e-2     // margin (in t-units) below which we recompute exactly in f64

__device__ inline float bf2f(unsigned short u) {
  union { unsigned int i; float f; } x; x.i = ((unsigned int)u) << 16; return x.f;
}

// ---------------------------------------------------------------------------
// Fast fp32 GEMM: C[m][n] = act( sum_k A[m][k]*W[n][k] + bias[n] )
// BM=BN=128, BK=16, 256 threads, 8x8 micro-tile. ACT: 0=none 1=relu 2=tanh.
// ABF16: A operand is bf16 (stage 5), else fp32.
// ---------------------------------------------------------------------------
template<int ACT, int ABF16>
__global__ __launch_bounds__(256) void gemm_f32(
    const void* __restrict__ Av, const float* __restrict__ W,
    const float* __restrict__ bias, float* __restrict__ C,
    int M, int N, int K)
{
  __shared__ float As[16][132];
  __shared__ float Bs[16][132];
  const int tid = threadIdx.x;
  const int tx = tid & 15, ty = tid >> 4;
  const int m0 = blockIdx.x * 128;
  const int n0 = blockIdx.y * 128;
  const int lrow = tid >> 1;          // 0..127
  const int lk = (tid & 1) * 8;       // 0 or 8

  float acc[8][8];
  #pragma unroll
  for (int i = 0; i < 8; ++i)
    #pragma unroll
    for (int j = 0; j < 8; ++j) acc[i][j] = 0.f;

  for (int k0 = 0; k0 < K; k0 += 16) {
    // stage A (128 x 16)
    if (ABF16) {
      const unsigned short* A = (const unsigned short*)Av;
      uint4 v = *reinterpret_cast<const uint4*>(A + (size_t)(m0 + lrow) * K + k0 + lk);
      As[lk + 0][lrow] = bf2f((unsigned short)(v.x & 0xffff));
      As[lk + 1][lrow] = bf2f((unsigned short)(v.x >> 16));
      As[lk + 2][lrow] = bf2f((unsigned short)(v.y & 0xffff));
      As[lk + 3][lrow] = bf2f((unsigned short)(v.y >> 16));
      As[lk + 4][lrow] = bf2f((unsigned short)(v.z & 0xffff));
      As[lk + 5][lrow] = bf2f((unsigned short)(v.z >> 16));
      As[lk + 6][lrow] = bf2f((unsigned short)(v.w & 0xffff));
      As[lk + 7][lrow] = bf2f((unsigned short)(v.w >> 16));
    } else {
      const float* A = (const float*)Av;
      float4 v0 = *reinterpret_cast<const float4*>(A + (size_t)(m0 + lrow) * K + k0 + lk);
      float4 v1 = *reinterpret_cast<const float4*>(A + (size_t)(m0 + lrow) * K + k0 + lk + 4);
      As[lk + 0][lrow] = v0.x; As[lk + 1][lrow] = v0.y;
      As[lk + 2][lrow] = v0.z; As[lk + 3][lrow] = v0.w;
      As[lk + 4][lrow] = v1.x; As[lk + 5][lrow] = v1.y;
      As[lk + 6][lrow] = v1.z; As[lk + 7][lrow] = v1.w;
    }
    // stage B (128 x 16), guard rows >= N
    float4 w0 = make_float4(0.f, 0.f, 0.f, 0.f), w1 = w0;
    if (n0 + lrow < N) {
      w0 = *reinterpret_cast<const float4*>(W + (size_t)(n0 + lrow) * K + k0 + lk);
      w1 = *reinterpret_cast<const float4*>(W + (size_t)(n0 + lrow) * K + k0 + lk + 4);
    }
    Bs[lk + 0][lrow] = w0.x; Bs[lk + 1][lrow] = w0.y;
    Bs[lk + 2][lrow] = w0.z; Bs[lk + 3][lrow] = w0.w;
    Bs[lk + 4][lrow] = w1.x; Bs[lk + 5][lrow] = w1.y;
    Bs[lk + 6][lrow] = w1.z; Bs[lk + 7][lrow] = w1.w;
    __syncthreads();
    #pragma unroll
    for (int kk = 0; kk < 16; ++kk) {
      float4 a0 = *reinterpret_cast<const float4*>(&As[kk][ty * 8]);
      float4 a1 = *reinterpret_cast<const float4*>(&As[kk][ty * 8 + 4]);
      float4 b0 = *reinterpret_cast<const float4*>(&Bs[kk][tx * 8]);
      float4 b1 = *reinterpret_cast<const float4*>(&Bs[kk][tx * 8 + 4]);
      float a[8] = {a0.x, a0.y, a0.z, a0.w, a1.x, a1.y, a1.z, a1.w};
      float b[8] = {b0.x, b0.y, b0.z, b0.w, b1.x, b1.y, b1.z, b1.w};
      #pragma unroll
      for (int i = 0; i < 8; ++i)
        #pragma unroll
        for (int j = 0; j < 8; ++j)
          acc[i][j] = fmaf(a[i], b[j], acc[i][j]);
    }
    __syncthreads();
  }

  #pragma unroll
  for (int i = 0; i < 8; ++i) {
    const int m = m0 + ty * 8 + i;
    #pragma unroll
    for (int j = 0; j < 8; ++j) {
      const int n = n0 + tx * 8 + j;
      if (n < N) {
        float r = acc[i][j] + bias[n];
        if (ACT == 1) r = fmaxf(r, 0.f);
        if (ACT == 2) r = tanhf(r);
        C[(size_t)m * N + n] = r;
      }
    }
  }
}

// ---------------------------------------------------------------------------
// Quantization with margin test. t_j = 0.5|c_j|^2 - v.c_j (same argmin as
// |v-c_j|^2). Distances in f64 from the fast fp32 z_e; groups whose
// best/second margin < TAU are flagged for exact recomputation.
// ---------------------------------------------------------------------------
__global__ __launch_bounds__(256) void quant_kernel(
    const float* __restrict__ z_e, const float* __restrict__ cb,
    float* __restrict__ emb, unsigned char* __restrict__ idx_out,
    int* __restrict__ counter, int* __restrict__ list)
{
  __shared__ double cs[KD][KD];
  __shared__ double chalf[KD];
  const int tid = threadIdx.x;
  if (tid < KD * KD) cs[tid / KD][tid % KD] = (double)cb[tid];
  __syncthreads();
  if (tid < KD) {
    double s = 0.0;
    #pragma unroll
    for (int k = 0; k < KD; ++k) s += cs[tid][k] * cs[tid][k];
    chalf[tid] = 0.5 * s;
  }
  __syncthreads();

  const int gi = blockIdx.x * 256 + tid;
  const int b = gi / NG;
  const int g = gi % NG;
  const float* zp = z_e + (size_t)b * NH + g;
  double v[KD];
  #pragma unroll
  for (int k = 0; k < KD; ++k) v[k] = (double)zp[k * NG];

  int best = 0; double bt = 1e300, bt2 = 1e300;
  #pragma unroll
  for (int j = 0; j < KD; ++j) {
    double t = chalf[j];
    #pragma unroll
    for (int k = 0; k < KD; ++k) t -= v[k] * cs[j][k];
    if (t < bt) { bt2 = bt; bt = t; best = j; }
    else if (t < bt2) { bt2 = t; }
  }
  float* ep = emb + (size_t)b * NH + g;
  #pragma unroll
  for (int k = 0; k < KD; ++k) ep[k * NG] = (float)cs[best][k];
  idx_out[gi] = (unsigned char)best;

  if (bt2 - bt < TAU) {
    int pos = atomicAdd(counter, 1);
    if (pos < REPAIR_CAP) list[pos] = gi;
  }
}

// ---------------------------------------------------------------------------
// Exact f64 recompute for flagged groups: x -> h1 -> z_e[:,g] -> argmin.
// One block (256 threads) per flagged group.
// ---------------------------------------------------------------------------
__global__ __launch_bounds__(256) void repair_kernel(
    const float* __restrict__ x, const float* __restrict__ W1,
    const float* __restrict__ b1, const float* __restrict__ W2,
    const float* __restrict__ b2, const float* __restrict__ cb,
    const int* __restrict__ list, const int* __restrict__ counter,
    float* __restrict__ emb, unsigned char* __restrict__ idx_out)
{
  __shared__ double h1s[NH1];
  __shared__ double parts[256];
  __shared__ double zk[KD];
  const int tid = threadIdx.x;
  int n = *counter; if (n > REPAIR_CAP) n = REPAIR_CAP;

  for (int it = blockIdx.x; it < n; it += gridDim.x) {
    const int gi = list[it];
    const int b = gi / NG;
    const int g = gi % NG;
    const float* xr = x + (size_t)b * NIN;
    // h1 in f64
    for (int j = tid; j < NH1; j += 256) {
      const float* wr = W1 + (size_t)j * NIN;
      double a0 = 0.0, a1 = 0.0;
      for (int k = 0; k < NIN; k += 2) {
        a0 += (double)xr[k] * (double)wr[k];
        a1 += (double)xr[k + 1] * (double)wr[k + 1];
      }
      double h = a0 + a1 + (double)b1[j];
      h1s[j] = h > 0.0 ? h : 0.0;
    }
    __syncthreads();
    // z components for this group in f64
    if (tid < 250) {
      const int k = tid / 25, jj = tid % 25;
      const float* wr = W2 + (size_t)(k * NG + g) * NH1;
      double s = 0.0;
      for (int j = jj; j < NH1; j += 25) s += h1s[j] * (double)wr[j];
      parts[tid] = s;
    }
    __syncthreads();
    if (tid < KD) {
      double s = 0.0;
      for (int q = 0; q < 25; ++q) s += parts[tid * 25 + q];
      zk[tid] = s + (double)b2[tid * NG + g];
    }
    __syncthreads();
    if (tid == 0) {
      int best = 0; double bt = 1e300;
      for (int j = 0; j < KD; ++j) {
        double t = 0.0;
        for (int k = 0; k < KD; ++k) {
          double c = (double)cb[j * KD + k];
          t += 0.5 * c * c - zk[k] * c;
        }
        if (t < bt) { bt = t; best = j; }
      }
      idx_out[gi] = (unsigned char)best;
      for (int k = 0; k < KD; ++k)
        emb[(size_t)b * NH + k * NG + g] = cb[best * KD + k];
    }
    __syncthreads();
  }
}

// P[g][c][j] = sum_k cb[c][k] * W3[j][k*NG + g]
__global__ __launch_bounds__(256) void build_table(
    const float* __restrict__ cb, const float* __restrict__ W3,
    float* __restrict__ P)
{
  const int i = blockIdx.x * 256 + threadIdx.x;
  if (i >= NG * KD * NH1) return;
  const int j = i % NH1;
  const int c = (i / NH1) % KD;
  const int g = i / (NH1 * KD);
  float s = 0.f;
  #pragma unroll
  for (int k = 0; k < KD; ++k)
    s = fmaf(cb[c * KD + k], W3[(size_t)j * NH + k * NG + g], s);
  P[i] = s;
}

// h3[b][j] = relu(b3[j] + sum_g P[g][idx[b,g]][j])  -> bf16
__global__ __launch_bounds__(256) void compute_h3(
    const unsigned char* __restrict__ idx, const float* __restrict__ P,
    const float* __restrict__ b3, __hip_bfloat16* __restrict__ h3)
{
  __shared__ unsigned char sidx[64][NG];
  const int tid = threadIdx.x;
  const int b0 = blockIdx.x * 64;
  for (int t = tid; t < 64 * NG; t += 256)
    sidx[t / NG][t % NG] = idx[(size_t)b0 * NG + t];
  __syncthreads();
  for (int s = 0; s < 64; ++s) {
    for (int j = tid; j < NH1; j += 256) {
      float acc = b3[j];
      #pragma unroll
      for (int g = 0; g < NG; ++g) {
        const int c = sidx[s][g];
        acc += P[(g * KD + c) * NH1 + j];
      }
      h3[(size_t)(b0 + s) * NH1 + j] = __float2bfloat16(fmaxf(acc, 0.f));
    }
  }
}

__global__ void zero_counter(int* c) { *c = 0; }

extern "C" void kernel_launch(void* const* d_in, const int* in_sizes, int n_in,
                              void* d_out, int out_size, void* d_ws, size_t ws_size,
                              hipStream_t stream) {
  const float* x  = (const float*)d_in[0];
  const float* W1 = (const float*)d_in[1];
  const float* b1 = (const float*)d_in[2];
  const float* W2 = (const float*)d_in[3];
  const float* b2 = (const float*)d_in[4];
  const float* W3 = (const float*)d_in[5];
  const float* b3 = (const float*)d_in[6];
  const float* W4 = (const float*)d_in[7];
  const float* b4 = (const float*)d_in[8];
  const float* cb = (const float*)d_in[9];

  float* out   = (float*)d_out;
  float* recon = out;                              // NB x 784
  float* z_e   = out + (size_t)NB * NIN;           // NB x 200
  float* emb   = z_e + (size_t)NB * NH;            // NB x 200

  char* ws = (char*)d_ws;
  int*            counter = (int*)ws;                         // 4 B
  float*          P   = (float*)(ws + (1u << 20));            // 320 KB
  unsigned char*  idx = (unsigned char*)(ws + (2u << 20));    // 1.31 MB
  int*            list = (int*)(ws + (4u << 20));             // 4 MB
  __hip_bfloat16* h3  = (__hip_bfloat16*)(ws + (9u << 20));   // 52.4 MB
  float* h1 = recon;   // reuse recon region (205 MB) as h1 scratch; rewritten last

  dim3 blk(256);
  zero_counter<<<1, 1, 0, stream>>>(counter);
  // stage 1: h1 = relu(x @ W1^T + b1)   M=65536 N=400 K=784
  gemm_f32<1, 0><<<dim3(NB / 128, 4), blk, 0, stream>>>(x, W1, b1, h1, NB, NH1, NIN);
  // stage 2: z_e = h1 @ W2^T + b2       M=65536 N=200 K=400
  gemm_f32<0, 0><<<dim3(NB / 128, 2), blk, 0, stream>>>(h1, W2, b2, z_e, NB, NH, NH1);
  // stage 3a: codeword x W3 table
  build_table<<<(NG * KD * NH1 + 255) / 256, blk, 0, stream>>>(cb, W3, P);
  // stage 3b: quantize with margin flagging
  quant_kernel<<<(NB * NG) / 256, blk, 0, stream>>>(z_e, cb, emb, idx, counter, list);
  // stage 3c: exact f64 repair of borderline groups
  repair_kernel<<<2048, blk, 0, stream>>>(x, W1, b1, W2, b2, cb, list, counter, emb, idx);
  // stage 4: h3 = relu(b3 + sum_g P[g][idx]) -> bf16
  compute_h3<<<NB / 64, blk, 0, stream>>>(idx, P, b3, h3);
  // stage 5: recon = tanh(h3 @ W4^T + b4)  M=65536 N=784 K=400
  gemm_f32<2, 1><<<dim3(NB / 128, 7), blk, 0, stream>>>(h3, W4, b4, recon, NB, NIN, NH1);
}

// Round 3
// 1742.691 us; speedup vs baseline: 1.7476x; 1.7476x over previous
//
#include <hip/hip_runtime.h>
#include <hip/hip_bf16.h>

#define NB   65536
#define KD   10
#define NG   20
#define NH   200     // KD*NG
#define NH1  400
#define NIN  784

#define REPAIR_CAP (1 << 18)
#define TAU 1e-3     // margin below which we recompute exactly in f64 (~200 sigma of fp32-path margin error)

using short8 = __attribute__((ext_vector_type(8))) short;
using f32x4  = __attribute__((ext_vector_type(4))) float;

__device__ inline float bf2f(unsigned short u) {
  union { unsigned int i; float f; } x; x.i = ((unsigned int)u) << 16; return x.f;
}

__device__ inline void gload_lds16(const void* g, void* l) {
  __builtin_amdgcn_global_load_lds(
      (const __attribute__((address_space(1))) unsigned int*)g,
      (__attribute__((address_space(3))) unsigned int*)l, 16, 0, 0);
}

// ---------------------------------------------------------------------------
// fp32 GEMM (argmin feeder path): C = act(A @ W^T + bias). BM=BN=128, BK=16.
// ---------------------------------------------------------------------------
template<int ACT>
__global__ __launch_bounds__(256) void gemm_f32(
    const float* __restrict__ A, const float* __restrict__ W,
    const float* __restrict__ bias, float* __restrict__ C,
    int M, int N, int K)
{
  __shared__ float As[16][132];
  __shared__ float Bs[16][132];
  const int tid = threadIdx.x;
  const int tx = tid & 15, ty = tid >> 4;
  const int m0 = blockIdx.x * 128;
  const int n0 = blockIdx.y * 128;
  const int lrow = tid >> 1;
  const int lk = (tid & 1) * 8;

  float acc[8][8];
  #pragma unroll
  for (int i = 0; i < 8; ++i)
    #pragma unroll
    for (int j = 0; j < 8; ++j) acc[i][j] = 0.f;

  for (int k0 = 0; k0 < K; k0 += 16) {
    float4 v0 = *reinterpret_cast<const float4*>(A + (size_t)(m0 + lrow) * K + k0 + lk);
    float4 v1 = *reinterpret_cast<const float4*>(A + (size_t)(m0 + lrow) * K + k0 + lk + 4);
    As[lk + 0][lrow] = v0.x; As[lk + 1][lrow] = v0.y;
    As[lk + 2][lrow] = v0.z; As[lk + 3][lrow] = v0.w;
    As[lk + 4][lrow] = v1.x; As[lk + 5][lrow] = v1.y;
    As[lk + 6][lrow] = v1.z; As[lk + 7][lrow] = v1.w;
    float4 w0 = make_float4(0.f, 0.f, 0.f, 0.f), w1 = w0;
    if (n0 + lrow < N) {
      w0 = *reinterpret_cast<const float4*>(W + (size_t)(n0 + lrow) * K + k0 + lk);
      w1 = *reinterpret_cast<const float4*>(W + (size_t)(n0 + lrow) * K + k0 + lk + 4);
    }
    Bs[lk + 0][lrow] = w0.x; Bs[lk + 1][lrow] = w0.y;
    Bs[lk + 2][lrow] = w0.z; Bs[lk + 3][lrow] = w0.w;
    Bs[lk + 4][lrow] = w1.x; Bs[lk + 5][lrow] = w1.y;
    Bs[lk + 6][lrow] = w1.z; Bs[lk + 7][lrow] = w1.w;
    __syncthreads();
    #pragma unroll
    for (int kk = 0; kk < 16; ++kk) {
      float4 a0 = *reinterpret_cast<const float4*>(&As[kk][ty * 8]);
      float4 a1 = *reinterpret_cast<const float4*>(&As[kk][ty * 8 + 4]);
      float4 b0 = *reinterpret_cast<const float4*>(&Bs[kk][tx * 8]);
      float4 b1 = *reinterpret_cast<const float4*>(&Bs[kk][tx * 8 + 4]);
      float a[8] = {a0.x, a0.y, a0.z, a0.w, a1.x, a1.y, a1.z, a1.w};
      float b[8] = {b0.x, b0.y, b0.z, b0.w, b1.x, b1.y, b1.z, b1.w};
      #pragma unroll
      for (int i = 0; i < 8; ++i)
        #pragma unroll
        for (int j = 0; j < 8; ++j)
          acc[i][j] = fmaf(a[i], b[j], acc[i][j]);
    }
    __syncthreads();
  }
  #pragma unroll
  for (int i = 0; i < 8; ++i) {
    const int m = m0 + ty * 8 + i;
    #pragma unroll
    for (int j = 0; j < 8; ++j) {
      const int n = n0 + tx * 8 + j;
      if (n < N) {
        float r = acc[i][j] + bias[n];
        if (ACT == 1) r = fmaxf(r, 0.f);
        C[(size_t)m * N + n] = r;
      }
    }
  }
}

// ---------------------------------------------------------------------------
// Stage 5: recon = tanh(h3(bf16) @ W4p^T + b4). MFMA 16x16x32, m97 structure.
// W4p pre-padded to 896x416 (zeros beyond 784/400) -> no bounds checks.
// ---------------------------------------------------------------------------
__global__ __launch_bounds__(256) void gemm5_mfma(
    const __hip_bfloat16* __restrict__ A,   // h3: NB x 400 (row-major)
    const __hip_bfloat16* __restrict__ Bp,  // W4p: 896 x 416 (row-major)
    const float* __restrict__ bias, float* __restrict__ C)
{
  __shared__ __align__(16) short As[128][32];
  __shared__ __align__(16) short Bs[128][32];
  const int tid = threadIdx.x;
  const int lane = tid & 63, wid = tid >> 6;
  const int wr = wid >> 1, wc = wid & 1;
  const int m0 = blockIdx.x * 128, n0 = blockIdx.y * 128;
  const int srow = lane >> 2;           // 0..15
  const int skp  = (lane & 3) * 8;      // 0,8,16,24
  const short* Ag = (const short*)A;
  const short* Bg = (const short*)Bp;
  f32x4 acc[4][4];
  #pragma unroll
  for (int i = 0; i < 4; ++i)
    #pragma unroll
    for (int j = 0; j < 4; ++j) acc[i][j] = (f32x4){0.f, 0.f, 0.f, 0.f};

  for (int k0 = 0; k0 < 416; k0 += 32) {
    #pragma unroll
    for (int c = 0; c < 2; ++c) {
      const int row = c * 64 + wid * 16 + srow;
      // A: K-stride 400; tail k>=400 reads spill into next row, but multiply
      // W4p zeros, so the products vanish.
      gload_lds16(Ag + (size_t)(m0 + row) * 400 + k0 + skp,
                  (char*)&As[0][0] + c * 4096 + wid * 1024);
      gload_lds16(Bg + (size_t)(n0 + row) * 416 + k0 + skp,
                  (char*)&Bs[0][0] + c * 4096 + wid * 1024);
    }
    __syncthreads();
    short8 af[4], bf[4];
    #pragma unroll
    for (int i = 0; i < 4; ++i)
      af[i] = *reinterpret_cast<const short8*>(&As[wr * 64 + i * 16 + (lane & 15)][(lane >> 4) * 8]);
    #pragma unroll
    for (int j = 0; j < 4; ++j)
      bf[j] = *reinterpret_cast<const short8*>(&Bs[wc * 64 + j * 16 + (lane & 15)][(lane >> 4) * 8]);
    #pragma unroll
    for (int i = 0; i < 4; ++i)
      #pragma unroll
      for (int j = 0; j < 4; ++j)
        acc[i][j] = __builtin_amdgcn_mfma_f32_16x16x32_bf16(af[i], bf[j], acc[i][j], 0, 0, 0);
    __syncthreads();
  }

  #pragma unroll
  for (int j = 0; j < 4; ++j) {
    const int n = n0 + wc * 64 + j * 16 + (lane & 15);
    if (n >= NIN) continue;
    const float bn = bias[n];
    #pragma unroll
    for (int i = 0; i < 4; ++i) {
      const int mb = m0 + wr * 64 + i * 16 + (lane >> 4) * 4;
      #pragma unroll
      for (int r = 0; r < 4; ++r)
        C[(size_t)(mb + r) * NIN + n] = tanhf(acc[i][j][r] + bn);
    }
  }
}

__global__ __launch_bounds__(256) void pad_w4(
    const float* __restrict__ W4, __hip_bfloat16* __restrict__ W4p)
{
  const int i = blockIdx.x * 256 + threadIdx.x;
  if (i >= 896 * 416) return;
  const int n = i / 416, k = i % 416;
  const float v = (n < NIN && k < NH1) ? W4[(size_t)n * NH1 + k] : 0.f;
  W4p[i] = __float2bfloat16(v);
}

// ---------------------------------------------------------------------------
// Quantization: distances in f64 from fast fp32 z_e; margin < TAU -> flag.
// ---------------------------------------------------------------------------
__global__ __launch_bounds__(256) void quant_kernel(
    const float* __restrict__ z_e, const float* __restrict__ cb,
    float* __restrict__ emb, unsigned char* __restrict__ idx_out,
    int* __restrict__ counter, int* __restrict__ list)
{
  __shared__ double cs[KD][KD];
  __shared__ double chalf[KD];
  const int tid = threadIdx.x;
  if (tid < KD * KD) cs[tid / KD][tid % KD] = (double)cb[tid];
  __syncthreads();
  if (tid < KD) {
    double s = 0.0;
    #pragma unroll
    for (int k = 0; k < KD; ++k) s += cs[tid][k] * cs[tid][k];
    chalf[tid] = 0.5 * s;
  }
  __syncthreads();

  const int gi = blockIdx.x * 256 + tid;
  const int b = gi / NG;
  const int g = gi % NG;
  const float* zp = z_e + (size_t)b * NH + g;
  double v[KD];
  #pragma unroll
  for (int k = 0; k < KD; ++k) v[k] = (double)zp[k * NG];

  int best = 0; double bt = 1e300, bt2 = 1e300;
  #pragma unroll
  for (int j = 0; j < KD; ++j) {
    double t = chalf[j];
    #pragma unroll
    for (int k = 0; k < KD; ++k) t -= v[k] * cs[j][k];
    if (t < bt) { bt2 = bt; bt = t; best = j; }
    else if (t < bt2) { bt2 = t; }
  }
  float* ep = emb + (size_t)b * NH + g;
  #pragma unroll
  for (int k = 0; k < KD; ++k) ep[k * NG] = (float)cs[best][k];
  idx_out[gi] = (unsigned char)best;

  if (bt2 - bt < TAU) {
    int pos = atomicAdd(counter, 1);
    if (pos < REPAIR_CAP) list[pos] = gi;
  }
}

// ---------------------------------------------------------------------------
// Exact f64 repair, coalesced: wave-per-j dots with shuffle reduce.
// ---------------------------------------------------------------------------
__global__ __launch_bounds__(256) void repair_kernel(
    const float* __restrict__ x, const float* __restrict__ W1,
    const float* __restrict__ b1, const float* __restrict__ W2,
    const float* __restrict__ b2, const float* __restrict__ cb,
    const int* __restrict__ list, const int* __restrict__ counter,
    float* __restrict__ emb, unsigned char* __restrict__ idx_out)
{
  __shared__ double xs[NIN];
  __shared__ double h1s[NH1];
  __shared__ double zk[KD];
  const int tid = threadIdx.x;
  const int lane = tid & 63, wid = tid >> 6;
  int n = *counter; if (n > REPAIR_CAP) n = REPAIR_CAP;

  for (int it = blockIdx.x; it < n; it += gridDim.x) {
    const int gi = list[it];
    const int b = gi / NG, g = gi % NG;
    for (int k = tid; k < NIN; k += 256) xs[k] = (double)x[(size_t)b * NIN + k];
    __syncthreads();
    for (int j = wid; j < NH1; j += 4) {
      const float* wr = W1 + (size_t)j * NIN;
      double s = 0.0;
      for (int k = lane; k < NIN; k += 64) s = fma(xs[k], (double)wr[k], s);
      #pragma unroll
      for (int off = 32; off > 0; off >>= 1) s += __shfl_down(s, off);
      if (lane == 0) { double h = s + (double)b1[j]; h1s[j] = h > 0.0 ? h : 0.0; }
    }
    __syncthreads();
    for (int kk = wid; kk < KD; kk += 4) {
      const float* wr = W2 + (size_t)(kk * NG + g) * NH1;
      double s = 0.0;
      for (int j = lane; j < NH1; j += 64) s = fma(h1s[j], (double)wr[j], s);
      #pragma unroll
      for (int off = 32; off > 0; off >>= 1) s += __shfl_down(s, off);
      if (lane == 0) zk[kk] = s + (double)b2[kk * NG + g];
    }
    __syncthreads();
    if (tid == 0) {
      int best = 0; double bt = 1e300;
      for (int j = 0; j < KD; ++j) {
        double t = 0.0;
        for (int k = 0; k < KD; ++k) {
          double c = (double)cb[j * KD + k];
          t += 0.5 * c * c - zk[k] * c;
        }
        if (t < bt) { bt = t; best = j; }
      }
      idx_out[gi] = (unsigned char)best;
      for (int k = 0; k < KD; ++k)
        emb[(size_t)b * NH + k * NG + g] = cb[best * KD + k];
    }
    __syncthreads();
  }
}

// P[g][c][j] = sum_k cb[c][k] * W3[j][k*NG + g]
__global__ __launch_bounds__(256) void build_table(
    const float* __restrict__ cb, const float* __restrict__ W3,
    float* __restrict__ P)
{
  const int i = blockIdx.x * 256 + threadIdx.x;
  if (i >= NG * KD * NH1) return;
  const int j = i % NH1;
  const int c = (i / NH1) % KD;
  const int g = i / (NH1 * KD);
  float s = 0.f;
  #pragma unroll
  for (int k = 0; k < KD; ++k)
    s = fmaf(cb[c * KD + k], W3[(size_t)j * NH + k * NG + g], s);
  P[i] = s;
}

// h3[b][j] = relu(b3[j] + sum_g P[g][idx[b,g]][j])  -> bf16
__global__ __launch_bounds__(256) void compute_h3(
    const unsigned char* __restrict__ idx, const float* __restrict__ P,
    const float* __restrict__ b3, __hip_bfloat16* __restrict__ h3)
{
  __shared__ unsigned char sidx[64][NG];
  const int tid = threadIdx.x;
  const int b0 = blockIdx.x * 64;
  for (int t = tid; t < 64 * NG; t += 256)
    sidx[t / NG][t % NG] = idx[(size_t)b0 * NG + t];
  __syncthreads();
  for (int s = 0; s < 64; ++s) {
    for (int j = tid; j < NH1; j += 256) {
      float acc = b3[j];
      #pragma unroll
      for (int g = 0; g < NG; ++g) {
        const int c = sidx[s][g];
        acc += P[(g * KD + c) * NH1 + j];
      }
      h3[(size_t)(b0 + s) * NH1 + j] = __float2bfloat16(fmaxf(acc, 0.f));
    }
  }
}

__global__ void zero_counter(int* c) { *c = 0; }

extern "C" void kernel_launch(void* const* d_in, const int* in_sizes, int n_in,
                              void* d_out, int out_size, void* d_ws, size_t ws_size,
                              hipStream_t stream) {
  const float* x  = (const float*)d_in[0];
  const float* W1 = (const float*)d_in[1];
  const float* b1 = (const float*)d_in[2];
  const float* W2 = (const float*)d_in[3];
  const float* b2 = (const float*)d_in[4];
  const float* W3 = (const float*)d_in[5];
  const float* b3 = (const float*)d_in[6];
  const float* W4 = (const float*)d_in[7];
  const float* b4 = (const float*)d_in[8];
  const float* cb = (const float*)d_in[9];

  float* out   = (float*)d_out;
  float* recon = out;                              // NB x 784
  float* z_e   = out + (size_t)NB * NIN;           // NB x 200
  float* emb   = z_e + (size_t)NB * NH;            // NB x 200

  char* ws = (char*)d_ws;
  int*            counter = (int*)ws;
  float*          P    = (float*)(ws + (1u << 20));
  unsigned char*  idx  = (unsigned char*)(ws + (2u << 20));
  int*            list = (int*)(ws + (4u << 20));             // 1 MB cap
  __hip_bfloat16* W4p  = (__hip_bfloat16*)(ws + (6u << 20));  // 896x416 bf16
  __hip_bfloat16* h3   = (__hip_bfloat16*)(ws + (8u << 20));  // 52.4 MB
  float* h1 = recon;   // reuse recon region as h1 scratch; rewritten last

  dim3 blk(256);
  zero_counter<<<1, 1, 0, stream>>>(counter);
  pad_w4<<<(896 * 416 + 255) / 256, blk, 0, stream>>>(W4, W4p);
  // stage 1: h1 = relu(x @ W1^T + b1)
  gemm_f32<1><<<dim3(NB / 128, 4), blk, 0, stream>>>(x, W1, b1, h1, NB, NH1, NIN);
  // stage 2: z_e = h1 @ W2^T + b2
  gemm_f32<0><<<dim3(NB / 128, 2), blk, 0, stream>>>(h1, W2, b2, z_e, NB, NH, NH1);
  // stage 3a/3b/3c
  build_table<<<(NG * KD * NH1 + 255) / 256, blk, 0, stream>>>(cb, W3, P);
  quant_kernel<<<(NB * NG) / 256, blk, 0, stream>>>(z_e, cb, emb, idx, counter, list);
  repair_kernel<<<2048, blk, 0, stream>>>(x, W1, b1, W2, b2, cb, list, counter, emb, idx);
  // stage 4
  compute_h3<<<NB / 64, blk, 0, stream>>>(idx, P, b3, h3);
  // stage 5: recon = tanh(h3 @ W4p^T + b4), MFMA
  gemm5_mfma<<<dim3(NB / 128, 7), blk, 0, stream>>>(h3, W4p, b4, recon);
}

// Round 4
// 1337.165 us; speedup vs baseline: 2.2776x; 1.3033x over previous
//
#include <hip/hip_runtime.h>
#include <hip/hip_bf16.h>

#define NB   65536
#define KD   10
#define NG   20
#define NH   200     // KD*NG
#define NH1  400
#define NIN  784

#define REPAIR_CAP (1 << 18)
#define TAU 1e-3     // margin below which we recompute exactly in f64

using short8 = __attribute__((ext_vector_type(8))) short;
using f32x4  = __attribute__((ext_vector_type(4))) float;

__device__ inline float bf2f(unsigned short u) {
  union { unsigned int i; float f; } x; x.i = ((unsigned int)u) << 16; return x.f;
}
__device__ inline unsigned short f2bf(float v) {
  __hip_bfloat16 b = __float2bfloat16(v);
  return *reinterpret_cast<unsigned short*>(&b);
}
__device__ inline void gload_lds16(const void* g, void* l) {
  __builtin_amdgcn_global_load_lds(
      (const __attribute__((address_space(1))) unsigned int*)g,
      (__attribute__((address_space(3))) unsigned int*)l, 16, 0, 0);
}

// ---------------------------------------------------------------------------
// Split-bf16 MFMA GEMM: C = A @ B^T (+bias, act), A = Ahi+Alo, B = Bhi+Blo.
// 3 MFMAs per fragment pair: hi*hi + lo*hi + hi*lo (error ~2^-16 relative).
// BM=BN=128, BK=32, 4 waves (one stages each LDS tile). A K-tail lanes
// (k >= KA) redirect their GLOBAL address to a zero page (LDS stays linear).
// MODE 1: Ohi/Olo = split(relu(acc+bias))  [h1, stride NH1]
// MODE 2: Of = acc + bias                  [z_e, stride NH]
// ---------------------------------------------------------------------------
template<int KSTEPS, int LDA, int KA, int LDB, int MODE>
__global__ __launch_bounds__(256) void gemm_split(
    const unsigned short* __restrict__ Ahi, const unsigned short* __restrict__ Alo,
    const unsigned short* __restrict__ Bhi, const unsigned short* __restrict__ Blo,
    const unsigned short* __restrict__ zp, const float* __restrict__ bias,
    unsigned short* __restrict__ Ohi, unsigned short* __restrict__ Olo,
    float* __restrict__ Of)
{
  __shared__ __align__(16) short As_hi[128][32];
  __shared__ __align__(16) short As_lo[128][32];
  __shared__ __align__(16) short Bs_hi[128][32];
  __shared__ __align__(16) short Bs_lo[128][32];
  const int tid = threadIdx.x;
  const int lane = tid & 63, wid = tid >> 6;
  const int wr = wid >> 1, wc = wid & 1;
  const int m0 = blockIdx.x * 128, n0 = blockIdx.y * 128;

  const unsigned short* G = (wid == 0) ? Ahi : (wid == 1) ? Alo
                          : (wid == 2) ? Bhi : Blo;
  short* Lt = (wid == 0) ? &As_hi[0][0] : (wid == 1) ? &As_lo[0][0]
            : (wid == 2) ? &Bs_hi[0][0] : &Bs_lo[0][0];
  const bool isA = wid < 2;
  const int rbase = isA ? m0 : n0;
  const int ld = isA ? LDA : LDB;
  const int rr = lane >> 2;             // 0..15
  const int kofs = (lane & 3) * 8;      // 0,8,16,24

  f32x4 acc[4][4];
  #pragma unroll
  for (int i = 0; i < 4; ++i)
    #pragma unroll
    for (int j = 0; j < 4; ++j) acc[i][j] = (f32x4){0.f, 0.f, 0.f, 0.f};

  for (int ks = 0; ks < KSTEPS; ++ks) {
    const int k0 = ks * 32;
    #pragma unroll
    for (int c = 0; c < 8; ++c) {
      const unsigned short* src =
          G + (size_t)(rbase + c * 16 + rr) * ld + k0 + kofs;
      if (isA && (k0 + kofs >= KA)) src = zp;   // per-lane global redirect
      gload_lds16(src, (char*)Lt + c * 1024);
    }
    __syncthreads();
    short8 ah[4], al[4], bh[4], bl[4];
    #pragma unroll
    for (int i = 0; i < 4; ++i) {
      ah[i] = *reinterpret_cast<const short8*>(&As_hi[wr * 64 + i * 16 + (lane & 15)][(lane >> 4) * 8]);
      al[i] = *reinterpret_cast<const short8*>(&As_lo[wr * 64 + i * 16 + (lane & 15)][(lane >> 4) * 8]);
      bh[i] = *reinterpret_cast<const short8*>(&Bs_hi[wc * 64 + i * 16 + (lane & 15)][(lane >> 4) * 8]);
      bl[i] = *reinterpret_cast<const short8*>(&Bs_lo[wc * 64 + i * 16 + (lane & 15)][(lane >> 4) * 8]);
    }
    #pragma unroll
    for (int i = 0; i < 4; ++i)
      #pragma unroll
      for (int j = 0; j < 4; ++j) {
        acc[i][j] = __builtin_amdgcn_mfma_f32_16x16x32_bf16(ah[i], bh[j], acc[i][j], 0, 0, 0);
        acc[i][j] = __builtin_amdgcn_mfma_f32_16x16x32_bf16(al[i], bh[j], acc[i][j], 0, 0, 0);
        acc[i][j] = __builtin_amdgcn_mfma_f32_16x16x32_bf16(ah[i], bl[j], acc[i][j], 0, 0, 0);
      }
    __syncthreads();
  }

  #pragma unroll
  for (int j = 0; j < 4; ++j) {
    const int n = n0 + wc * 64 + j * 16 + (lane & 15);
    if (MODE == 1) {
      if (n >= NH1) continue;
      const float bn = bias[n];
      #pragma unroll
      for (int i = 0; i < 4; ++i) {
        const int mb = m0 + wr * 64 + i * 16 + (lane >> 4) * 4;
        #pragma unroll
        for (int r = 0; r < 4; ++r) {
          float v = fmaxf(acc[i][j][r] + bn, 0.f);
          unsigned short h = f2bf(v);
          Ohi[(size_t)(mb + r) * NH1 + n] = h;
          Olo[(size_t)(mb + r) * NH1 + n] = f2bf(v - bf2f(h));
        }
      }
    } else {
      if (n >= NH) continue;
      const float bn = bias[n];
      #pragma unroll
      for (int i = 0; i < 4; ++i) {
        const int mb = m0 + wr * 64 + i * 16 + (lane >> 4) * 4;
        #pragma unroll
        for (int r = 0; r < 4; ++r)
          Of[(size_t)(mb + r) * NH + n] = acc[i][j][r] + bn;
      }
    }
  }
}

// ---------------------------------------------------------------------------
// Stage 5: recon = tanh(h3(bf16) @ W4p^T + b4). MFMA, validated round 3.
// ---------------------------------------------------------------------------
__global__ __launch_bounds__(256) void gemm5_mfma(
    const __hip_bfloat16* __restrict__ A,   // h3: NB x 400
    const __hip_bfloat16* __restrict__ Bp,  // W4p: 896 x 416
    const float* __restrict__ bias, float* __restrict__ C)
{
  __shared__ __align__(16) short As[128][32];
  __shared__ __align__(16) short Bs[128][32];
  const int tid = threadIdx.x;
  const int lane = tid & 63, wid = tid >> 6;
  const int wr = wid >> 1, wc = wid & 1;
  const int m0 = blockIdx.x * 128, n0 = blockIdx.y * 128;
  const int srow = lane >> 2;
  const int skp  = (lane & 3) * 8;
  const short* Ag = (const short*)A;
  const short* Bg = (const short*)Bp;
  f32x4 acc[4][4];
  #pragma unroll
  for (int i = 0; i < 4; ++i)
    #pragma unroll
    for (int j = 0; j < 4; ++j) acc[i][j] = (f32x4){0.f, 0.f, 0.f, 0.f};

  for (int k0 = 0; k0 < 416; k0 += 32) {
    #pragma unroll
    for (int c = 0; c < 2; ++c) {
      const int row = c * 64 + wid * 16 + srow;
      gload_lds16(Ag + (size_t)(m0 + row) * 400 + k0 + skp,
                  (char*)&As[0][0] + c * 4096 + wid * 1024);
      gload_lds16(Bg + (size_t)(n0 + row) * 416 + k0 + skp,
                  (char*)&Bs[0][0] + c * 4096 + wid * 1024);
    }
    __syncthreads();
    short8 af[4], bf[4];
    #pragma unroll
    for (int i = 0; i < 4; ++i)
      af[i] = *reinterpret_cast<const short8*>(&As[wr * 64 + i * 16 + (lane & 15)][(lane >> 4) * 8]);
    #pragma unroll
    for (int j = 0; j < 4; ++j)
      bf[j] = *reinterpret_cast<const short8*>(&Bs[wc * 64 + j * 16 + (lane & 15)][(lane >> 4) * 8]);
    #pragma unroll
    for (int i = 0; i < 4; ++i)
      #pragma unroll
      for (int j = 0; j < 4; ++j)
        acc[i][j] = __builtin_amdgcn_mfma_f32_16x16x32_bf16(af[i], bf[j], acc[i][j], 0, 0, 0);
    __syncthreads();
  }

  #pragma unroll
  for (int j = 0; j < 4; ++j) {
    const int n = n0 + wc * 64 + j * 16 + (lane & 15);
    if (n >= NIN) continue;
    const float bn = bias[n];
    #pragma unroll
    for (int i = 0; i < 4; ++i) {
      const int mb = m0 + wr * 64 + i * 16 + (lane >> 4) * 4;
      #pragma unroll
      for (int r = 0; r < 4; ++r)
        C[(size_t)(mb + r) * NIN + n] = tanhf(acc[i][j][r] + bn);
    }
  }
}

// -------------------------- converters / padders ---------------------------
__global__ __launch_bounds__(256) void conv_x(
    const float* __restrict__ x, unsigned short* __restrict__ xh,
    unsigned short* __restrict__ xl)
{
  const size_t i = (size_t)blockIdx.x * 256 + threadIdx.x;   // 4 floats each
  float4 v = reinterpret_cast<const float4*>(x)[i];
  ushort4 h, l;
  h.x = f2bf(v.x); l.x = f2bf(v.x - bf2f(h.x));
  h.y = f2bf(v.y); l.y = f2bf(v.y - bf2f(h.y));
  h.z = f2bf(v.z); l.z = f2bf(v.z - bf2f(h.z));
  h.w = f2bf(v.w); l.w = f2bf(v.w - bf2f(h.w));
  reinterpret_cast<ushort4*>(xh)[i] = h;
  reinterpret_cast<ushort4*>(xl)[i] = l;
}

__global__ __launch_bounds__(256) void conv_w(
    const float* __restrict__ W, unsigned short* __restrict__ Wh,
    unsigned short* __restrict__ Wl, int NP, int KP, int N, int K)
{
  const int i = blockIdx.x * 256 + threadIdx.x;
  if (i >= NP * KP) return;
  const int n = i / KP, k = i % KP;
  const float v = (n < N && k < K) ? W[(size_t)n * K + k] : 0.f;
  const unsigned short h = f2bf(v);
  Wh[i] = h;
  Wl[i] = f2bf(v - bf2f(h));
}

__global__ __launch_bounds__(256) void pad_w4(
    const float* __restrict__ W4, __hip_bfloat16* __restrict__ W4p)
{
  const int i = blockIdx.x * 256 + threadIdx.x;
  if (i >= 896 * 416) return;
  const int n = i / 416, k = i % 416;
  const float v = (n < NIN && k < NH1) ? W4[(size_t)n * NH1 + k] : 0.f;
  W4p[i] = __float2bfloat16(v);
}

// ---------------------------------------------------------------------------
// Quantization: f64 distances from fast z_e; margin < TAU -> flag for repair.
// ---------------------------------------------------------------------------
__global__ __launch_bounds__(256) void quant_kernel(
    const float* __restrict__ z_e, const float* __restrict__ cb,
    float* __restrict__ emb, unsigned char* __restrict__ idx_out,
    int* __restrict__ counter, int* __restrict__ list)
{
  __shared__ double cs[KD][KD];
  __shared__ double chalf[KD];
  const int tid = threadIdx.x;
  if (tid < KD * KD) cs[tid / KD][tid % KD] = (double)cb[tid];
  __syncthreads();
  if (tid < KD) {
    double s = 0.0;
    #pragma unroll
    for (int k = 0; k < KD; ++k) s += cs[tid][k] * cs[tid][k];
    chalf[tid] = 0.5 * s;
  }
  __syncthreads();

  const int gi = blockIdx.x * 256 + tid;
  const int b = gi / NG;
  const int g = gi % NG;
  const float* zp = z_e + (size_t)b * NH + g;
  double v[KD];
  #pragma unroll
  for (int k = 0; k < KD; ++k) v[k] = (double)zp[k * NG];

  int best = 0; double bt = 1e300, bt2 = 1e300;
  #pragma unroll
  for (int j = 0; j < KD; ++j) {
    double t = chalf[j];
    #pragma unroll
    for (int k = 0; k < KD; ++k) t -= v[k] * cs[j][k];
    if (t < bt) { bt2 = bt; bt = t; best = j; }
    else if (t < bt2) { bt2 = t; }
  }
  float* ep = emb + (size_t)b * NH + g;
  #pragma unroll
  for (int k = 0; k < KD; ++k) ep[k * NG] = (float)cs[best][k];
  idx_out[gi] = (unsigned char)best;

  if (bt2 - bt < TAU) {
    int pos = atomicAdd(counter, 1);
    if (pos < REPAIR_CAP) list[pos] = gi;
  }
}

// ---------------------------------------------------------------------------
// Exact f64 repair (coalesced wave-per-j dots), validated round 3.
// ---------------------------------------------------------------------------
__global__ __launch_bounds__(256) void repair_kernel(
    const float* __restrict__ x, const float* __restrict__ W1,
    const float* __restrict__ b1, const float* __restrict__ W2,
    const float* __restrict__ b2, const float* __restrict__ cb,
    const int* __restrict__ list, const int* __restrict__ counter,
    float* __restrict__ emb, unsigned char* __restrict__ idx_out)
{
  __shared__ double xs[NIN];
  __shared__ double h1s[NH1];
  __shared__ double zk[KD];
  const int tid = threadIdx.x;
  const int lane = tid & 63, wid = tid >> 6;
  int n = *counter; if (n > REPAIR_CAP) n = REPAIR_CAP;

  for (int it = blockIdx.x; it < n; it += gridDim.x) {
    const int gi = list[it];
    const int b = gi / NG, g = gi % NG;
    for (int k = tid; k < NIN; k += 256) xs[k] = (double)x[(size_t)b * NIN + k];
    __syncthreads();
    for (int j = wid; j < NH1; j += 4) {
      const float* wr = W1 + (size_t)j * NIN;
      double s = 0.0;
      for (int k = lane; k < NIN; k += 64) s = fma(xs[k], (double)wr[k], s);
      #pragma unroll
      for (int off = 32; off > 0; off >>= 1) s += __shfl_down(s, off);
      if (lane == 0) { double h = s + (double)b1[j]; h1s[j] = h > 0.0 ? h : 0.0; }
    }
    __syncthreads();
    for (int kk = wid; kk < KD; kk += 4) {
      const float* wr = W2 + (size_t)(kk * NG + g) * NH1;
      double s = 0.0;
      for (int j = lane; j < NH1; j += 64) s = fma(h1s[j], (double)wr[j], s);
      #pragma unroll
      for (int off = 32; off > 0; off >>= 1) s += __shfl_down(s, off);
      if (lane == 0) zk[kk] = s + (double)b2[kk * NG + g];
    }
    __syncthreads();
    if (tid == 0) {
      int best = 0; double bt = 1e300;
      for (int j = 0; j < KD; ++j) {
        double t = 0.0;
        for (int k = 0; k < KD; ++k) {
          double c = (double)cb[j * KD + k];
          t += 0.5 * c * c - zk[k] * c;
        }
        if (t < bt) { bt = t; best = j; }
      }
      idx_out[gi] = (unsigned char)best;
      for (int k = 0; k < KD; ++k)
        emb[(size_t)b * NH + k * NG + g] = cb[best * KD + k];
    }
    __syncthreads();
  }
}

// P[g][c][j] = sum_k cb[c][k] * W3[j][k*NG + g]
__global__ __launch_bounds__(256) void build_table(
    const float* __restrict__ cb, const float* __restrict__ W3,
    float* __restrict__ P)
{
  const int i = blockIdx.x * 256 + threadIdx.x;
  if (i >= NG * KD * NH1) return;
  const int j = i % NH1;
  const int c = (i / NH1) % KD;
  const int g = i / (NH1 * KD);
  float s = 0.f;
  #pragma unroll
  for (int k = 0; k < KD; ++k)
    s = fmaf(cb[c * KD + k], W3[(size_t)j * NH + k * NG + g], s);
  P[i] = s;
}

// h3[b][j] = relu(b3[j] + sum_g P[g][idx[b,g]][j]) -> bf16
__global__ __launch_bounds__(256) void compute_h3(
    const unsigned char* __restrict__ idx, const float* __restrict__ P,
    const float* __restrict__ b3, __hip_bfloat16* __restrict__ h3)
{
  __shared__ unsigned char sidx[64][NG];
  const int tid = threadIdx.x;
  const int b0 = blockIdx.x * 64;
  for (int t = tid; t < 64 * NG; t += 256)
    sidx[t / NG][t % NG] = idx[(size_t)b0 * NG + t];
  __syncthreads();
  for (int s = 0; s < 64; ++s) {
    for (int j = tid; j < NH1; j += 256) {
      float acc = b3[j];
      #pragma unroll
      for (int g = 0; g < NG; ++g) {
        const int c = sidx[s][g];
        acc += P[(g * KD + c) * NH1 + j];
      }
      h3[(size_t)(b0 + s) * NH1 + j] = __float2bfloat16(fmaxf(acc, 0.f));
    }
  }
}

__global__ void init_misc(int* counter, unsigned short* zp) {
  if (threadIdx.x == 0) *counter = 0;
  if (threadIdx.x < 128) zp[threadIdx.x] = 0;
}

extern "C" void kernel_launch(void* const* d_in, const int* in_sizes, int n_in,
                              void* d_out, int out_size, void* d_ws, size_t ws_size,
                              hipStream_t stream) {
  const float* x  = (const float*)d_in[0];
  const float* W1 = (const float*)d_in[1];
  const float* b1 = (const float*)d_in[2];
  const float* W2 = (const float*)d_in[3];
  const float* b2 = (const float*)d_in[4];
  const float* W3 = (const float*)d_in[5];
  const float* b3 = (const float*)d_in[6];
  const float* W4 = (const float*)d_in[7];
  const float* b4 = (const float*)d_in[8];
  const float* cb = (const float*)d_in[9];

  float* out   = (float*)d_out;
  float* recon = out;                              // NB x 784 (written last)
  float* z_e   = out + (size_t)NB * NIN;           // NB x 200
  float* emb   = z_e + (size_t)NB * NH;            // NB x 200

  // x_hi/x_lo exactly fill the recon region (NB*NIN*4 bytes); dead before GEMM5.
  unsigned short* x_hi = (unsigned short*)recon;
  unsigned short* x_lo = x_hi + (size_t)NB * NIN;
  // h1_lo exactly fills the emb region; dead before quant writes emb.
  unsigned short* h1_lo = (unsigned short*)emb;

  char* ws = (char*)d_ws;
  int*            counter = (int*)ws;                           // 4 B
  unsigned short* zp   = (unsigned short*)(ws + 256);           // 256 B zeros
  float*          P    = (float*)(ws + (1u << 20));             // 320 KB
  unsigned char*  idx  = (unsigned char*)(ws + (2u << 20));     // 1.31 MB
  int*            list = (int*)(ws + (4u << 20));               // 1 MB
  __hip_bfloat16* W4p  = (__hip_bfloat16*)(ws + (6u << 20));    // 745 KB
  unsigned short* W1ph = (unsigned short*)(ws + (7u << 20));    // 512x800
  unsigned short* W1pl = (unsigned short*)(ws + (8u << 20));
  unsigned short* W2ph = (unsigned short*)(ws + (9u << 20));    // 256x416
  unsigned short* W2pl = (unsigned short*)(ws + (10u << 20));
  unsigned short* h1_hi = (unsigned short*)(ws + (16u << 20));  // NB x 400 bf16
  __hip_bfloat16* h3    = (__hip_bfloat16*)(ws + (16u << 20));  // overlaps h1_hi (dead)

  dim3 blk(256);
  init_misc<<<1, 128, 0, stream>>>(counter, zp);
  conv_x<<<(NB * NIN / 4) / 256, blk, 0, stream>>>(x, x_hi, x_lo);
  conv_w<<<(512 * 800 + 255) / 256, blk, 0, stream>>>(W1, W1ph, W1pl, 512, 800, NH1, NIN);
  conv_w<<<(256 * 416 + 255) / 256, blk, 0, stream>>>(W2, W2ph, W2pl, 256, 416, NH, NH1);
  pad_w4<<<(896 * 416 + 255) / 256, blk, 0, stream>>>(W4, W4p);

  // stage 1: h1 = relu(x @ W1^T + b1) -> split bf16   M=65536 N=400(512) K=784(800)
  gemm_split<25, 784, 784, 800, 1><<<dim3(NB / 128, 4), blk, 0, stream>>>(
      x_hi, x_lo, W1ph, W1pl, zp, b1, h1_hi, h1_lo, nullptr);
  // stage 2: z_e = h1 @ W2^T + b2                     M=65536 N=200(256) K=400(416)
  gemm_split<13, 400, 400, 416, 2><<<dim3(NB / 128, 2), blk, 0, stream>>>(
      h1_hi, h1_lo, W2ph, W2pl, zp, b2, nullptr, nullptr, z_e);

  build_table<<<(NG * KD * NH1 + 255) / 256, blk, 0, stream>>>(cb, W3, P);
  quant_kernel<<<(NB * NG) / 256, blk, 0, stream>>>(z_e, cb, emb, idx, counter, list);
  repair_kernel<<<2048, blk, 0, stream>>>(x, W1, b1, W2, b2, cb, list, counter, emb, idx);
  compute_h3<<<NB / 64, blk, 0, stream>>>(idx, P, b3, h3);
  gemm5_mfma<<<dim3(NB / 128, 7), blk, 0, stream>>>(h3, W4p, b4, recon);
}

// Round 5
// 1235.442 us; speedup vs baseline: 2.4652x; 1.0823x over previous
//
#include <hip/hip_runtime.h>
#include <hip/hip_bf16.h>

#define NB   65536
#define KD   10
#define NG   20
#define NH   200     // KD*NG
#define NH1  400
#define NIN  784

#define TAU 3e-4     // margin below which the sample is recomputed exactly in f64

using short8 = __attribute__((ext_vector_type(8))) short;
using f32x4  = __attribute__((ext_vector_type(4))) float;

__device__ inline float bf2f(unsigned short u) {
  union { unsigned int i; float f; } x; x.i = ((unsigned int)u) << 16; return x.f;
}
__device__ inline unsigned short f2bf(float v) {
  __hip_bfloat16 b = __float2bfloat16(v);
  return *reinterpret_cast<unsigned short*>(&b);
}
__device__ inline void gload_lds16(const void* g, void* l) {
  __builtin_amdgcn_global_load_lds(
      (const __attribute__((address_space(1))) unsigned int*)g,
      (__attribute__((address_space(3))) unsigned int*)l, 16, 0, 0);
}

// ---------------------------------------------------------------------------
// Split-bf16 MFMA GEMM (validated R4): C = A @ B^T, A = Ahi+Alo, B = Bhi+Blo,
// 3 MFMAs per fragment pair. Grid: blockIdx.x = n-tile (few), y = m-tile, so
// same-m blocks are dispatch-adjacent -> A-tile re-reads hit L2.
// ---------------------------------------------------------------------------
template<int KSTEPS, int LDA, int KA, int LDB, int MODE>
__global__ __launch_bounds__(256) void gemm_split(
    const unsigned short* __restrict__ Ahi, const unsigned short* __restrict__ Alo,
    const unsigned short* __restrict__ Bhi, const unsigned short* __restrict__ Blo,
    const unsigned short* __restrict__ zp, const float* __restrict__ bias,
    unsigned short* __restrict__ Ohi, unsigned short* __restrict__ Olo,
    float* __restrict__ Of)
{
  __shared__ __align__(16) short As_hi[128][32];
  __shared__ __align__(16) short As_lo[128][32];
  __shared__ __align__(16) short Bs_hi[128][32];
  __shared__ __align__(16) short Bs_lo[128][32];
  const int tid = threadIdx.x;
  const int lane = tid & 63, wid = tid >> 6;
  const int wr = wid >> 1, wc = wid & 1;
  const int m0 = blockIdx.y * 128, n0 = blockIdx.x * 128;

  const unsigned short* G = (wid == 0) ? Ahi : (wid == 1) ? Alo
                          : (wid == 2) ? Bhi : Blo;
  short* Lt = (wid == 0) ? &As_hi[0][0] : (wid == 1) ? &As_lo[0][0]
            : (wid == 2) ? &Bs_hi[0][0] : &Bs_lo[0][0];
  const bool isA = wid < 2;
  const int rbase = isA ? m0 : n0;
  const int ld = isA ? LDA : LDB;
  const int rr = lane >> 2;
  const int kofs = (lane & 3) * 8;

  f32x4 acc[4][4];
  #pragma unroll
  for (int i = 0; i < 4; ++i)
    #pragma unroll
    for (int j = 0; j < 4; ++j) acc[i][j] = (f32x4){0.f, 0.f, 0.f, 0.f};

  for (int ks = 0; ks < KSTEPS; ++ks) {
    const int k0 = ks * 32;
    #pragma unroll
    for (int c = 0; c < 8; ++c) {
      const unsigned short* src =
          G + (size_t)(rbase + c * 16 + rr) * ld + k0 + kofs;
      if (isA && (k0 + kofs >= KA)) src = zp;
      gload_lds16(src, (char*)Lt + c * 1024);
    }
    __syncthreads();
    short8 ah[4], al[4], bh[4], bl[4];
    #pragma unroll
    for (int i = 0; i < 4; ++i) {
      ah[i] = *reinterpret_cast<const short8*>(&As_hi[wr * 64 + i * 16 + (lane & 15)][(lane >> 4) * 8]);
      al[i] = *reinterpret_cast<const short8*>(&As_lo[wr * 64 + i * 16 + (lane & 15)][(lane >> 4) * 8]);
      bh[i] = *reinterpret_cast<const short8*>(&Bs_hi[wc * 64 + i * 16 + (lane & 15)][(lane >> 4) * 8]);
      bl[i] = *reinterpret_cast<const short8*>(&Bs_lo[wc * 64 + i * 16 + (lane & 15)][(lane >> 4) * 8]);
    }
    #pragma unroll
    for (int i = 0; i < 4; ++i)
      #pragma unroll
      for (int j = 0; j < 4; ++j) {
        acc[i][j] = __builtin_amdgcn_mfma_f32_16x16x32_bf16(ah[i], bh[j], acc[i][j], 0, 0, 0);
        acc[i][j] = __builtin_amdgcn_mfma_f32_16x16x32_bf16(al[i], bh[j], acc[i][j], 0, 0, 0);
        acc[i][j] = __builtin_amdgcn_mfma_f32_16x16x32_bf16(ah[i], bl[j], acc[i][j], 0, 0, 0);
      }
    __syncthreads();
  }

  #pragma unroll
  for (int j = 0; j < 4; ++j) {
    const int n = n0 + wc * 64 + j * 16 + (lane & 15);
    if (MODE == 1) {
      if (n >= NH1) continue;
      const float bn = bias[n];
      #pragma unroll
      for (int i = 0; i < 4; ++i) {
        const int mb = m0 + wr * 64 + i * 16 + (lane >> 4) * 4;
        #pragma unroll
        for (int r = 0; r < 4; ++r) {
          float v = fmaxf(acc[i][j][r] + bn, 0.f);
          unsigned short h = f2bf(v);
          Ohi[(size_t)(mb + r) * NH1 + n] = h;
          Olo[(size_t)(mb + r) * NH1 + n] = f2bf(v - bf2f(h));
        }
      }
    } else {
      if (n >= NH) continue;
      const float bn = bias[n];
      #pragma unroll
      for (int i = 0; i < 4; ++i) {
        const int mb = m0 + wr * 64 + i * 16 + (lane >> 4) * 4;
        #pragma unroll
        for (int r = 0; r < 4; ++r)
          Of[(size_t)(mb + r) * NH + n] = acc[i][j][r] + bn;
      }
    }
  }
}

// ---------------------------------------------------------------------------
// Stage 5: recon = tanh(h3(bf16) @ W4p^T + b4). MFMA (validated R3/R4).
// ---------------------------------------------------------------------------
__global__ __launch_bounds__(256) void gemm5_mfma(
    const __hip_bfloat16* __restrict__ A,   // h3: NB x 400
    const __hip_bfloat16* __restrict__ Bp,  // W4p: 896 x 416
    const float* __restrict__ bias, float* __restrict__ C)
{
  __shared__ __align__(16) short As[128][32];
  __shared__ __align__(16) short Bs[128][32];
  const int tid = threadIdx.x;
  const int lane = tid & 63, wid = tid >> 6;
  const int wr = wid >> 1, wc = wid & 1;
  const int m0 = blockIdx.y * 128, n0 = blockIdx.x * 128;
  const int srow = lane >> 2;
  const int skp  = (lane & 3) * 8;
  const short* Ag = (const short*)A;
  const short* Bg = (const short*)Bp;
  f32x4 acc[4][4];
  #pragma unroll
  for (int i = 0; i < 4; ++i)
    #pragma unroll
    for (int j = 0; j < 4; ++j) acc[i][j] = (f32x4){0.f, 0.f, 0.f, 0.f};

  for (int k0 = 0; k0 < 416; k0 += 32) {
    #pragma unroll
    for (int c = 0; c < 2; ++c) {
      const int row = c * 64 + wid * 16 + srow;
      gload_lds16(Ag + (size_t)(m0 + row) * 400 + k0 + skp,
                  (char*)&As[0][0] + c * 4096 + wid * 1024);
      gload_lds16(Bg + (size_t)(n0 + row) * 416 + k0 + skp,
                  (char*)&Bs[0][0] + c * 4096 + wid * 1024);
    }
    __syncthreads();
    short8 af[4], bf[4];
    #pragma unroll
    for (int i = 0; i < 4; ++i)
      af[i] = *reinterpret_cast<const short8*>(&As[wr * 64 + i * 16 + (lane & 15)][(lane >> 4) * 8]);
    #pragma unroll
    for (int j = 0; j < 4; ++j)
      bf[j] = *reinterpret_cast<const short8*>(&Bs[wc * 64 + j * 16 + (lane & 15)][(lane >> 4) * 8]);
    #pragma unroll
    for (int i = 0; i < 4; ++i)
      #pragma unroll
      for (int j = 0; j < 4; ++j)
        acc[i][j] = __builtin_amdgcn_mfma_f32_16x16x32_bf16(af[i], bf[j], acc[i][j], 0, 0, 0);
    __syncthreads();
  }

  #pragma unroll
  for (int j = 0; j < 4; ++j) {
    const int n = n0 + wc * 64 + j * 16 + (lane & 15);
    if (n >= NIN) continue;
    const float bn = bias[n];
    #pragma unroll
    for (int i = 0; i < 4; ++i) {
      const int mb = m0 + wr * 64 + i * 16 + (lane >> 4) * 4;
      #pragma unroll
      for (int r = 0; r < 4; ++r)
        C[(size_t)(mb + r) * NIN + n] = tanhf(acc[i][j][r] + bn);
    }
  }
}

// -------------------------- converters / padders ---------------------------
__global__ __launch_bounds__(256) void conv_x(
    const float* __restrict__ x, unsigned short* __restrict__ xh,
    unsigned short* __restrict__ xl)
{
  const size_t i = (size_t)blockIdx.x * 256 + threadIdx.x;
  float4 v = reinterpret_cast<const float4*>(x)[i];
  ushort4 h, l;
  h.x = f2bf(v.x); l.x = f2bf(v.x - bf2f(h.x));
  h.y = f2bf(v.y); l.y = f2bf(v.y - bf2f(h.y));
  h.z = f2bf(v.z); l.z = f2bf(v.z - bf2f(h.z));
  h.w = f2bf(v.w); l.w = f2bf(v.w - bf2f(h.w));
  reinterpret_cast<ushort4*>(xh)[i] = h;
  reinterpret_cast<ushort4*>(xl)[i] = l;
}

__global__ __launch_bounds__(256) void conv_w(
    const float* __restrict__ W, unsigned short* __restrict__ Wh,
    unsigned short* __restrict__ Wl, int NP, int KP, int N, int K)
{
  const int i = blockIdx.x * 256 + threadIdx.x;
  if (i >= NP * KP) return;
  const int n = i / KP, k = i % KP;
  const float v = (n < N && k < K) ? W[(size_t)n * K + k] : 0.f;
  const unsigned short h = f2bf(v);
  Wh[i] = h;
  Wl[i] = f2bf(v - bf2f(h));
}

__global__ __launch_bounds__(256) void pad_w4(
    const float* __restrict__ W4, __hip_bfloat16* __restrict__ W4p)
{
  const int i = blockIdx.x * 256 + threadIdx.x;
  if (i >= 896 * 416) return;
  const int n = i / 416, k = i % 416;
  const float v = (n < NIN && k < NH1) ? W4[(size_t)n * NH1 + k] : 0.f;
  W4p[i] = __float2bfloat16(v);
}

// ---------------------------------------------------------------------------
// Quantization: f64 distances from fast z_e; margin < TAU -> flag the SAMPLE.
// ---------------------------------------------------------------------------
__global__ __launch_bounds__(256) void quant_kernel(
    const float* __restrict__ z_e, const float* __restrict__ cb,
    float* __restrict__ emb, unsigned char* __restrict__ idx_out,
    unsigned char* __restrict__ sflag)
{
  __shared__ double cs[KD][KD];
  __shared__ double chalf[KD];
  const int tid = threadIdx.x;
  if (tid < KD * KD) cs[tid / KD][tid % KD] = (double)cb[tid];
  __syncthreads();
  if (tid < KD) {
    double s = 0.0;
    #pragma unroll
    for (int k = 0; k < KD; ++k) s += cs[tid][k] * cs[tid][k];
    chalf[tid] = 0.5 * s;
  }
  __syncthreads();

  const int gi = blockIdx.x * 256 + tid;
  const int b = gi / NG;
  const int g = gi % NG;
  const float* zrow = z_e + (size_t)b * NH + g;
  double v[KD];
  #pragma unroll
  for (int k = 0; k < KD; ++k) v[k] = (double)zrow[k * NG];

  int best = 0; double bt = 1e300, bt2 = 1e300;
  #pragma unroll
  for (int j = 0; j < KD; ++j) {
    double t = chalf[j];
    #pragma unroll
    for (int k = 0; k < KD; ++k) t -= v[k] * cs[j][k];
    if (t < bt) { bt2 = bt; bt = t; best = j; }
    else if (t < bt2) { bt2 = t; }
  }
  float* ep = emb + (size_t)b * NH + g;
  #pragma unroll
  for (int k = 0; k < KD; ++k) ep[k * NG] = (float)cs[best][k];
  idx_out[gi] = (unsigned char)best;

  if (bt2 - bt < TAU) sflag[b] = 1;
}

__global__ __launch_bounds__(256) void compact_kernel(
    const unsigned char* __restrict__ sflag, int* __restrict__ scount,
    int* __restrict__ slist)
{
  const int i = blockIdx.x * 256 + threadIdx.x;
  if (i < NB && sflag[i]) slist[atomicAdd(scount, 1)] = i;
}

// ---------------------------------------------------------------------------
// Exact f64 repair over compacted flagged samples, 8 samples per block-chunk.
// W1 is read once per chunk (16-lane broadcast rows) instead of once per group.
// Recomputes h1 (f64), full z (f64), and all 20 argmins of each sample.
// ---------------------------------------------------------------------------
__global__ __launch_bounds__(256) void repair_kernel(
    const float* __restrict__ x, const float* __restrict__ W1,
    const float* __restrict__ b1, const float* __restrict__ W2,
    const float* __restrict__ b2, const float* __restrict__ cb,
    const int* __restrict__ slist, const int* __restrict__ scount,
    float* __restrict__ emb, unsigned char* __restrict__ idx_out)
{
  __shared__ float  xs[8][788];
  __shared__ double h1s[8][400];
  __shared__ double zs[8][200];
  __shared__ double cs[KD][KD];
  __shared__ double chalf[KD];
  __shared__ int sl[8];
  const int tid = threadIdx.x;
  if (tid < KD * KD) cs[tid / KD][tid % KD] = (double)cb[tid];
  __syncthreads();
  if (tid < KD) {
    double s = 0.0;
    #pragma unroll
    for (int k = 0; k < KD; ++k) s += cs[tid][k] * cs[tid][k];
    chalf[tid] = 0.5 * s;
  }

  int S = *scount; if (S > NB) S = NB;

  for (int base = blockIdx.x * 8; base < S; base += gridDim.x * 8) {
    const int cnt = min(8, S - base);
    __syncthreads();
    if (tid < cnt) sl[tid] = slist[base + tid];
    __syncthreads();
    for (int t = tid; t < cnt * NIN; t += 256) {
      const int ss = t / NIN, k = t % NIN;
      xs[ss][k] = x[(size_t)sl[ss] * NIN + k];
    }
    __syncthreads();
    // h1 in f64: s8 = tid&7, jg = tid>>3 (0..31); j = jg + 32*it
    {
      const int s8 = tid & 7, jg = tid >> 3;
      if (s8 < cnt) {
        const float4* xr = reinterpret_cast<const float4*>(&xs[s8][0]);
        for (int it = 0; it < 13; ++it) {
          const int j = jg + 32 * it;
          if (j >= NH1) break;
          const float4* wr = reinterpret_cast<const float4*>(W1 + (size_t)j * NIN);
          double p0 = 0, p1 = 0, p2 = 0, p3 = 0;
          for (int k4 = 0; k4 < NIN / 4; ++k4) {
            float4 w = wr[k4], v = xr[k4];
            p0 = fma((double)v.x, (double)w.x, p0);
            p1 = fma((double)v.y, (double)w.y, p1);
            p2 = fma((double)v.z, (double)w.z, p2);
            p3 = fma((double)v.w, (double)w.w, p3);
          }
          double h = (p0 + p1) + (p2 + p3) + (double)b1[j];
          h1s[s8][j] = h > 0.0 ? h : 0.0;
        }
      }
    }
    __syncthreads();
    // z in f64: n = ng + 32*it over 200
    {
      const int s8 = tid & 7, ng = tid >> 3;
      if (s8 < cnt) {
        for (int it = 0; it < 7; ++it) {
          const int n = ng + 32 * it;
          if (n >= NH) break;
          const float2* wr = reinterpret_cast<const float2*>(W2 + (size_t)n * NH1);
          double p0 = 0, p1 = 0;
          for (int j2 = 0; j2 < NH1 / 2; ++j2) {
            float2 w = wr[j2];
            p0 = fma(h1s[s8][2 * j2],     (double)w.x, p0);
            p1 = fma(h1s[s8][2 * j2 + 1], (double)w.y, p1);
          }
          zs[s8][n] = p0 + p1 + (double)b2[n];
        }
      }
    }
    __syncthreads();
    // argmin per (sample, group); rewrite all 20 groups of the sample
    if (tid < cnt * NG) {
      const int s8 = tid / NG, g = tid % NG;
      const int b = sl[s8];
      int best = 0; double bt = 1e300;
      #pragma unroll
      for (int j = 0; j < KD; ++j) {
        double t = chalf[j];
        #pragma unroll
        for (int k = 0; k < KD; ++k) t -= zs[s8][k * NG + g] * cs[j][k];
        if (t < bt) { bt = t; best = j; }
      }
      idx_out[(size_t)b * NG + g] = (unsigned char)best;
      #pragma unroll
      for (int k = 0; k < KD; ++k)
        emb[(size_t)b * NH + k * NG + g] = (float)cs[best][k];
    }
  }
}

// P[g][c][j] = sum_k cb[c][k] * W3[j][k*NG + g]
__global__ __launch_bounds__(256) void build_table(
    const float* __restrict__ cb, const float* __restrict__ W3,
    float* __restrict__ P)
{
  const int i = blockIdx.x * 256 + threadIdx.x;
  if (i >= NG * KD * NH1) return;
  const int j = i % NH1;
  const int c = (i / NH1) % KD;
  const int g = i / (NH1 * KD);
  float s = 0.f;
  #pragma unroll
  for (int k = 0; k < KD; ++k)
    s = fmaf(cb[c * KD + k], W3[(size_t)j * NH + k * NG + g], s);
  P[i] = s;
}

// h3[b][j] = relu(b3[j] + sum_g P[g][idx[b,g]][j]) -> bf16
__global__ __launch_bounds__(256) void compute_h3(
    const unsigned char* __restrict__ idx, const float* __restrict__ P,
    const float* __restrict__ b3, __hip_bfloat16* __restrict__ h3)
{
  __shared__ unsigned char sidx[64][NG];
  const int tid = threadIdx.x;
  const int b0 = blockIdx.x * 64;
  for (int t = tid; t < 64 * NG; t += 256)
    sidx[t / NG][t % NG] = idx[(size_t)b0 * NG + t];
  __syncthreads();
  for (int s = 0; s < 64; ++s) {
    for (int j = tid; j < NH1; j += 256) {
      float acc = b3[j];
      #pragma unroll
      for (int g = 0; g < NG; ++g) {
        const int c = sidx[s][g];
        acc += P[(g * KD + c) * NH1 + j];
      }
      h3[(size_t)(b0 + s) * NH1 + j] = __float2bfloat16(fmaxf(acc, 0.f));
    }
  }
}

extern "C" void kernel_launch(void* const* d_in, const int* in_sizes, int n_in,
                              void* d_out, int out_size, void* d_ws, size_t ws_size,
                              hipStream_t stream) {
  const float* x  = (const float*)d_in[0];
  const float* W1 = (const float*)d_in[1];
  const float* b1 = (const float*)d_in[2];
  const float* W2 = (const float*)d_in[3];
  const float* b2 = (const float*)d_in[4];
  const float* W3 = (const float*)d_in[5];
  const float* b3 = (const float*)d_in[6];
  const float* W4 = (const float*)d_in[7];
  const float* b4 = (const float*)d_in[8];
  const float* cb = (const float*)d_in[9];

  float* out   = (float*)d_out;
  float* recon = out;                              // NB x 784 (written last)
  float* z_e   = out + (size_t)NB * NIN;           // NB x 200
  float* emb   = z_e + (size_t)NB * NH;            // NB x 200

  // x_hi/x_lo exactly fill the recon region; dead before GEMM5 writes recon.
  unsigned short* x_hi = (unsigned short*)recon;
  unsigned short* x_lo = x_hi + (size_t)NB * NIN;
  // h1_lo fills the emb region; dead before quant/repair write emb.
  unsigned short* h1_lo = (unsigned short*)emb;

  char* ws = (char*)d_ws;
  int*            scount = (int*)ws;                            // 4 B
  unsigned short* zp    = (unsigned short*)(ws + 256);          // 256 B zeros
  unsigned char*  sflag = (unsigned char*)(ws + 4096);          // 64 KB
  float*          P     = (float*)(ws + (1u << 20));            // 320 KB
  unsigned char*  idx   = (unsigned char*)(ws + (2u << 20));    // 1.31 MB
  int*            slist = (int*)(ws + (4u << 20));              // 256 KB
  __hip_bfloat16* W4p   = (__hip_bfloat16*)(ws + (6u << 20));   // 745 KB
  unsigned short* W1ph  = (unsigned short*)(ws + (7u << 20));   // 512x800
  unsigned short* W1pl  = (unsigned short*)(ws + (8u << 20));
  unsigned short* W2ph  = (unsigned short*)(ws + (9u << 20));   // 256x416
  unsigned short* W2pl  = (unsigned short*)(ws + (10u << 20));
  unsigned short* h1_hi = (unsigned short*)(ws + (16u << 20));  // NB x 400 bf16
  __hip_bfloat16* h3    = (__hip_bfloat16*)(ws + (16u << 20));  // reuses h1_hi (dead)

  dim3 blk(256);
  hipMemsetAsync(ws, 0, 4096 + NB, stream);   // scount + zp + sflag
  conv_x<<<(NB * NIN / 4) / 256, blk, 0, stream>>>(x, x_hi, x_lo);
  conv_w<<<(512 * 800 + 255) / 256, blk, 0, stream>>>(W1, W1ph, W1pl, 512, 800, NH1, NIN);
  conv_w<<<(256 * 416 + 255) / 256, blk, 0, stream>>>(W2, W2ph, W2pl, 256, 416, NH, NH1);
  pad_w4<<<(896 * 416 + 255) / 256, blk, 0, stream>>>(W4, W4p);

  // stage 1: h1 = relu(x @ W1^T + b1) -> split bf16   (n-tile major grid)
  gemm_split<25, 784, 784, 800, 1><<<dim3(4, NB / 128), blk, 0, stream>>>(
      x_hi, x_lo, W1ph, W1pl, zp, b1, h1_hi, h1_lo, nullptr);
  // stage 2: z_e = h1 @ W2^T + b2
  gemm_split<13, 400, 400, 416, 2><<<dim3(2, NB / 128), blk, 0, stream>>>(
      h1_hi, h1_lo, W2ph, W2pl, zp, b2, nullptr, nullptr, z_e);

  build_table<<<(NG * KD * NH1 + 255) / 256, blk, 0, stream>>>(cb, W3, P);
  quant_kernel<<<(NB * NG) / 256, blk, 0, stream>>>(z_e, cb, emb, idx, sflag);
  compact_kernel<<<NB / 256, blk, 0, stream>>>(sflag, scount, slist);
  repair_kernel<<<1024, blk, 0, stream>>>(x, W1, b1, W2, b2, cb, slist, scount, emb, idx);
  compute_h3<<<NB / 64, blk, 0, stream>>>(idx, P, b3, h3);
  gemm5_mfma<<<dim3(7, NB / 128), blk, 0, stream>>>(h3, W4p, b4, recon);
}

// Round 6
// 1003.292 us; speedup vs baseline: 3.0356x; 1.2314x over previous
//
#include <hip/hip_runtime.h>
#include <hip/hip_bf16.h>

#define NB   65536
#define KD   10
#define NG   20
#define NH   200     // KD*NG
#define NH1  400
#define NIN  784

#define TAU 3e-4     // margin below which the sample is recomputed exactly in f64

using short8 = __attribute__((ext_vector_type(8))) short;
using f32x4  = __attribute__((ext_vector_type(4))) float;

__device__ inline float bf2f(unsigned short u) {
  union { unsigned int i; float f; } x; x.i = ((unsigned int)u) << 16; return x.f;
}
__device__ inline unsigned short f2bf(float v) {
  __hip_bfloat16 b = __float2bfloat16(v);
  return *reinterpret_cast<unsigned short*>(&b);
}
__device__ inline void gload_lds16(const void* g, void* l) {
  __builtin_amdgcn_global_load_lds(
      (const __attribute__((address_space(1))) unsigned int*)g,
      (__attribute__((address_space(3))) unsigned int*)l, 16, 0, 0);
}

// ---------------------------------------------------------------------------
// Split-bf16 MFMA GEMM (validated R4/R5): C = A @ B^T, A = Ahi+Alo, B = Bhi+Blo.
// ---------------------------------------------------------------------------
template<int KSTEPS, int LDA, int KA, int LDB, int MODE>
__global__ __launch_bounds__(256) void gemm_split(
    const unsigned short* __restrict__ Ahi, const unsigned short* __restrict__ Alo,
    const unsigned short* __restrict__ Bhi, const unsigned short* __restrict__ Blo,
    const unsigned short* __restrict__ zp, const float* __restrict__ bias,
    unsigned short* __restrict__ Ohi, unsigned short* __restrict__ Olo,
    float* __restrict__ Of)
{
  __shared__ __align__(16) short As_hi[128][32];
  __shared__ __align__(16) short As_lo[128][32];
  __shared__ __align__(16) short Bs_hi[128][32];
  __shared__ __align__(16) short Bs_lo[128][32];
  const int tid = threadIdx.x;
  const int lane = tid & 63, wid = tid >> 6;
  const int wr = wid >> 1, wc = wid & 1;
  const int m0 = blockIdx.y * 128, n0 = blockIdx.x * 128;

  const unsigned short* G = (wid == 0) ? Ahi : (wid == 1) ? Alo
                          : (wid == 2) ? Bhi : Blo;
  short* Lt = (wid == 0) ? &As_hi[0][0] : (wid == 1) ? &As_lo[0][0]
            : (wid == 2) ? &Bs_hi[0][0] : &Bs_lo[0][0];
  const bool isA = wid < 2;
  const int rbase = isA ? m0 : n0;
  const int ld = isA ? LDA : LDB;
  const int rr = lane >> 2;
  const int kofs = (lane & 3) * 8;

  f32x4 acc[4][4];
  #pragma unroll
  for (int i = 0; i < 4; ++i)
    #pragma unroll
    for (int j = 0; j < 4; ++j) acc[i][j] = (f32x4){0.f, 0.f, 0.f, 0.f};

  for (int ks = 0; ks < KSTEPS; ++ks) {
    const int k0 = ks * 32;
    #pragma unroll
    for (int c = 0; c < 8; ++c) {
      const unsigned short* src =
          G + (size_t)(rbase + c * 16 + rr) * ld + k0 + kofs;
      if (isA && (k0 + kofs >= KA)) src = zp;
      gload_lds16(src, (char*)Lt + c * 1024);
    }
    __syncthreads();
    short8 ah[4], al[4], bh[4], bl[4];
    #pragma unroll
    for (int i = 0; i < 4; ++i) {
      ah[i] = *reinterpret_cast<const short8*>(&As_hi[wr * 64 + i * 16 + (lane & 15)][(lane >> 4) * 8]);
      al[i] = *reinterpret_cast<const short8*>(&As_lo[wr * 64 + i * 16 + (lane & 15)][(lane >> 4) * 8]);
      bh[i] = *reinterpret_cast<const short8*>(&Bs_hi[wc * 64 + i * 16 + (lane & 15)][(lane >> 4) * 8]);
      bl[i] = *reinterpret_cast<const short8*>(&Bs_lo[wc * 64 + i * 16 + (lane & 15)][(lane >> 4) * 8]);
    }
    #pragma unroll
    for (int i = 0; i < 4; ++i)
      #pragma unroll
      for (int j = 0; j < 4; ++j) {
        acc[i][j] = __builtin_amdgcn_mfma_f32_16x16x32_bf16(ah[i], bh[j], acc[i][j], 0, 0, 0);
        acc[i][j] = __builtin_amdgcn_mfma_f32_16x16x32_bf16(al[i], bh[j], acc[i][j], 0, 0, 0);
        acc[i][j] = __builtin_amdgcn_mfma_f32_16x16x32_bf16(ah[i], bl[j], acc[i][j], 0, 0, 0);
      }
    __syncthreads();
  }

  #pragma unroll
  for (int j = 0; j < 4; ++j) {
    const int n = n0 + wc * 64 + j * 16 + (lane & 15);
    if (MODE == 1) {
      if (n >= NH1) continue;
      const float bn = bias[n];
      #pragma unroll
      for (int i = 0; i < 4; ++i) {
        const int mb = m0 + wr * 64 + i * 16 + (lane >> 4) * 4;
        #pragma unroll
        for (int r = 0; r < 4; ++r) {
          float v = fmaxf(acc[i][j][r] + bn, 0.f);
          unsigned short h = f2bf(v);
          Ohi[(size_t)(mb + r) * NH1 + n] = h;
          Olo[(size_t)(mb + r) * NH1 + n] = f2bf(v - bf2f(h));
        }
      }
    } else {
      if (n >= NH) continue;
      const float bn = bias[n];
      #pragma unroll
      for (int i = 0; i < 4; ++i) {
        const int mb = m0 + wr * 64 + i * 16 + (lane >> 4) * 4;
        #pragma unroll
        for (int r = 0; r < 4; ++r)
          Of[(size_t)(mb + r) * NH + n] = acc[i][j][r] + bn;
      }
    }
  }
}

// ---------------------------------------------------------------------------
// Stage 5: recon = tanh(h3(bf16) @ W4p^T + b4). MFMA (validated R3/R4).
// ---------------------------------------------------------------------------
__global__ __launch_bounds__(256) void gemm5_mfma(
    const __hip_bfloat16* __restrict__ A,   // h3: NB x 400
    const __hip_bfloat16* __restrict__ Bp,  // W4p: 896 x 416
    const float* __restrict__ bias, float* __restrict__ C)
{
  __shared__ __align__(16) short As[128][32];
  __shared__ __align__(16) short Bs[128][32];
  const int tid = threadIdx.x;
  const int lane = tid & 63, wid = tid >> 6;
  const int wr = wid >> 1, wc = wid & 1;
  const int m0 = blockIdx.y * 128, n0 = blockIdx.x * 128;
  const int srow = lane >> 2;
  const int skp  = (lane & 3) * 8;
  const short* Ag = (const short*)A;
  const short* Bg = (const short*)Bp;
  f32x4 acc[4][4];
  #pragma unroll
  for (int i = 0; i < 4; ++i)
    #pragma unroll
    for (int j = 0; j < 4; ++j) acc[i][j] = (f32x4){0.f, 0.f, 0.f, 0.f};

  for (int k0 = 0; k0 < 416; k0 += 32) {
    #pragma unroll
    for (int c = 0; c < 2; ++c) {
      const int row = c * 64 + wid * 16 + srow;
      gload_lds16(Ag + (size_t)(m0 + row) * 400 + k0 + skp,
                  (char*)&As[0][0] + c * 4096 + wid * 1024);
      gload_lds16(Bg + (size_t)(n0 + row) * 416 + k0 + skp,
                  (char*)&Bs[0][0] + c * 4096 + wid * 1024);
    }
    __syncthreads();
    short8 af[4], bf[4];
    #pragma unroll
    for (int i = 0; i < 4; ++i)
      af[i] = *reinterpret_cast<const short8*>(&As[wr * 64 + i * 16 + (lane & 15)][(lane >> 4) * 8]);
    #pragma unroll
    for (int j = 0; j < 4; ++j)
      bf[j] = *reinterpret_cast<const short8*>(&Bs[wc * 64 + j * 16 + (lane & 15)][(lane >> 4) * 8]);
    #pragma unroll
    for (int i = 0; i < 4; ++i)
      #pragma unroll
      for (int j = 0; j < 4; ++j)
        acc[i][j] = __builtin_amdgcn_mfma_f32_16x16x32_bf16(af[i], bf[j], acc[i][j], 0, 0, 0);
    __syncthreads();
  }

  #pragma unroll
  for (int j = 0; j < 4; ++j) {
    const int n = n0 + wc * 64 + j * 16 + (lane & 15);
    if (n >= NIN) continue;
    const float bn = bias[n];
    #pragma unroll
    for (int i = 0; i < 4; ++i) {
      const int mb = m0 + wr * 64 + i * 16 + (lane >> 4) * 4;
      #pragma unroll
      for (int r = 0; r < 4; ++r)
        C[(size_t)(mb + r) * NIN + n] = tanhf(acc[i][j][r] + bn);
    }
  }
}

// -------------------------- converters / padders ---------------------------
__global__ __launch_bounds__(256) void conv_x(
    const float* __restrict__ x, unsigned short* __restrict__ xh,
    unsigned short* __restrict__ xl)
{
  const size_t i = (size_t)blockIdx.x * 256 + threadIdx.x;
  float4 v = reinterpret_cast<const float4*>(x)[i];
  ushort4 h, l;
  h.x = f2bf(v.x); l.x = f2bf(v.x - bf2f(h.x));
  h.y = f2bf(v.y); l.y = f2bf(v.y - bf2f(h.y));
  h.z = f2bf(v.z); l.z = f2bf(v.z - bf2f(h.z));
  h.w = f2bf(v.w); l.w = f2bf(v.w - bf2f(h.w));
  reinterpret_cast<ushort4*>(xh)[i] = h;
  reinterpret_cast<ushort4*>(xl)[i] = l;
}

__global__ __launch_bounds__(256) void conv_w(
    const float* __restrict__ W, unsigned short* __restrict__ Wh,
    unsigned short* __restrict__ Wl, int NP, int KP, int N, int K)
{
  const int i = blockIdx.x * 256 + threadIdx.x;
  if (i >= NP * KP) return;
  const int n = i / KP, k = i % KP;
  const float v = (n < N && k < K) ? W[(size_t)n * K + k] : 0.f;
  const unsigned short h = f2bf(v);
  Wh[i] = h;
  Wl[i] = f2bf(v - bf2f(h));
}

__global__ __launch_bounds__(256) void pad_w4(
    const float* __restrict__ W4, __hip_bfloat16* __restrict__ W4p)
{
  const int i = blockIdx.x * 256 + threadIdx.x;
  if (i >= 896 * 416) return;
  const int n = i / 416, k = i % 416;
  const float v = (n < NIN && k < NH1) ? W4[(size_t)n * NH1 + k] : 0.f;
  W4p[i] = __float2bfloat16(v);
}

// ---------------------------------------------------------------------------
// Quantization: f64 distances from fast z_e; margin < TAU -> flag the SAMPLE.
// ---------------------------------------------------------------------------
__global__ __launch_bounds__(256) void quant_kernel(
    const float* __restrict__ z_e, const float* __restrict__ cb,
    float* __restrict__ emb, unsigned char* __restrict__ idx_out,
    unsigned char* __restrict__ sflag)
{
  __shared__ double cs[KD][KD];
  __shared__ double chalf[KD];
  const int tid = threadIdx.x;
  if (tid < KD * KD) cs[tid / KD][tid % KD] = (double)cb[tid];
  __syncthreads();
  if (tid < KD) {
    double s = 0.0;
    #pragma unroll
    for (int k = 0; k < KD; ++k) s += cs[tid][k] * cs[tid][k];
    chalf[tid] = 0.5 * s;
  }
  __syncthreads();

  const int gi = blockIdx.x * 256 + tid;
  const int b = gi / NG;
  const int g = gi % NG;
  const float* zrow = z_e + (size_t)b * NH + g;
  double v[KD];
  #pragma unroll
  for (int k = 0; k < KD; ++k) v[k] = (double)zrow[k * NG];

  int best = 0; double bt = 1e300, bt2 = 1e300;
  #pragma unroll
  for (int j = 0; j < KD; ++j) {
    double t = chalf[j];
    #pragma unroll
    for (int k = 0; k < KD; ++k) t -= v[k] * cs[j][k];
    if (t < bt) { bt2 = bt; bt = t; best = j; }
    else if (t < bt2) { bt2 = t; }
  }
  float* ep = emb + (size_t)b * NH + g;
  #pragma unroll
  for (int k = 0; k < KD; ++k) ep[k * NG] = (float)cs[best][k];
  idx_out[gi] = (unsigned char)best;

  if (bt2 - bt < TAU) sflag[b] = 1;
}

__global__ __launch_bounds__(256) void compact_kernel(
    const unsigned char* __restrict__ sflag, int* __restrict__ scount,
    int* __restrict__ slist)
{
  const int i = blockIdx.x * 256 + threadIdx.x;
  if (i < NB && sflag[i]) slist[atomicAdd(scount, 1)] = i;
}

// ---------------------------------------------------------------------------
// Exact f64 repair, one sample per block. Lane-parallel dots, x row cached in
// registers (reused across all 400 h1 rows), f64 shuffle reductions.
// ---------------------------------------------------------------------------
__global__ __launch_bounds__(256) void repair_kernel(
    const float* __restrict__ x, const float* __restrict__ W1,
    const float* __restrict__ b1, const float* __restrict__ W2,
    const float* __restrict__ b2, const float* __restrict__ cb,
    const int* __restrict__ slist, const int* __restrict__ scount,
    float* __restrict__ emb, unsigned char* __restrict__ idx_out)
{
  __shared__ double h1s[NH1];
  __shared__ double zs[NH];
  __shared__ double cs[KD][KD];
  __shared__ double chalf[KD];
  const int tid = threadIdx.x;
  const int lane = tid & 63, wv = tid >> 6;
  if (tid < KD * KD) cs[tid / KD][tid % KD] = (double)cb[tid];
  __syncthreads();
  if (tid < KD) {
    double s = 0.0;
    #pragma unroll
    for (int k = 0; k < KD; ++k) s += cs[tid][k] * cs[tid][k];
    chalf[tid] = 0.5 * s;
  }

  int S = *scount; if (S > NB) S = NB;

  for (int si = blockIdx.x; si < S; si += gridDim.x) {
    const int b = slist[si];
    // x row -> registers (lane-parallel float4 slices), reused for all rows
    double xr[4][4];
    #pragma unroll
    for (int it = 0; it < 4; ++it) {
      const int c4 = it * 64 + lane;    // float4 index over 196
      if (c4 < 196) {
        float4 v = reinterpret_cast<const float4*>(x + (size_t)b * NIN)[c4];
        xr[it][0] = v.x; xr[it][1] = v.y; xr[it][2] = v.z; xr[it][3] = v.w;
      } else {
        xr[it][0] = xr[it][1] = xr[it][2] = xr[it][3] = 0.0;
      }
    }
    // h1 in f64: wave wv owns rows j = wv, wv+4, ...
    for (int j = wv; j < NH1; j += 4) {
      const float4* wr = reinterpret_cast<const float4*>(W1 + (size_t)j * NIN);
      double s0 = 0, s1 = 0, s2 = 0, s3 = 0;
      #pragma unroll
      for (int it = 0; it < 4; ++it) {
        const int c4 = it * 64 + lane;
        if (c4 < 196) {
          float4 w = wr[c4];
          s0 = fma(xr[it][0], (double)w.x, s0);
          s1 = fma(xr[it][1], (double)w.y, s1);
          s2 = fma(xr[it][2], (double)w.z, s2);
          s3 = fma(xr[it][3], (double)w.w, s3);
        }
      }
      double s = (s0 + s1) + (s2 + s3);
      #pragma unroll
      for (int off = 32; off > 0; off >>= 1) s += __shfl_down(s, off);
      if (lane == 0) { double h = s + (double)b1[j]; h1s[j] = h > 0.0 ? h : 0.0; }
    }
    __syncthreads();
    // h1 slice -> registers
    double hr[2][4];
    #pragma unroll
    for (int it = 0; it < 2; ++it) {
      const int c4 = it * 64 + lane;    // double4 index over 100
      if (c4 < 100) {
        hr[it][0] = h1s[4 * c4 + 0]; hr[it][1] = h1s[4 * c4 + 1];
        hr[it][2] = h1s[4 * c4 + 2]; hr[it][3] = h1s[4 * c4 + 3];
      } else {
        hr[it][0] = hr[it][1] = hr[it][2] = hr[it][3] = 0.0;
      }
    }
    // z in f64: wave wv owns n = wv, wv+4, ...
    for (int n = wv; n < NH; n += 4) {
      const float4* wr = reinterpret_cast<const float4*>(W2 + (size_t)n * NH1);
      double s0 = 0, s1 = 0, s2 = 0, s3 = 0;
      #pragma unroll
      for (int it = 0; it < 2; ++it) {
        const int c4 = it * 64 + lane;
        if (c4 < 100) {
          float4 w = wr[c4];
          s0 = fma(hr[it][0], (double)w.x, s0);
          s1 = fma(hr[it][1], (double)w.y, s1);
          s2 = fma(hr[it][2], (double)w.z, s2);
          s3 = fma(hr[it][3], (double)w.w, s3);
        }
      }
      double s = (s0 + s1) + (s2 + s3);
      #pragma unroll
      for (int off = 32; off > 0; off >>= 1) s += __shfl_down(s, off);
      if (lane == 0) zs[n] = s + (double)b2[n];
    }
    __syncthreads();
    // argmin per group; rewrite this sample's 20 groups
    if (tid < NG) {
      const int g = tid;
      int best = 0; double bt = 1e300;
      #pragma unroll
      for (int j = 0; j < KD; ++j) {
        double t = chalf[j];
        #pragma unroll
        for (int k = 0; k < KD; ++k) t -= zs[k * NG + g] * cs[j][k];
        if (t < bt) { bt = t; best = j; }
      }
      idx_out[(size_t)b * NG + g] = (unsigned char)best;
      #pragma unroll
      for (int k = 0; k < KD; ++k)
        emb[(size_t)b * NH + k * NG + g] = (float)cs[best][k];
    }
    __syncthreads();   // protect h1s/zs before next sample
  }
}

// P[g][c][j] = sum_k cb[c][k] * W3[j][k*NG + g]
__global__ __launch_bounds__(256) void build_table(
    const float* __restrict__ cb, const float* __restrict__ W3,
    float* __restrict__ P)
{
  const int i = blockIdx.x * 256 + threadIdx.x;
  if (i >= NG * KD * NH1) return;
  const int j = i % NH1;
  const int c = (i / NH1) % KD;
  const int g = i / (NH1 * KD);
  float s = 0.f;
  #pragma unroll
  for (int k = 0; k < KD; ++k)
    s = fmaf(cb[c * KD + k], W3[(size_t)j * NH + k * NG + g], s);
  P[i] = s;
}

// h3[b][j] = relu(b3[j] + sum_g P[g][idx[b,g]][j]) -> bf16
__global__ __launch_bounds__(256) void compute_h3(
    const unsigned char* __restrict__ idx, const float* __restrict__ P,
    const float* __restrict__ b3, __hip_bfloat16* __restrict__ h3)
{
  __shared__ unsigned char sidx[64][NG];
  const int tid = threadIdx.x;
  const int b0 = blockIdx.x * 64;
  for (int t = tid; t < 64 * NG; t += 256)
    sidx[t / NG][t % NG] = idx[(size_t)b0 * NG + t];
  __syncthreads();
  for (int s = 0; s < 64; ++s) {
    for (int j = tid; j < NH1; j += 256) {
      float acc = b3[j];
      #pragma unroll
      for (int g = 0; g < NG; ++g) {
        const int c = sidx[s][g];
        acc += P[(g * KD + c) * NH1 + j];
      }
      h3[(size_t)(b0 + s) * NH1 + j] = __float2bfloat16(fmaxf(acc, 0.f));
    }
  }
}

extern "C" void kernel_launch(void* const* d_in, const int* in_sizes, int n_in,
                              void* d_out, int out_size, void* d_ws, size_t ws_size,
                              hipStream_t stream) {
  const float* x  = (const float*)d_in[0];
  const float* W1 = (const float*)d_in[1];
  const float* b1 = (const float*)d_in[2];
  const float* W2 = (const float*)d_in[3];
  const float* b2 = (const float*)d_in[4];
  const float* W3 = (const float*)d_in[5];
  const float* b3 = (const float*)d_in[6];
  const float* W4 = (const float*)d_in[7];
  const float* b4 = (const float*)d_in[8];
  const float* cb = (const float*)d_in[9];

  float* out   = (float*)d_out;
  float* recon = out;                              // NB x 784 (written last)
  float* z_e   = out + (size_t)NB * NIN;           // NB x 200
  float* emb   = z_e + (size_t)NB * NH;            // NB x 200

  unsigned short* x_hi = (unsigned short*)recon;   // dead before GEMM5
  unsigned short* x_lo = x_hi + (size_t)NB * NIN;
  unsigned short* h1_lo = (unsigned short*)emb;    // dead before quant/repair

  char* ws = (char*)d_ws;
  int*            scount = (int*)ws;                            // 4 B
  unsigned short* zp    = (unsigned short*)(ws + 256);          // 256 B zeros
  unsigned char*  sflag = (unsigned char*)(ws + 4096);          // 64 KB
  float*          P     = (float*)(ws + (1u << 20));            // 320 KB
  unsigned char*  idx   = (unsigned char*)(ws + (2u << 20));    // 1.31 MB
  int*            slist = (int*)(ws + (4u << 20));              // 256 KB
  __hip_bfloat16* W4p   = (__hip_bfloat16*)(ws + (6u << 20));   // 745 KB
  unsigned short* W1ph  = (unsigned short*)(ws + (7u << 20));   // 512x800
  unsigned short* W1pl  = (unsigned short*)(ws + (8u << 20));
  unsigned short* W2ph  = (unsigned short*)(ws + (9u << 20));   // 256x416
  unsigned short* W2pl  = (unsigned short*)(ws + (10u << 20));
  unsigned short* h1_hi = (unsigned short*)(ws + (16u << 20));  // NB x 400 bf16
  __hip_bfloat16* h3    = (__hip_bfloat16*)(ws + (16u << 20));  // reuses h1_hi (dead)

  dim3 blk(256);
  hipMemsetAsync(ws, 0, 4096 + NB, stream);   // scount + zp + sflag
  conv_x<<<(NB * NIN / 4) / 256, blk, 0, stream>>>(x, x_hi, x_lo);
  conv_w<<<(512 * 800 + 255) / 256, blk, 0, stream>>>(W1, W1ph, W1pl, 512, 800, NH1, NIN);
  conv_w<<<(256 * 416 + 255) / 256, blk, 0, stream>>>(W2, W2ph, W2pl, 256, 416, NH, NH1);
  pad_w4<<<(896 * 416 + 255) / 256, blk, 0, stream>>>(W4, W4p);

  // stage 1: h1 = relu(x @ W1^T + b1) -> split bf16   (n-tile major grid)
  gemm_split<25, 784, 784, 800, 1><<<dim3(4, NB / 128), blk, 0, stream>>>(
      x_hi, x_lo, W1ph, W1pl, zp, b1, h1_hi, h1_lo, nullptr);
  // stage 2: z_e = h1 @ W2^T + b2
  gemm_split<13, 400, 400, 416, 2><<<dim3(2, NB / 128), blk, 0, stream>>>(
      h1_hi, h1_lo, W2ph, W2pl, zp, b2, nullptr, nullptr, z_e);

  build_table<<<(NG * KD * NH1 + 255) / 256, blk, 0, stream>>>(cb, W3, P);
  quant_kernel<<<(NB * NG) / 256, blk, 0, stream>>>(z_e, cb, emb, idx, sflag);
  compact_kernel<<<NB / 256, blk, 0, stream>>>(sflag, scount, slist);
  repair_kernel<<<2048, blk, 0, stream>>>(x, W1, b1, W2, b2, cb, slist, scount, emb, idx);
  compute_h3<<<NB / 64, blk, 0, stream>>>(idx, P, b3, h3);
  gemm5_mfma<<<dim3(7, NB / 128), blk, 0, stream>>>(h3, W4p, b4, recon);
}

// Round 7
// 996.579 us; speedup vs baseline: 3.0560x; 1.0067x over previous
//
#include <hip/hip_runtime.h>
#include <hip/hip_bf16.h>

#define NB   65536
#define KD   10
#define NG   20
#define NH   200     // KD*NG
#define NH1  400
#define NIN  784

#define TAU 3e-4     // margin below which the sample is recomputed exactly in f64

using short8 = __attribute__((ext_vector_type(8))) short;
using f32x4  = __attribute__((ext_vector_type(4))) float;

__device__ inline float bf2f(unsigned short u) {
  union { unsigned int i; float f; } x; x.i = ((unsigned int)u) << 16; return x.f;
}
__device__ inline unsigned short f2bf(float v) {
  __hip_bfloat16 b = __float2bfloat16(v);
  return *reinterpret_cast<unsigned short*>(&b);
}
__device__ inline void gload_lds16(const void* g, void* l) {
  __builtin_amdgcn_global_load_lds(
      (const __attribute__((address_space(1))) unsigned int*)g,
      (__attribute__((address_space(3))) unsigned int*)l, 16, 0, 0);
}

// ---------------------------------------------------------------------------
// Stage 1 fused: h1 = relu(x @ W1^T + b1) -> split bf16.
// A (x, fp32) is reg-staged and split to hi/lo in-register (conv_x fused in).
// B (W1 pre-split, padded 512x800) staged via global_load_lds.
// XCD-bijective swizzle: 2048 blocks, 256/XCD, n-tile fastest.
// ---------------------------------------------------------------------------
__global__ __launch_bounds__(256) void gemm1_fused(
    const float* __restrict__ xf,
    const unsigned short* __restrict__ Bhi, const unsigned short* __restrict__ Blo,
    const float* __restrict__ bias,
    unsigned short* __restrict__ Ohi, unsigned short* __restrict__ Olo)
{
  __shared__ __align__(16) short As_hi[128][32];
  __shared__ __align__(16) short As_lo[128][32];
  __shared__ __align__(16) short Bs_hi[128][32];
  __shared__ __align__(16) short Bs_lo[128][32];
  const int tid = threadIdx.x;
  const int lane = tid & 63, wid = tid >> 6;
  const int wr = wid >> 1, wc = wid & 1;
  const int bid = blockIdx.x;
  const int sw = (bid & 7) * 256 + (bid >> 3);
  const int n0 = (sw & 3) * 128;
  const int m0 = (sw >> 2) * 128;
  const int rr = lane >> 2, kofs = (lane & 3) * 8;

  f32x4 acc[4][4];
  #pragma unroll
  for (int i = 0; i < 4; ++i)
    #pragma unroll
    for (int j = 0; j < 4; ++j) acc[i][j] = (f32x4){0.f, 0.f, 0.f, 0.f};

  for (int ks = 0; ks < 25; ++ks) {
    const int k0 = ks * 32;
    // B: 16 chunks of 1 KiB via global_load_lds, 4 per wave
    #pragma unroll
    for (int c = 0; c < 4; ++c) {
      const int ch = wid * 4 + c;
      if (ch < 8)
        gload_lds16(Bhi + (size_t)(n0 + ch * 16 + rr) * 800 + k0 + kofs,
                    (char*)&Bs_hi[0][0] + ch * 1024);
      else
        gload_lds16(Blo + (size_t)(n0 + (ch - 8) * 16 + rr) * 800 + k0 + kofs,
                    (char*)&Bs_lo[0][0] + (ch - 8) * 1024);
    }
    // A: reg-stage fp32 x -> split hi/lo -> LDS (4 passes x 32 rows)
    #pragma unroll
    for (int p = 0; p < 4; ++p) {
      const int row = p * 32 + (tid >> 3);
      const int kk = k0 + (tid & 7) * 4;
      float4 v = make_float4(0.f, 0.f, 0.f, 0.f);
      if (kk < NIN)   // 784 % 4 == 0: float4 fully valid or fully tail
        v = *reinterpret_cast<const float4*>(xf + (size_t)(m0 + row) * NIN + kk);
      short4 h, l;
      h.x = (short)f2bf(v.x); l.x = (short)f2bf(v.x - bf2f((unsigned short)h.x));
      h.y = (short)f2bf(v.y); l.y = (short)f2bf(v.y - bf2f((unsigned short)h.y));
      h.z = (short)f2bf(v.z); l.z = (short)f2bf(v.z - bf2f((unsigned short)h.z));
      h.w = (short)f2bf(v.w); l.w = (short)f2bf(v.w - bf2f((unsigned short)h.w));
      *reinterpret_cast<short4*>(&As_hi[row][(tid & 7) * 4]) = h;
      *reinterpret_cast<short4*>(&As_lo[row][(tid & 7) * 4]) = l;
    }
    __syncthreads();
    short8 ah[4], al[4], bh[4], bl[4];
    #pragma unroll
    for (int i = 0; i < 4; ++i) {
      ah[i] = *reinterpret_cast<const short8*>(&As_hi[wr * 64 + i * 16 + (lane & 15)][(lane >> 4) * 8]);
      al[i] = *reinterpret_cast<const short8*>(&As_lo[wr * 64 + i * 16 + (lane & 15)][(lane >> 4) * 8]);
      bh[i] = *reinterpret_cast<const short8*>(&Bs_hi[wc * 64 + i * 16 + (lane & 15)][(lane >> 4) * 8]);
      bl[i] = *reinterpret_cast<const short8*>(&Bs_lo[wc * 64 + i * 16 + (lane & 15)][(lane >> 4) * 8]);
    }
    #pragma unroll
    for (int i = 0; i < 4; ++i)
      #pragma unroll
      for (int j = 0; j < 4; ++j) {
        acc[i][j] = __builtin_amdgcn_mfma_f32_16x16x32_bf16(ah[i], bh[j], acc[i][j], 0, 0, 0);
        acc[i][j] = __builtin_amdgcn_mfma_f32_16x16x32_bf16(al[i], bh[j], acc[i][j], 0, 0, 0);
        acc[i][j] = __builtin_amdgcn_mfma_f32_16x16x32_bf16(ah[i], bl[j], acc[i][j], 0, 0, 0);
      }
    __syncthreads();
  }

  #pragma unroll
  for (int j = 0; j < 4; ++j) {
    const int n = n0 + wc * 64 + j * 16 + (lane & 15);
    if (n >= NH1) continue;
    const float bn = bias[n];
    #pragma unroll
    for (int i = 0; i < 4; ++i) {
      const int mb = m0 + wr * 64 + i * 16 + (lane >> 4) * 4;
      #pragma unroll
      for (int r = 0; r < 4; ++r) {
        float v = fmaxf(acc[i][j][r] + bn, 0.f);
        unsigned short h = f2bf(v);
        Ohi[(size_t)(mb + r) * NH1 + n] = h;
        Olo[(size_t)(mb + r) * NH1 + n] = f2bf(v - bf2f(h));
      }
    }
  }
}

// ---------------------------------------------------------------------------
// Stage 2: z_e = h1 @ W2^T + b2 (split bf16, all tiles via global_load_lds).
// 1024 blocks, 128/XCD, n-tile (2) fastest.
// ---------------------------------------------------------------------------
__global__ __launch_bounds__(256) void gemm2_split(
    const unsigned short* __restrict__ Ahi, const unsigned short* __restrict__ Alo,
    const unsigned short* __restrict__ Bhi, const unsigned short* __restrict__ Blo,
    const unsigned short* __restrict__ zp, const float* __restrict__ bias,
    float* __restrict__ Of)
{
  __shared__ __align__(16) short As_hi[128][32];
  __shared__ __align__(16) short As_lo[128][32];
  __shared__ __align__(16) short Bs_hi[128][32];
  __shared__ __align__(16) short Bs_lo[128][32];
  const int tid = threadIdx.x;
  const int lane = tid & 63, wid = tid >> 6;
  const int wr = wid >> 1, wc = wid & 1;
  const int bid = blockIdx.x;
  const int sw = (bid & 7) * 128 + (bid >> 3);
  const int n0 = (sw & 1) * 128;
  const int m0 = (sw >> 1) * 128;

  const unsigned short* G = (wid == 0) ? Ahi : (wid == 1) ? Alo
                          : (wid == 2) ? Bhi : Blo;
  short* Lt = (wid == 0) ? &As_hi[0][0] : (wid == 1) ? &As_lo[0][0]
            : (wid == 2) ? &Bs_hi[0][0] : &Bs_lo[0][0];
  const bool isA = wid < 2;
  const int rbase = isA ? m0 : n0;
  const int ld = isA ? 400 : 416;
  const int rr = lane >> 2;
  const int kofs = (lane & 3) * 8;

  f32x4 acc[4][4];
  #pragma unroll
  for (int i = 0; i < 4; ++i)
    #pragma unroll
    for (int j = 0; j < 4; ++j) acc[i][j] = (f32x4){0.f, 0.f, 0.f, 0.f};

  for (int ks = 0; ks < 13; ++ks) {
    const int k0 = ks * 32;
    #pragma unroll
    for (int c = 0; c < 8; ++c) {
      const unsigned short* src =
          G + (size_t)(rbase + c * 16 + rr) * ld + k0 + kofs;
      if (isA && (k0 + kofs >= 400)) src = zp;
      gload_lds16(src, (char*)Lt + c * 1024);
    }
    __syncthreads();
    short8 ah[4], al[4], bh[4], bl[4];
    #pragma unroll
    for (int i = 0; i < 4; ++i) {
      ah[i] = *reinterpret_cast<const short8*>(&As_hi[wr * 64 + i * 16 + (lane & 15)][(lane >> 4) * 8]);
      al[i] = *reinterpret_cast<const short8*>(&As_lo[wr * 64 + i * 16 + (lane & 15)][(lane >> 4) * 8]);
      bh[i] = *reinterpret_cast<const short8*>(&Bs_hi[wc * 64 + i * 16 + (lane & 15)][(lane >> 4) * 8]);
      bl[i] = *reinterpret_cast<const short8*>(&Bs_lo[wc * 64 + i * 16 + (lane & 15)][(lane >> 4) * 8]);
    }
    #pragma unroll
    for (int i = 0; i < 4; ++i)
      #pragma unroll
      for (int j = 0; j < 4; ++j) {
        acc[i][j] = __builtin_amdgcn_mfma_f32_16x16x32_bf16(ah[i], bh[j], acc[i][j], 0, 0, 0);
        acc[i][j] = __builtin_amdgcn_mfma_f32_16x16x32_bf16(al[i], bh[j], acc[i][j], 0, 0, 0);
        acc[i][j] = __builtin_amdgcn_mfma_f32_16x16x32_bf16(ah[i], bl[j], acc[i][j], 0, 0, 0);
      }
    __syncthreads();
  }

  #pragma unroll
  for (int j = 0; j < 4; ++j) {
    const int n = n0 + wc * 64 + j * 16 + (lane & 15);
    if (n >= NH) continue;
    const float bn = bias[n];
    #pragma unroll
    for (int i = 0; i < 4; ++i) {
      const int mb = m0 + wr * 64 + i * 16 + (lane >> 4) * 4;
      #pragma unroll
      for (int r = 0; r < 4; ++r)
        Of[(size_t)(mb + r) * NH + n] = acc[i][j][r] + bn;
    }
  }
}

// ---------------------------------------------------------------------------
// Stage 5: recon = tanh(h3(bf16) @ W4p^T + b4). 3584 blocks, 448/XCD.
// ---------------------------------------------------------------------------
__global__ __launch_bounds__(256) void gemm5_mfma(
    const __hip_bfloat16* __restrict__ A,   // h3: NB x 400
    const __hip_bfloat16* __restrict__ Bp,  // W4p: 896 x 416
    const float* __restrict__ bias, float* __restrict__ C)
{
  __shared__ __align__(16) short As[128][32];
  __shared__ __align__(16) short Bs[128][32];
  const int tid = threadIdx.x;
  const int lane = tid & 63, wid = tid >> 6;
  const int wr = wid >> 1, wc = wid & 1;
  const int bid = blockIdx.x;
  const int sw = (bid & 7) * 448 + (bid >> 3);
  const int n0 = (sw % 7) * 128;
  const int m0 = (sw / 7) * 128;
  const int srow = lane >> 2;
  const int skp  = (lane & 3) * 8;
  const short* Ag = (const short*)A;
  const short* Bg = (const short*)Bp;
  f32x4 acc[4][4];
  #pragma unroll
  for (int i = 0; i < 4; ++i)
    #pragma unroll
    for (int j = 0; j < 4; ++j) acc[i][j] = (f32x4){0.f, 0.f, 0.f, 0.f};

  for (int k0 = 0; k0 < 416; k0 += 32) {
    #pragma unroll
    for (int c = 0; c < 2; ++c) {
      const int row = c * 64 + wid * 16 + srow;
      gload_lds16(Ag + (size_t)(m0 + row) * 400 + k0 + skp,
                  (char*)&As[0][0] + c * 4096 + wid * 1024);
      gload_lds16(Bg + (size_t)(n0 + row) * 416 + k0 + skp,
                  (char*)&Bs[0][0] + c * 4096 + wid * 1024);
    }
    __syncthreads();
    short8 af[4], bf[4];
    #pragma unroll
    for (int i = 0; i < 4; ++i)
      af[i] = *reinterpret_cast<const short8*>(&As[wr * 64 + i * 16 + (lane & 15)][(lane >> 4) * 8]);
    #pragma unroll
    for (int j = 0; j < 4; ++j)
      bf[j] = *reinterpret_cast<const short8*>(&Bs[wc * 64 + j * 16 + (lane & 15)][(lane >> 4) * 8]);
    #pragma unroll
    for (int i = 0; i < 4; ++i)
      #pragma unroll
      for (int j = 0; j < 4; ++j)
        acc[i][j] = __builtin_amdgcn_mfma_f32_16x16x32_bf16(af[i], bf[j], acc[i][j], 0, 0, 0);
    __syncthreads();
  }

  #pragma unroll
  for (int j = 0; j < 4; ++j) {
    const int n = n0 + wc * 64 + j * 16 + (lane & 15);
    if (n >= NIN) continue;
    const float bn = bias[n];
    #pragma unroll
    for (int i = 0; i < 4; ++i) {
      const int mb = m0 + wr * 64 + i * 16 + (lane >> 4) * 4;
      #pragma unroll
      for (int r = 0; r < 4; ++r)
        C[(size_t)(mb + r) * NIN + n] = tanhf(acc[i][j][r] + bn);
    }
  }
}

// -------------------------- converters / padders ---------------------------
__global__ __launch_bounds__(256) void conv_w(
    const float* __restrict__ W, unsigned short* __restrict__ Wh,
    unsigned short* __restrict__ Wl, int NP, int KP, int N, int K)
{
  const int i = blockIdx.x * 256 + threadIdx.x;
  if (i >= NP * KP) return;
  const int n = i / KP, k = i % KP;
  const float v = (n < N && k < K) ? W[(size_t)n * K + k] : 0.f;
  const unsigned short h = f2bf(v);
  Wh[i] = h;
  Wl[i] = f2bf(v - bf2f(h));
}

__global__ __launch_bounds__(256) void pad_w4(
    const float* __restrict__ W4, __hip_bfloat16* __restrict__ W4p)
{
  const int i = blockIdx.x * 256 + threadIdx.x;
  if (i >= 896 * 416) return;
  const int n = i / 416, k = i % 416;
  const float v = (n < NIN && k < NH1) ? W4[(size_t)n * NH1 + k] : 0.f;
  W4p[i] = __float2bfloat16(v);
}

// ---------------------------------------------------------------------------
// Quantization: f64 distances from fast z_e; margin < TAU -> flag the SAMPLE.
// ---------------------------------------------------------------------------
__global__ __launch_bounds__(256) void quant_kernel(
    const float* __restrict__ z_e, const float* __restrict__ cb,
    float* __restrict__ emb, unsigned char* __restrict__ idx_out,
    unsigned char* __restrict__ sflag)
{
  __shared__ double cs[KD][KD];
  __shared__ double chalf[KD];
  const int tid = threadIdx.x;
  if (tid < KD * KD) cs[tid / KD][tid % KD] = (double)cb[tid];
  __syncthreads();
  if (tid < KD) {
    double s = 0.0;
    #pragma unroll
    for (int k = 0; k < KD; ++k) s += cs[tid][k] * cs[tid][k];
    chalf[tid] = 0.5 * s;
  }
  __syncthreads();

  const int gi = blockIdx.x * 256 + tid;
  const int b = gi / NG;
  const int g = gi % NG;
  const float* zrow = z_e + (size_t)b * NH + g;
  double v[KD];
  #pragma unroll
  for (int k = 0; k < KD; ++k) v[k] = (double)zrow[k * NG];

  int best = 0; double bt = 1e300, bt2 = 1e300;
  #pragma unroll
  for (int j = 0; j < KD; ++j) {
    double t = chalf[j];
    #pragma unroll
    for (int k = 0; k < KD; ++k) t -= v[k] * cs[j][k];
    if (t < bt) { bt2 = bt; bt = t; best = j; }
    else if (t < bt2) { bt2 = t; }
  }
  float* ep = emb + (size_t)b * NH + g;
  #pragma unroll
  for (int k = 0; k < KD; ++k) ep[k * NG] = (float)cs[best][k];
  idx_out[gi] = (unsigned char)best;

  if (bt2 - bt < TAU) sflag[b] = 1;
}

__global__ __launch_bounds__(256) void compact_kernel(
    const unsigned char* __restrict__ sflag, int* __restrict__ scount,
    int* __restrict__ slist)
{
  const int i = blockIdx.x * 256 + threadIdx.x;
  if (i < NB && sflag[i]) slist[atomicAdd(scount, 1)] = i;
}

// ---------------------------------------------------------------------------
// Exact f64 repair, one sample per block (validated R6).
// ---------------------------------------------------------------------------
__global__ __launch_bounds__(256) void repair_kernel(
    const float* __restrict__ x, const float* __restrict__ W1,
    const float* __restrict__ b1, const float* __restrict__ W2,
    const float* __restrict__ b2, const float* __restrict__ cb,
    const int* __restrict__ slist, const int* __restrict__ scount,
    float* __restrict__ emb, unsigned char* __restrict__ idx_out)
{
  __shared__ double h1s[NH1];
  __shared__ double zs[NH];
  __shared__ double cs[KD][KD];
  __shared__ double chalf[KD];
  const int tid = threadIdx.x;
  const int lane = tid & 63, wv = tid >> 6;
  if (tid < KD * KD) cs[tid / KD][tid % KD] = (double)cb[tid];
  __syncthreads();
  if (tid < KD) {
    double s = 0.0;
    #pragma unroll
    for (int k = 0; k < KD; ++k) s += cs[tid][k] * cs[tid][k];
    chalf[tid] = 0.5 * s;
  }

  int S = *scount; if (S > NB) S = NB;

  for (int si = blockIdx.x; si < S; si += gridDim.x) {
    const int b = slist[si];
    double xr[4][4];
    #pragma unroll
    for (int it = 0; it < 4; ++it) {
      const int c4 = it * 64 + lane;
      if (c4 < 196) {
        float4 v = reinterpret_cast<const float4*>(x + (size_t)b * NIN)[c4];
        xr[it][0] = v.x; xr[it][1] = v.y; xr[it][2] = v.z; xr[it][3] = v.w;
      } else {
        xr[it][0] = xr[it][1] = xr[it][2] = xr[it][3] = 0.0;
      }
    }
    for (int j = wv; j < NH1; j += 4) {
      const float4* wr = reinterpret_cast<const float4*>(W1 + (size_t)j * NIN);
      double s0 = 0, s1 = 0, s2 = 0, s3 = 0;
      #pragma unroll
      for (int it = 0; it < 4; ++it) {
        const int c4 = it * 64 + lane;
        if (c4 < 196) {
          float4 w = wr[c4];
          s0 = fma(xr[it][0], (double)w.x, s0);
          s1 = fma(xr[it][1], (double)w.y, s1);
          s2 = fma(xr[it][2], (double)w.z, s2);
          s3 = fma(xr[it][3], (double)w.w, s3);
        }
      }
      double s = (s0 + s1) + (s2 + s3);
      #pragma unroll
      for (int off = 32; off > 0; off >>= 1) s += __shfl_down(s, off);
      if (lane == 0) { double h = s + (double)b1[j]; h1s[j] = h > 0.0 ? h : 0.0; }
    }
    __syncthreads();
    double hr[2][4];
    #pragma unroll
    for (int it = 0; it < 2; ++it) {
      const int c4 = it * 64 + lane;
      if (c4 < 100) {
        hr[it][0] = h1s[4 * c4 + 0]; hr[it][1] = h1s[4 * c4 + 1];
        hr[it][2] = h1s[4 * c4 + 2]; hr[it][3] = h1s[4 * c4 + 3];
      } else {
        hr[it][0] = hr[it][1] = hr[it][2] = hr[it][3] = 0.0;
      }
    }
    for (int n = wv; n < NH; n += 4) {
      const float4* wr = reinterpret_cast<const float4*>(W2 + (size_t)n * NH1);
      double s0 = 0, s1 = 0, s2 = 0, s3 = 0;
      #pragma unroll
      for (int it = 0; it < 2; ++it) {
        const int c4 = it * 64 + lane;
        if (c4 < 100) {
          float4 w = wr[c4];
          s0 = fma(hr[it][0], (double)w.x, s0);
          s1 = fma(hr[it][1], (double)w.y, s1);
          s2 = fma(hr[it][2], (double)w.z, s2);
          s3 = fma(hr[it][3], (double)w.w, s3);
        }
      }
      double s = (s0 + s1) + (s2 + s3);
      #pragma unroll
      for (int off = 32; off > 0; off >>= 1) s += __shfl_down(s, off);
      if (lane == 0) zs[n] = s + (double)b2[n];
    }
    __syncthreads();
    if (tid < NG) {
      const int g = tid;
      int best = 0; double bt = 1e300;
      #pragma unroll
      for (int j = 0; j < KD; ++j) {
        double t = chalf[j];
        #pragma unroll
        for (int k = 0; k < KD; ++k) t -= zs[k * NG + g] * cs[j][k];
        if (t < bt) { bt = t; best = j; }
      }
      idx_out[(size_t)b * NG + g] = (unsigned char)best;
      #pragma unroll
      for (int k = 0; k < KD; ++k)
        emb[(size_t)b * NH + k * NG + g] = (float)cs[best][k];
    }
    __syncthreads();
  }
}

// P[g][c][j] = sum_k cb[c][k] * W3[j][k*NG + g]
__global__ __launch_bounds__(256) void build_table(
    const float* __restrict__ cb, const float* __restrict__ W3,
    float* __restrict__ P)
{
  const int i = blockIdx.x * 256 + threadIdx.x;
  if (i >= NG * KD * NH1) return;
  const int j = i % NH1;
  const int c = (i / NH1) % KD;
  const int g = i / (NH1 * KD);
  float s = 0.f;
  #pragma unroll
  for (int k = 0; k < KD; ++k)
    s = fmaf(cb[c * KD + k], W3[(size_t)j * NH + k * NG + g], s);
  P[i] = s;
}

// h3[b][j] = relu(b3[j] + sum_g P[g][idx[b,g]][j]) -> bf16
__global__ __launch_bounds__(256) void compute_h3(
    const unsigned char* __restrict__ idx, const float* __restrict__ P,
    const float* __restrict__ b3, __hip_bfloat16* __restrict__ h3)
{
  __shared__ unsigned char sidx[64][NG];
  const int tid = threadIdx.x;
  const int b0 = blockIdx.x * 64;
  for (int t = tid; t < 64 * NG; t += 256)
    sidx[t / NG][t % NG] = idx[(size_t)b0 * NG + t];
  __syncthreads();
  for (int s = 0; s < 64; ++s) {
    for (int j = tid; j < NH1; j += 256) {
      float acc = b3[j];
      #pragma unroll
      for (int g = 0; g < NG; ++g) {
        const int c = sidx[s][g];
        acc += P[(g * KD + c) * NH1 + j];
      }
      h3[(size_t)(b0 + s) * NH1 + j] = __float2bfloat16(fmaxf(acc, 0.f));
    }
  }
}

extern "C" void kernel_launch(void* const* d_in, const int* in_sizes, int n_in,
                              void* d_out, int out_size, void* d_ws, size_t ws_size,
                              hipStream_t stream) {
  const float* x  = (const float*)d_in[0];
  const float* W1 = (const float*)d_in[1];
  const float* b1 = (const float*)d_in[2];
  const float* W2 = (const float*)d_in[3];
  const float* b2 = (const float*)d_in[4];
  const float* W3 = (const float*)d_in[5];
  const float* b3 = (const float*)d_in[6];
  const float* W4 = (const float*)d_in[7];
  const float* b4 = (const float*)d_in[8];
  const float* cb = (const float*)d_in[9];

  float* out   = (float*)d_out;
  float* recon = out;                              // NB x 784 (written last)
  float* z_e   = out + (size_t)NB * NIN;           // NB x 200
  float* emb   = z_e + (size_t)NB * NH;            // NB x 200

  unsigned short* h1_lo = (unsigned short*)emb;    // dead before quant/repair

  char* ws = (char*)d_ws;
  int*            scount = (int*)ws;                            // 4 B
  unsigned short* zp    = (unsigned short*)(ws + 256);          // 256 B zeros
  unsigned char*  sflag = (unsigned char*)(ws + 4096);          // 64 KB
  float*          P     = (float*)(ws + (1u << 20));            // 320 KB
  unsigned char*  idx   = (unsigned char*)(ws + (2u << 20));    // 1.31 MB
  int*            slist = (int*)(ws + (4u << 20));              // 256 KB
  __hip_bfloat16* W4p   = (__hip_bfloat16*)(ws + (6u << 20));   // 745 KB
  unsigned short* W1ph  = (unsigned short*)(ws + (7u << 20));   // 512x800
  unsigned short* W1pl  = (unsigned short*)(ws + (8u << 20));
  unsigned short* W2ph  = (unsigned short*)(ws + (9u << 20));   // 256x416
  unsigned short* W2pl  = (unsigned short*)(ws + (10u << 20));
  unsigned short* h1_hi = (unsigned short*)(ws + (16u << 20));  // NB x 400 bf16
  __hip_bfloat16* h3    = (__hip_bfloat16*)(ws + (16u << 20));  // reuses h1_hi (dead)

  dim3 blk(256);
  hipMemsetAsync(ws, 0, 4096 + NB, stream);   // scount + zp + sflag
  conv_w<<<(512 * 800 + 255) / 256, blk, 0, stream>>>(W1, W1ph, W1pl, 512, 800, NH1, NIN);
  conv_w<<<(256 * 416 + 255) / 256, blk, 0, stream>>>(W2, W2ph, W2pl, 256, 416, NH, NH1);
  pad_w4<<<(896 * 416 + 255) / 256, blk, 0, stream>>>(W4, W4p);

  // stage 1: h1 = relu(x @ W1^T + b1) -> split bf16 (x conversion fused)
  gemm1_fused<<<2048, blk, 0, stream>>>(x, W1ph, W1pl, b1, h1_hi, h1_lo);
  // stage 2: z_e = h1 @ W2^T + b2
  gemm2_split<<<1024, blk, 0, stream>>>(h1_hi, h1_lo, W2ph, W2pl, zp, b2, z_e);

  build_table<<<(NG * KD * NH1 + 255) / 256, blk, 0, stream>>>(cb, W3, P);
  quant_kernel<<<(NB * NG) / 256, blk, 0, stream>>>(z_e, cb, emb, idx, sflag);
  compact_kernel<<<NB / 256, blk, 0, stream>>>(sflag, scount, slist);
  repair_kernel<<<2048, blk, 0, stream>>>(x, W1, b1, W2, b2, cb, slist, scount, emb, idx);
  compute_h3<<<NB / 64, blk, 0, stream>>>(idx, P, b3, h3);
  gemm5_mfma<<<3584, blk, 0, stream>>>(h3, W4p, b4, recon);
}

// Round 8
// 825.937 us; speedup vs baseline: 3.6874x; 1.2066x over previous
//
#include <hip/hip_runtime.h>
#include <hip/hip_bf16.h>

#define NB   65536
#define KD   10
#define NG   20
#define NH   200     // KD*NG
#define NH1  400
#define NIN  784

#define TAU 3e-4     // margin below which the sample is recomputed exactly in f64

using short8 = __attribute__((ext_vector_type(8))) short;
using f32x4  = __attribute__((ext_vector_type(4))) float;

__device__ inline float bf2f(unsigned short u) {
  union { unsigned int i; float f; } x; x.i = ((unsigned int)u) << 16; return x.f;
}
__device__ inline unsigned short f2bf(float v) {
  __hip_bfloat16 b = __float2bfloat16(v);
  return *reinterpret_cast<unsigned short*>(&b);
}
__device__ inline void gload_lds16(const void* g, void* l) {
  __builtin_amdgcn_global_load_lds(
      (const __attribute__((address_space(1))) unsigned int*)g,
      (__attribute__((address_space(3))) unsigned int*)l, 16, 0, 0);
}

// ---------------------------------------------------------------------------
// Stage 1 fused + pipelined: h1 = relu(x @ W1^T + b1) -> split bf16.
// Double-buffered LDS; next-step x float4 loads and B global_load_lds are
// ISSUED before the MFMA cluster; the x split+ds_write happens AFTER the
// MFMAs (T14 issue-early/write-late), so HBM latency hides under compute.
// ---------------------------------------------------------------------------
__global__ __launch_bounds__(256) void gemm1_fused(
    const float* __restrict__ xf,
    const unsigned short* __restrict__ Bhi, const unsigned short* __restrict__ Blo,
    const float* __restrict__ bias,
    unsigned short* __restrict__ Ohi, unsigned short* __restrict__ Olo)
{
  __shared__ __align__(16) short As_hi[2][128][32];
  __shared__ __align__(16) short As_lo[2][128][32];
  __shared__ __align__(16) short Bs_hi[2][128][32];
  __shared__ __align__(16) short Bs_lo[2][128][32];
  const int tid = threadIdx.x;
  const int lane = tid & 63, wid = tid >> 6;
  const int wr = wid >> 1, wc = wid & 1;
  const int bid = blockIdx.x;
  const int sw = (bid & 7) * 256 + (bid >> 3);     // XCD-bijective swizzle
  const int n0 = (sw & 3) * 128;
  const int m0 = (sw >> 2) * 128;
  const int rr = lane >> 2, kofs = (lane & 3) * 8;
  const int arow = tid >> 3;          // 0..31
  const int acol = (tid & 7) * 4;     // 0,4,..,28

  f32x4 acc[4][4];
  #pragma unroll
  for (int i = 0; i < 4; ++i)
    #pragma unroll
    for (int j = 0; j < 4; ++j) acc[i][j] = (f32x4){0.f, 0.f, 0.f, 0.f};

  float4 va[4];

  auto loadA = [&](int ks) {
    const int k0 = ks * 32;
    #pragma unroll
    for (int p = 0; p < 4; ++p) {
      const int row = p * 32 + arow;
      const int kk = k0 + acol;
      va[p] = make_float4(0.f, 0.f, 0.f, 0.f);
      if (kk < NIN)   // 784 % 4 == 0: float4 fully valid or fully tail
        va[p] = *reinterpret_cast<const float4*>(xf + (size_t)(m0 + row) * NIN + kk);
    }
  };
  auto stageB = [&](int ks, int buf) {
    const int k0 = ks * 32;
    #pragma unroll
    for (int c = 0; c < 4; ++c) {
      const int ch = wid * 4 + c;
      if (ch < 8)
        gload_lds16(Bhi + (size_t)(n0 + ch * 16 + rr) * 800 + k0 + kofs,
                    (char*)&Bs_hi[buf][0][0] + ch * 1024);
      else
        gload_lds16(Blo + (size_t)(n0 + (ch - 8) * 16 + rr) * 800 + k0 + kofs,
                    (char*)&Bs_lo[buf][0][0] + (ch - 8) * 1024);
    }
  };
  auto writeA = [&](int buf) {
    #pragma unroll
    for (int p = 0; p < 4; ++p) {
      const int row = p * 32 + arow;
      const float4 v = va[p];
      short4 h, l;
      h.x = (short)f2bf(v.x); l.x = (short)f2bf(v.x - bf2f((unsigned short)h.x));
      h.y = (short)f2bf(v.y); l.y = (short)f2bf(v.y - bf2f((unsigned short)h.y));
      h.z = (short)f2bf(v.z); l.z = (short)f2bf(v.z - bf2f((unsigned short)h.z));
      h.w = (short)f2bf(v.w); l.w = (short)f2bf(v.w - bf2f((unsigned short)h.w));
      *reinterpret_cast<short4*>(&As_hi[buf][row][acol]) = h;
      *reinterpret_cast<short4*>(&As_lo[buf][row][acol]) = l;
    }
  };

  // prologue: fill buffer 0
  loadA(0);
  stageB(0, 0);
  writeA(0);
  __syncthreads();

  for (int ks = 0; ks < 25; ++ks) {
    const int cur = ks & 1, nxt = cur ^ 1;
    const bool more = (ks + 1 < 25);
    if (more) {
      loadA(ks + 1);       // issue x loads early (latency hides under MFMA)
      stageB(ks + 1, nxt); // issue async B staging into the other buffer
    }
    short8 ah[4], al[4], bh[4], bl[4];
    #pragma unroll
    for (int i = 0; i < 4; ++i) {
      ah[i] = *reinterpret_cast<const short8*>(&As_hi[cur][wr * 64 + i * 16 + (lane & 15)][(lane >> 4) * 8]);
      al[i] = *reinterpret_cast<const short8*>(&As_lo[cur][wr * 64 + i * 16 + (lane & 15)][(lane >> 4) * 8]);
      bh[i] = *reinterpret_cast<const short8*>(&Bs_hi[cur][wc * 64 + i * 16 + (lane & 15)][(lane >> 4) * 8]);
      bl[i] = *reinterpret_cast<const short8*>(&Bs_lo[cur][wc * 64 + i * 16 + (lane & 15)][(lane >> 4) * 8]);
    }
    #pragma unroll
    for (int i = 0; i < 4; ++i)
      #pragma unroll
      for (int j = 0; j < 4; ++j) {
        acc[i][j] = __builtin_amdgcn_mfma_f32_16x16x32_bf16(ah[i], bh[j], acc[i][j], 0, 0, 0);
        acc[i][j] = __builtin_amdgcn_mfma_f32_16x16x32_bf16(al[i], bh[j], acc[i][j], 0, 0, 0);
        acc[i][j] = __builtin_amdgcn_mfma_f32_16x16x32_bf16(ah[i], bl[j], acc[i][j], 0, 0, 0);
      }
    if (more) writeA(nxt);  // write-late: x loads have had the MFMA phase to land
    __syncthreads();
  }

  #pragma unroll
  for (int j = 0; j < 4; ++j) {
    const int n = n0 + wc * 64 + j * 16 + (lane & 15);
    if (n >= NH1) continue;
    const float bn = bias[n];
    #pragma unroll
    for (int i = 0; i < 4; ++i) {
      const int mb = m0 + wr * 64 + i * 16 + (lane >> 4) * 4;
      #pragma unroll
      for (int r = 0; r < 4; ++r) {
        float v = fmaxf(acc[i][j][r] + bn, 0.f);
        unsigned short h = f2bf(v);
        Ohi[(size_t)(mb + r) * NH1 + n] = h;
        Olo[(size_t)(mb + r) * NH1 + n] = f2bf(v - bf2f(h));
      }
    }
  }
}

// ---------------------------------------------------------------------------
// Stage 2: z_e = h1 @ W2^T + b2 (split bf16, all tiles via global_load_lds).
// ---------------------------------------------------------------------------
__global__ __launch_bounds__(256) void gemm2_split(
    const unsigned short* __restrict__ Ahi, const unsigned short* __restrict__ Alo,
    const unsigned short* __restrict__ Bhi, const unsigned short* __restrict__ Blo,
    const unsigned short* __restrict__ zp, const float* __restrict__ bias,
    float* __restrict__ Of)
{
  __shared__ __align__(16) short As_hi[128][32];
  __shared__ __align__(16) short As_lo[128][32];
  __shared__ __align__(16) short Bs_hi[128][32];
  __shared__ __align__(16) short Bs_lo[128][32];
  const int tid = threadIdx.x;
  const int lane = tid & 63, wid = tid >> 6;
  const int wr = wid >> 1, wc = wid & 1;
  const int bid = blockIdx.x;
  const int sw = (bid & 7) * 128 + (bid >> 3);
  const int n0 = (sw & 1) * 128;
  const int m0 = (sw >> 1) * 128;

  const unsigned short* G = (wid == 0) ? Ahi : (wid == 1) ? Alo
                          : (wid == 2) ? Bhi : Blo;
  short* Lt = (wid == 0) ? &As_hi[0][0] : (wid == 1) ? &As_lo[0][0]
            : (wid == 2) ? &Bs_hi[0][0] : &Bs_lo[0][0];
  const bool isA = wid < 2;
  const int rbase = isA ? m0 : n0;
  const int ld = isA ? 400 : 416;
  const int rr = lane >> 2;
  const int kofs = (lane & 3) * 8;

  f32x4 acc[4][4];
  #pragma unroll
  for (int i = 0; i < 4; ++i)
    #pragma unroll
    for (int j = 0; j < 4; ++j) acc[i][j] = (f32x4){0.f, 0.f, 0.f, 0.f};

  for (int ks = 0; ks < 13; ++ks) {
    const int k0 = ks * 32;
    #pragma unroll
    for (int c = 0; c < 8; ++c) {
      const unsigned short* src =
          G + (size_t)(rbase + c * 16 + rr) * ld + k0 + kofs;
      if (isA && (k0 + kofs >= 400)) src = zp;
      gload_lds16(src, (char*)Lt + c * 1024);
    }
    __syncthreads();
    short8 ah[4], al[4], bh[4], bl[4];
    #pragma unroll
    for (int i = 0; i < 4; ++i) {
      ah[i] = *reinterpret_cast<const short8*>(&As_hi[wr * 64 + i * 16 + (lane & 15)][(lane >> 4) * 8]);
      al[i] = *reinterpret_cast<const short8*>(&As_lo[wr * 64 + i * 16 + (lane & 15)][(lane >> 4) * 8]);
      bh[i] = *reinterpret_cast<const short8*>(&Bs_hi[wc * 64 + i * 16 + (lane & 15)][(lane >> 4) * 8]);
      bl[i] = *reinterpret_cast<const short8*>(&Bs_lo[wc * 64 + i * 16 + (lane & 15)][(lane >> 4) * 8]);
    }
    #pragma unroll
    for (int i = 0; i < 4; ++i)
      #pragma unroll
      for (int j = 0; j < 4; ++j) {
        acc[i][j] = __builtin_amdgcn_mfma_f32_16x16x32_bf16(ah[i], bh[j], acc[i][j], 0, 0, 0);
        acc[i][j] = __builtin_amdgcn_mfma_f32_16x16x32_bf16(al[i], bh[j], acc[i][j], 0, 0, 0);
        acc[i][j] = __builtin_amdgcn_mfma_f32_16x16x32_bf16(ah[i], bl[j], acc[i][j], 0, 0, 0);
      }
    __syncthreads();
  }

  #pragma unroll
  for (int j = 0; j < 4; ++j) {
    const int n = n0 + wc * 64 + j * 16 + (lane & 15);
    if (n >= NH) continue;
    const float bn = bias[n];
    #pragma unroll
    for (int i = 0; i < 4; ++i) {
      const int mb = m0 + wr * 64 + i * 16 + (lane >> 4) * 4;
      #pragma unroll
      for (int r = 0; r < 4; ++r)
        Of[(size_t)(mb + r) * NH + n] = acc[i][j][r] + bn;
    }
  }
}

// ---------------------------------------------------------------------------
// Stage 5: recon = tanh(h3(bf16) @ W4p^T + b4). 3584 blocks, 448/XCD.
// ---------------------------------------------------------------------------
__global__ __launch_bounds__(256) void gemm5_mfma(
    const __hip_bfloat16* __restrict__ A,   // h3: NB x 400
    const __hip_bfloat16* __restrict__ Bp,  // W4p: 896 x 416
    const float* __restrict__ bias, float* __restrict__ C)
{
  __shared__ __align__(16) short As[128][32];
  __shared__ __align__(16) short Bs[128][32];
  const int tid = threadIdx.x;
  const int lane = tid & 63, wid = tid >> 6;
  const int wr = wid >> 1, wc = wid & 1;
  const int bid = blockIdx.x;
  const int sw = (bid & 7) * 448 + (bid >> 3);
  const int n0 = (sw % 7) * 128;
  const int m0 = (sw / 7) * 128;
  const int srow = lane >> 2;
  const int skp  = (lane & 3) * 8;
  const short* Ag = (const short*)A;
  const short* Bg = (const short*)Bp;
  f32x4 acc[4][4];
  #pragma unroll
  for (int i = 0; i < 4; ++i)
    #pragma unroll
    for (int j = 0; j < 4; ++j) acc[i][j] = (f32x4){0.f, 0.f, 0.f, 0.f};

  for (int k0 = 0; k0 < 416; k0 += 32) {
    #pragma unroll
    for (int c = 0; c < 2; ++c) {
      const int row = c * 64 + wid * 16 + srow;
      gload_lds16(Ag + (size_t)(m0 + row) * 400 + k0 + skp,
                  (char*)&As[0][0] + c * 4096 + wid * 1024);
      gload_lds16(Bg + (size_t)(n0 + row) * 416 + k0 + skp,
                  (char*)&Bs[0][0] + c * 4096 + wid * 1024);
    }
    __syncthreads();
    short8 af[4], bf[4];
    #pragma unroll
    for (int i = 0; i < 4; ++i)
      af[i] = *reinterpret_cast<const short8*>(&As[wr * 64 + i * 16 + (lane & 15)][(lane >> 4) * 8]);
    #pragma unroll
    for (int j = 0; j < 4; ++j)
      bf[j] = *reinterpret_cast<const short8*>(&Bs[wc * 64 + j * 16 + (lane & 15)][(lane >> 4) * 8]);
    #pragma unroll
    for (int i = 0; i < 4; ++i)
      #pragma unroll
      for (int j = 0; j < 4; ++j)
        acc[i][j] = __builtin_amdgcn_mfma_f32_16x16x32_bf16(af[i], bf[j], acc[i][j], 0, 0, 0);
    __syncthreads();
  }

  #pragma unroll
  for (int j = 0; j < 4; ++j) {
    const int n = n0 + wc * 64 + j * 16 + (lane & 15);
    if (n >= NIN) continue;
    const float bn = bias[n];
    #pragma unroll
    for (int i = 0; i < 4; ++i) {
      const int mb = m0 + wr * 64 + i * 16 + (lane >> 4) * 4;
      #pragma unroll
      for (int r = 0; r < 4; ++r)
        C[(size_t)(mb + r) * NIN + n] = tanhf(acc[i][j][r] + bn);
    }
  }
}

// -------------------------- converters / padders ---------------------------
__global__ __launch_bounds__(256) void conv_w(
    const float* __restrict__ W, unsigned short* __restrict__ Wh,
    unsigned short* __restrict__ Wl, int NP, int KP, int N, int K)
{
  const int i = blockIdx.x * 256 + threadIdx.x;
  if (i >= NP * KP) return;
  const int n = i / KP, k = i % KP;
  const float v = (n < N && k < K) ? W[(size_t)n * K + k] : 0.f;
  const unsigned short h = f2bf(v);
  Wh[i] = h;
  Wl[i] = f2bf(v - bf2f(h));
}

__global__ __launch_bounds__(256) void pad_w4(
    const float* __restrict__ W4, __hip_bfloat16* __restrict__ W4p)
{
  const int i = blockIdx.x * 256 + threadIdx.x;
  if (i >= 896 * 416) return;
  const int n = i / 416, k = i % 416;
  const float v = (n < NIN && k < NH1) ? W4[(size_t)n * NH1 + k] : 0.f;
  W4p[i] = __float2bfloat16(v);
}

// ---------------------------------------------------------------------------
// Quantization: f64 distances from fast z_e; margin < TAU -> flag the SAMPLE.
// ---------------------------------------------------------------------------
__global__ __launch_bounds__(256) void quant_kernel(
    const float* __restrict__ z_e, const float* __restrict__ cb,
    float* __restrict__ emb, unsigned char* __restrict__ idx_out,
    unsigned char* __restrict__ sflag)
{
  __shared__ double cs[KD][KD];
  __shared__ double chalf[KD];
  const int tid = threadIdx.x;
  if (tid < KD * KD) cs[tid / KD][tid % KD] = (double)cb[tid];
  __syncthreads();
  if (tid < KD) {
    double s = 0.0;
    #pragma unroll
    for (int k = 0; k < KD; ++k) s += cs[tid][k] * cs[tid][k];
    chalf[tid] = 0.5 * s;
  }
  __syncthreads();

  const int gi = blockIdx.x * 256 + tid;
  const int b = gi / NG;
  const int g = gi % NG;
  const float* zrow = z_e + (size_t)b * NH + g;
  double v[KD];
  #pragma unroll
  for (int k = 0; k < KD; ++k) v[k] = (double)zrow[k * NG];

  int best = 0; double bt = 1e300, bt2 = 1e300;
  #pragma unroll
  for (int j = 0; j < KD; ++j) {
    double t = chalf[j];
    #pragma unroll
    for (int k = 0; k < KD; ++k) t -= v[k] * cs[j][k];
    if (t < bt) { bt2 = bt; bt = t; best = j; }
    else if (t < bt2) { bt2 = t; }
  }
  float* ep = emb + (size_t)b * NH + g;
  #pragma unroll
  for (int k = 0; k < KD; ++k) ep[k * NG] = (float)cs[best][k];
  idx_out[gi] = (unsigned char)best;

  if (bt2 - bt < TAU) sflag[b] = 1;
}

__global__ __launch_bounds__(256) void compact_kernel(
    const unsigned char* __restrict__ sflag, int* __restrict__ scount,
    int* __restrict__ slist)
{
  const int i = blockIdx.x * 256 + threadIdx.x;
  if (i < NB && sflag[i]) slist[atomicAdd(scount, 1)] = i;
}

// ---------------------------------------------------------------------------
// Exact f64 repair, one sample per block (validated R6).
// ---------------------------------------------------------------------------
__global__ __launch_bounds__(256) void repair_kernel(
    const float* __restrict__ x, const float* __restrict__ W1,
    const float* __restrict__ b1, const float* __restrict__ W2,
    const float* __restrict__ b2, const float* __restrict__ cb,
    const int* __restrict__ slist, const int* __restrict__ scount,
    float* __restrict__ emb, unsigned char* __restrict__ idx_out)
{
  __shared__ double h1s[NH1];
  __shared__ double zs[NH];
  __shared__ double cs[KD][KD];
  __shared__ double chalf[KD];
  const int tid = threadIdx.x;
  const int lane = tid & 63, wv = tid >> 6;
  if (tid < KD * KD) cs[tid / KD][tid % KD] = (double)cb[tid];
  __syncthreads();
  if (tid < KD) {
    double s = 0.0;
    #pragma unroll
    for (int k = 0; k < KD; ++k) s += cs[tid][k] * cs[tid][k];
    chalf[tid] = 0.5 * s;
  }

  int S = *scount; if (S > NB) S = NB;

  for (int si = blockIdx.x; si < S; si += gridDim.x) {
    const int b = slist[si];
    double xr[4][4];
    #pragma unroll
    for (int it = 0; it < 4; ++it) {
      const int c4 = it * 64 + lane;
      if (c4 < 196) {
        float4 v = reinterpret_cast<const float4*>(x + (size_t)b * NIN)[c4];
        xr[it][0] = v.x; xr[it][1] = v.y; xr[it][2] = v.z; xr[it][3] = v.w;
      } else {
        xr[it][0] = xr[it][1] = xr[it][2] = xr[it][3] = 0.0;
      }
    }
    for (int j = wv; j < NH1; j += 4) {
      const float4* wr = reinterpret_cast<const float4*>(W1 + (size_t)j * NIN);
      double s0 = 0, s1 = 0, s2 = 0, s3 = 0;
      #pragma unroll
      for (int it = 0; it < 4; ++it) {
        const int c4 = it * 64 + lane;
        if (c4 < 196) {
          float4 w = wr[c4];
          s0 = fma(xr[it][0], (double)w.x, s0);
          s1 = fma(xr[it][1], (double)w.y, s1);
          s2 = fma(xr[it][2], (double)w.z, s2);
          s3 = fma(xr[it][3], (double)w.w, s3);
        }
      }
      double s = (s0 + s1) + (s2 + s3);
      #pragma unroll
      for (int off = 32; off > 0; off >>= 1) s += __shfl_down(s, off);
      if (lane == 0) { double h = s + (double)b1[j]; h1s[j] = h > 0.0 ? h : 0.0; }
    }
    __syncthreads();
    double hr[2][4];
    #pragma unroll
    for (int it = 0; it < 2; ++it) {
      const int c4 = it * 64 + lane;
      if (c4 < 100) {
        hr[it][0] = h1s[4 * c4 + 0]; hr[it][1] = h1s[4 * c4 + 1];
        hr[it][2] = h1s[4 * c4 + 2]; hr[it][3] = h1s[4 * c4 + 3];
      } else {
        hr[it][0] = hr[it][1] = hr[it][2] = hr[it][3] = 0.0;
      }
    }
    for (int n = wv; n < NH; n += 4) {
      const float4* wr = reinterpret_cast<const float4*>(W2 + (size_t)n * NH1);
      double s0 = 0, s1 = 0, s2 = 0, s3 = 0;
      #pragma unroll
      for (int it = 0; it < 2; ++it) {
        const int c4 = it * 64 + lane;
        if (c4 < 100) {
          float4 w = wr[c4];
          s0 = fma(hr[it][0], (double)w.x, s0);
          s1 = fma(hr[it][1], (double)w.y, s1);
          s2 = fma(hr[it][2], (double)w.z, s2);
          s3 = fma(hr[it][3], (double)w.w, s3);
        }
      }
      double s = (s0 + s1) + (s2 + s3);
      #pragma unroll
      for (int off = 32; off > 0; off >>= 1) s += __shfl_down(s, off);
      if (lane == 0) zs[n] = s + (double)b2[n];
    }
    __syncthreads();
    if (tid < NG) {
      const int g = tid;
      int best = 0; double bt = 1e300;
      #pragma unroll
      for (int j = 0; j < KD; ++j) {
        double t = chalf[j];
        #pragma unroll
        for (int k = 0; k < KD; ++k) t -= zs[k * NG + g] * cs[j][k];
        if (t < bt) { bt = t; best = j; }
      }
      idx_out[(size_t)b * NG + g] = (unsigned char)best;
      #pragma unroll
      for (int k = 0; k < KD; ++k)
        emb[(size_t)b * NH + k * NG + g] = (float)cs[best][k];
    }
    __syncthreads();
  }
}

// P[g][c][j] = sum_k cb[c][k] * W3[j][k*NG + g]
__global__ __launch_bounds__(256) void build_table(
    const float* __restrict__ cb, const float* __restrict__ W3,
    float* __restrict__ P)
{
  const int i = blockIdx.x * 256 + threadIdx.x;
  if (i >= NG * KD * NH1) return;
  const int j = i % NH1;
  const int c = (i / NH1) % KD;
  const int g = i / (NH1 * KD);
  float s = 0.f;
  #pragma unroll
  for (int k = 0; k < KD; ++k)
    s = fmaf(cb[c * KD + k], W3[(size_t)j * NH + k * NG + g], s);
  P[i] = s;
}

// h3[b][j] = relu(b3[j] + sum_g P[g][idx[b,g]][j]) -> bf16
__global__ __launch_bounds__(256) void compute_h3(
    const unsigned char* __restrict__ idx, const float* __restrict__ P,
    const float* __restrict__ b3, __hip_bfloat16* __restrict__ h3)
{
  __shared__ unsigned char sidx[64][NG];
  const int tid = threadIdx.x;
  const int b0 = blockIdx.x * 64;
  for (int t = tid; t < 64 * NG; t += 256)
    sidx[t / NG][t % NG] = idx[(size_t)b0 * NG + t];
  __syncthreads();
  for (int s = 0; s < 64; ++s) {
    for (int j = tid; j < NH1; j += 256) {
      float acc = b3[j];
      #pragma unroll
      for (int g = 0; g < NG; ++g) {
        const int c = sidx[s][g];
        acc += P[(g * KD + c) * NH1 + j];
      }
      h3[(size_t)(b0 + s) * NH1 + j] = __float2bfloat16(fmaxf(acc, 0.f));
    }
  }
}

extern "C" void kernel_launch(void* const* d_in, const int* in_sizes, int n_in,
                              void* d_out, int out_size, void* d_ws, size_t ws_size,
                              hipStream_t stream) {
  const float* x  = (const float*)d_in[0];
  const float* W1 = (const float*)d_in[1];
  const float* b1 = (const float*)d_in[2];
  const float* W2 = (const float*)d_in[3];
  const float* b2 = (const float*)d_in[4];
  const float* W3 = (const float*)d_in[5];
  const float* b3 = (const float*)d_in[6];
  const float* W4 = (const float*)d_in[7];
  const float* b4 = (const float*)d_in[8];
  const float* cb = (const float*)d_in[9];

  float* out   = (float*)d_out;
  float* recon = out;                              // NB x 784 (written last)
  float* z_e   = out + (size_t)NB * NIN;           // NB x 200
  float* emb   = z_e + (size_t)NB * NH;            // NB x 200

  unsigned short* h1_lo = (unsigned short*)emb;    // dead before quant/repair

  char* ws = (char*)d_ws;
  int*            scount = (int*)ws;                            // 4 B
  unsigned short* zp    = (unsigned short*)(ws + 256);          // 256 B zeros
  unsigned char*  sflag = (unsigned char*)(ws + 4096);          // 64 KB
  float*          P     = (float*)(ws + (1u << 20));            // 320 KB
  unsigned char*  idx   = (unsigned char*)(ws + (2u << 20));    // 1.31 MB
  int*            slist = (int*)(ws + (4u << 20));              // 256 KB
  __hip_bfloat16* W4p   = (__hip_bfloat16*)(ws + (6u << 20));   // 745 KB
  unsigned short* W1ph  = (unsigned short*)(ws + (7u << 20));   // 512x800
  unsigned short* W1pl  = (unsigned short*)(ws + (8u << 20));
  unsigned short* W2ph  = (unsigned short*)(ws + (9u << 20));   // 256x416
  unsigned short* W2pl  = (unsigned short*)(ws + (10u << 20));
  unsigned short* h1_hi = (unsigned short*)(ws + (16u << 20));  // NB x 400 bf16
  __hip_bfloat16* h3    = (__hip_bfloat16*)(ws + (16u << 20));  // reuses h1_hi (dead)

  dim3 blk(256);
  hipMemsetAsync(ws, 0, 4096 + NB, stream);   // scount + zp + sflag
  conv_w<<<(512 * 800 + 255) / 256, blk, 0, stream>>>(W1, W1ph, W1pl, 512, 800, NH1, NIN);
  conv_w<<<(256 * 416 + 255) / 256, blk, 0, stream>>>(W2, W2ph, W2pl, 256, 416, NH, NH1);
  pad_w4<<<(896 * 416 + 255) / 256, blk, 0, stream>>>(W4, W4p);

  // stage 1: h1 = relu(x @ W1^T + b1) -> split bf16 (x conversion fused, pipelined)
  gemm1_fused<<<2048, blk, 0, stream>>>(x, W1ph, W1pl, b1, h1_hi, h1_lo);
  // stage 2: z_e = h1 @ W2^T + b2
  gemm2_split<<<1024, blk, 0, stream>>>(h1_hi, h1_lo, W2ph, W2pl, zp, b2, z_e);

  build_table<<<(NG * KD * NH1 + 255) / 256, blk, 0, stream>>>(cb, W3, P);
  quant_kernel<<<(NB * NG) / 256, blk, 0, stream>>>(z_e, cb, emb, idx, sflag);
  compact_kernel<<<NB / 256, blk, 0, stream>>>(sflag, scount, slist);
  repair_kernel<<<2048, blk, 0, stream>>>(x, W1, b1, W2, b2, cb, slist, scount, emb, idx);
  compute_h3<<<NB / 64, blk, 0, stream>>>(idx, P, b3, h3);
  gemm5_mfma<<<3584, blk, 0, stream>>>(h3, W4p, b4, recon);
}

// Round 9
// 600.973 us; speedup vs baseline: 5.0677x; 1.3743x over previous
//
#include <hip/hip_runtime.h>
#include <hip/hip_bf16.h>

#define NB   65536
#define KD   10
#define NG   20
#define NH   200     // KD*NG
#define NH1  400
#define NIN  784

#define TAU 3e-4     // margin below which the sample is recomputed exactly in f64

using short8 = __attribute__((ext_vector_type(8))) short;
using f32x4  = __attribute__((ext_vector_type(4))) float;

__device__ inline float bf2f(unsigned short u) {
  union { unsigned int i; float f; } x; x.i = ((unsigned int)u) << 16; return x.f;
}
__device__ inline unsigned short f2bf(float v) {
  __hip_bfloat16 b = __float2bfloat16(v);
  return *reinterpret_cast<unsigned short*>(&b);
}
__device__ inline void gload_lds16(const void* g, void* l) {
  __builtin_amdgcn_global_load_lds(
      (const __attribute__((address_space(1))) unsigned int*)g,
      (__attribute__((address_space(3))) unsigned int*)l, 16, 0, 0);
}

// ---------------------------------------------------------------------------
// Stage 1 fused + pipelined (validated R8): h1 = relu(x @ W1^T + b1) -> split.
// ---------------------------------------------------------------------------
__global__ __launch_bounds__(256) void gemm1_fused(
    const float* __restrict__ xf,
    const unsigned short* __restrict__ Bhi, const unsigned short* __restrict__ Blo,
    const float* __restrict__ bias,
    unsigned short* __restrict__ Ohi, unsigned short* __restrict__ Olo)
{
  __shared__ __align__(16) short As_hi[2][128][32];
  __shared__ __align__(16) short As_lo[2][128][32];
  __shared__ __align__(16) short Bs_hi[2][128][32];
  __shared__ __align__(16) short Bs_lo[2][128][32];
  const int tid = threadIdx.x;
  const int lane = tid & 63, wid = tid >> 6;
  const int wr = wid >> 1, wc = wid & 1;
  const int bid = blockIdx.x;
  const int sw = (bid & 7) * 256 + (bid >> 3);     // XCD-bijective swizzle
  const int n0 = (sw & 3) * 128;
  const int m0 = (sw >> 2) * 128;
  const int rr = lane >> 2, kofs = (lane & 3) * 8;
  const int arow = tid >> 3;
  const int acol = (tid & 7) * 4;

  f32x4 acc[4][4];
  #pragma unroll
  for (int i = 0; i < 4; ++i)
    #pragma unroll
    for (int j = 0; j < 4; ++j) acc[i][j] = (f32x4){0.f, 0.f, 0.f, 0.f};

  float4 va[4];

  auto loadA = [&](int ks) {
    const int k0 = ks * 32;
    #pragma unroll
    for (int p = 0; p < 4; ++p) {
      const int row = p * 32 + arow;
      const int kk = k0 + acol;
      va[p] = make_float4(0.f, 0.f, 0.f, 0.f);
      if (kk < NIN)
        va[p] = *reinterpret_cast<const float4*>(xf + (size_t)(m0 + row) * NIN + kk);
    }
  };
  auto stageB = [&](int ks, int buf) {
    const int k0 = ks * 32;
    #pragma unroll
    for (int c = 0; c < 4; ++c) {
      const int ch = wid * 4 + c;
      if (ch < 8)
        gload_lds16(Bhi + (size_t)(n0 + ch * 16 + rr) * 800 + k0 + kofs,
                    (char*)&Bs_hi[buf][0][0] + ch * 1024);
      else
        gload_lds16(Blo + (size_t)(n0 + (ch - 8) * 16 + rr) * 800 + k0 + kofs,
                    (char*)&Bs_lo[buf][0][0] + (ch - 8) * 1024);
    }
  };
  auto writeA = [&](int buf) {
    #pragma unroll
    for (int p = 0; p < 4; ++p) {
      const int row = p * 32 + arow;
      const float4 v = va[p];
      short4 h, l;
      h.x = (short)f2bf(v.x); l.x = (short)f2bf(v.x - bf2f((unsigned short)h.x));
      h.y = (short)f2bf(v.y); l.y = (short)f2bf(v.y - bf2f((unsigned short)h.y));
      h.z = (short)f2bf(v.z); l.z = (short)f2bf(v.z - bf2f((unsigned short)h.z));
      h.w = (short)f2bf(v.w); l.w = (short)f2bf(v.w - bf2f((unsigned short)h.w));
      *reinterpret_cast<short4*>(&As_hi[buf][row][acol]) = h;
      *reinterpret_cast<short4*>(&As_lo[buf][row][acol]) = l;
    }
  };

  loadA(0);
  stageB(0, 0);
  writeA(0);
  __syncthreads();

  for (int ks = 0; ks < 25; ++ks) {
    const int cur = ks & 1, nxt = cur ^ 1;
    const bool more = (ks + 1 < 25);
    if (more) {
      loadA(ks + 1);
      stageB(ks + 1, nxt);
    }
    short8 ah[4], al[4], bh[4], bl[4];
    #pragma unroll
    for (int i = 0; i < 4; ++i) {
      ah[i] = *reinterpret_cast<const short8*>(&As_hi[cur][wr * 64 + i * 16 + (lane & 15)][(lane >> 4) * 8]);
      al[i] = *reinterpret_cast<const short8*>(&As_lo[cur][wr * 64 + i * 16 + (lane & 15)][(lane >> 4) * 8]);
      bh[i] = *reinterpret_cast<const short8*>(&Bs_hi[cur][wc * 64 + i * 16 + (lane & 15)][(lane >> 4) * 8]);
      bl[i] = *reinterpret_cast<const short8*>(&Bs_lo[cur][wc * 64 + i * 16 + (lane & 15)][(lane >> 4) * 8]);
    }
    #pragma unroll
    for (int i = 0; i < 4; ++i)
      #pragma unroll
      for (int j = 0; j < 4; ++j) {
        acc[i][j] = __builtin_amdgcn_mfma_f32_16x16x32_bf16(ah[i], bh[j], acc[i][j], 0, 0, 0);
        acc[i][j] = __builtin_amdgcn_mfma_f32_16x16x32_bf16(al[i], bh[j], acc[i][j], 0, 0, 0);
        acc[i][j] = __builtin_amdgcn_mfma_f32_16x16x32_bf16(ah[i], bl[j], acc[i][j], 0, 0, 0);
      }
    if (more) writeA(nxt);
    __syncthreads();
  }

  #pragma unroll
  for (int j = 0; j < 4; ++j) {
    const int n = n0 + wc * 64 + j * 16 + (lane & 15);
    if (n >= NH1) continue;
    const float bn = bias[n];
    #pragma unroll
    for (int i = 0; i < 4; ++i) {
      const int mb = m0 + wr * 64 + i * 16 + (lane >> 4) * 4;
      #pragma unroll
      for (int r = 0; r < 4; ++r) {
        float v = fmaxf(acc[i][j][r] + bn, 0.f);
        unsigned short h = f2bf(v);
        Ohi[(size_t)(mb + r) * NH1 + n] = h;
        Olo[(size_t)(mb + r) * NH1 + n] = f2bf(v - bf2f(h));
      }
    }
  }
}

// ---------------------------------------------------------------------------
// Stage 2: z_e = h1 @ W2^T + b2 (split bf16, validated R7).
// ---------------------------------------------------------------------------
__global__ __launch_bounds__(256) void gemm2_split(
    const unsigned short* __restrict__ Ahi, const unsigned short* __restrict__ Alo,
    const unsigned short* __restrict__ Bhi, const unsigned short* __restrict__ Blo,
    const unsigned short* __restrict__ zp, const float* __restrict__ bias,
    float* __restrict__ Of)
{
  __shared__ __align__(16) short As_hi[128][32];
  __shared__ __align__(16) short As_lo[128][32];
  __shared__ __align__(16) short Bs_hi[128][32];
  __shared__ __align__(16) short Bs_lo[128][32];
  const int tid = threadIdx.x;
  const int lane = tid & 63, wid = tid >> 6;
  const int wr = wid >> 1, wc = wid & 1;
  const int bid = blockIdx.x;
  const int sw = (bid & 7) * 128 + (bid >> 3);
  const int n0 = (sw & 1) * 128;
  const int m0 = (sw >> 1) * 128;

  const unsigned short* G = (wid == 0) ? Ahi : (wid == 1) ? Alo
                          : (wid == 2) ? Bhi : Blo;
  short* Lt = (wid == 0) ? &As_hi[0][0] : (wid == 1) ? &As_lo[0][0]
            : (wid == 2) ? &Bs_hi[0][0] : &Bs_lo[0][0];
  const bool isA = wid < 2;
  const int rbase = isA ? m0 : n0;
  const int ld = isA ? 400 : 416;
  const int rr = lane >> 2;
  const int kofs = (lane & 3) * 8;

  f32x4 acc[4][4];
  #pragma unroll
  for (int i = 0; i < 4; ++i)
    #pragma unroll
    for (int j = 0; j < 4; ++j) acc[i][j] = (f32x4){0.f, 0.f, 0.f, 0.f};

  for (int ks = 0; ks < 13; ++ks) {
    const int k0 = ks * 32;
    #pragma unroll
    for (int c = 0; c < 8; ++c) {
      const unsigned short* src =
          G + (size_t)(rbase + c * 16 + rr) * ld + k0 + kofs;
      if (isA && (k0 + kofs >= 400)) src = zp;
      gload_lds16(src, (char*)Lt + c * 1024);
    }
    __syncthreads();
    short8 ah[4], al[4], bh[4], bl[4];
    #pragma unroll
    for (int i = 0; i < 4; ++i) {
      ah[i] = *reinterpret_cast<const short8*>(&As_hi[wr * 64 + i * 16 + (lane & 15)][(lane >> 4) * 8]);
      al[i] = *reinterpret_cast<const short8*>(&As_lo[wr * 64 + i * 16 + (lane & 15)][(lane >> 4) * 8]);
      bh[i] = *reinterpret_cast<const short8*>(&Bs_hi[wc * 64 + i * 16 + (lane & 15)][(lane >> 4) * 8]);
      bl[i] = *reinterpret_cast<const short8*>(&Bs_lo[wc * 64 + i * 16 + (lane & 15)][(lane >> 4) * 8]);
    }
    #pragma unroll
    for (int i = 0; i < 4; ++i)
      #pragma unroll
      for (int j = 0; j < 4; ++j) {
        acc[i][j] = __builtin_amdgcn_mfma_f32_16x16x32_bf16(ah[i], bh[j], acc[i][j], 0, 0, 0);
        acc[i][j] = __builtin_amdgcn_mfma_f32_16x16x32_bf16(al[i], bh[j], acc[i][j], 0, 0, 0);
        acc[i][j] = __builtin_amdgcn_mfma_f32_16x16x32_bf16(ah[i], bl[j], acc[i][j], 0, 0, 0);
      }
    __syncthreads();
  }

  #pragma unroll
  for (int j = 0; j < 4; ++j) {
    const int n = n0 + wc * 64 + j * 16 + (lane & 15);
    if (n >= NH) continue;
    const float bn = bias[n];
    #pragma unroll
    for (int i = 0; i < 4; ++i) {
      const int mb = m0 + wr * 64 + i * 16 + (lane >> 4) * 4;
      #pragma unroll
      for (int r = 0; r < 4; ++r)
        Of[(size_t)(mb + r) * NH + n] = acc[i][j][r] + bn;
    }
  }
}

// ---------------------------------------------------------------------------
// Stage 3 (NEW): h3 = relu(emb_bf @ W3p^T + b3) -> bf16. MFMA, gemm5 clone.
// W3p padded to 512x224 zeros; A K-spill (k>=200) multiplies zero pad.
// ---------------------------------------------------------------------------
__global__ __launch_bounds__(256) void gemm3_mfma(
    const unsigned short* __restrict__ A,   // emb_bf: NB x 200
    const __hip_bfloat16* __restrict__ Bp,  // W3p: 512 x 224
    const float* __restrict__ bias, __hip_bfloat16* __restrict__ H3)
{
  __shared__ __align__(16) short As[128][32];
  __shared__ __align__(16) short Bs[128][32];
  const int tid = threadIdx.x;
  const int lane = tid & 63, wid = tid >> 6;
  const int wr = wid >> 1, wc = wid & 1;
  const int bid = blockIdx.x;
  const int sw = (bid & 7) * 256 + (bid >> 3);   // 2048 blocks
  const int n0 = (sw & 3) * 128;
  const int m0 = (sw >> 2) * 128;
  const int srow = lane >> 2;
  const int skp  = (lane & 3) * 8;
  const short* Ag = (const short*)A;
  const short* Bg = (const short*)Bp;
  f32x4 acc[4][4];
  #pragma unroll
  for (int i = 0; i < 4; ++i)
    #pragma unroll
    for (int j = 0; j < 4; ++j) acc[i][j] = (f32x4){0.f, 0.f, 0.f, 0.f};

  for (int k0 = 0; k0 < 224; k0 += 32) {
    #pragma unroll
    for (int c = 0; c < 2; ++c) {
      const int row = c * 64 + wid * 16 + srow;
      gload_lds16(Ag + (size_t)(m0 + row) * 200 + k0 + skp,
                  (char*)&As[0][0] + c * 4096 + wid * 1024);
      gload_lds16(Bg + (size_t)(n0 + row) * 224 + k0 + skp,
                  (char*)&Bs[0][0] + c * 4096 + wid * 1024);
    }
    __syncthreads();
    short8 af[4], bf[4];
    #pragma unroll
    for (int i = 0; i < 4; ++i)
      af[i] = *reinterpret_cast<const short8*>(&As[wr * 64 + i * 16 + (lane & 15)][(lane >> 4) * 8]);
    #pragma unroll
    for (int j = 0; j < 4; ++j)
      bf[j] = *reinterpret_cast<const short8*>(&Bs[wc * 64 + j * 16 + (lane & 15)][(lane >> 4) * 8]);
    #pragma unroll
    for (int i = 0; i < 4; ++i)
      #pragma unroll
      for (int j = 0; j < 4; ++j)
        acc[i][j] = __builtin_amdgcn_mfma_f32_16x16x32_bf16(af[i], bf[j], acc[i][j], 0, 0, 0);
    __syncthreads();
  }

  #pragma unroll
  for (int j = 0; j < 4; ++j) {
    const int n = n0 + wc * 64 + j * 16 + (lane & 15);
    if (n >= NH1) continue;
    const float bn = bias[n];
    #pragma unroll
    for (int i = 0; i < 4; ++i) {
      const int mb = m0 + wr * 64 + i * 16 + (lane >> 4) * 4;
      #pragma unroll
      for (int r = 0; r < 4; ++r)
        H3[(size_t)(mb + r) * NH1 + n] = __float2bfloat16(fmaxf(acc[i][j][r] + bn, 0.f));
    }
  }
}

// ---------------------------------------------------------------------------
// Stage 5: recon = tanh(h3(bf16) @ W4p^T + b4). MFMA (validated R3-R7).
// ---------------------------------------------------------------------------
__global__ __launch_bounds__(256) void gemm5_mfma(
    const __hip_bfloat16* __restrict__ A,   // h3: NB x 400
    const __hip_bfloat16* __restrict__ Bp,  // W4p: 896 x 416
    const float* __restrict__ bias, float* __restrict__ C)
{
  __shared__ __align__(16) short As[128][32];
  __shared__ __align__(16) short Bs[128][32];
  const int tid = threadIdx.x;
  const int lane = tid & 63, wid = tid >> 6;
  const int wr = wid >> 1, wc = wid & 1;
  const int bid = blockIdx.x;
  const int sw = (bid & 7) * 448 + (bid >> 3);
  const int n0 = (sw % 7) * 128;
  const int m0 = (sw / 7) * 128;
  const int srow = lane >> 2;
  const int skp  = (lane & 3) * 8;
  const short* Ag = (const short*)A;
  const short* Bg = (const short*)Bp;
  f32x4 acc[4][4];
  #pragma unroll
  for (int i = 0; i < 4; ++i)
    #pragma unroll
    for (int j = 0; j < 4; ++j) acc[i][j] = (f32x4){0.f, 0.f, 0.f, 0.f};

  for (int k0 = 0; k0 < 416; k0 += 32) {
    #pragma unroll
    for (int c = 0; c < 2; ++c) {
      const int row = c * 64 + wid * 16 + srow;
      gload_lds16(Ag + (size_t)(m0 + row) * 400 + k0 + skp,
                  (char*)&As[0][0] + c * 4096 + wid * 1024);
      gload_lds16(Bg + (size_t)(n0 + row) * 416 + k0 + skp,
                  (char*)&Bs[0][0] + c * 4096 + wid * 1024);
    }
    __syncthreads();
    short8 af[4], bf[4];
    #pragma unroll
    for (int i = 0; i < 4; ++i)
      af[i] = *reinterpret_cast<const short8*>(&As[wr * 64 + i * 16 + (lane & 15)][(lane >> 4) * 8]);
    #pragma unroll
    for (int j = 0; j < 4; ++j)
      bf[j] = *reinterpret_cast<const short8*>(&Bs[wc * 64 + j * 16 + (lane & 15)][(lane >> 4) * 8]);
    #pragma unroll
    for (int i = 0; i < 4; ++i)
      #pragma unroll
      for (int j = 0; j < 4; ++j)
        acc[i][j] = __builtin_amdgcn_mfma_f32_16x16x32_bf16(af[i], bf[j], acc[i][j], 0, 0, 0);
    __syncthreads();
  }

  #pragma unroll
  for (int j = 0; j < 4; ++j) {
    const int n = n0 + wc * 64 + j * 16 + (lane & 15);
    if (n >= NIN) continue;
    const float bn = bias[n];
    #pragma unroll
    for (int i = 0; i < 4; ++i) {
      const int mb = m0 + wr * 64 + i * 16 + (lane >> 4) * 4;
      #pragma unroll
      for (int r = 0; r < 4; ++r)
        C[(size_t)(mb + r) * NIN + n] = tanhf(acc[i][j][r] + bn);
    }
  }
}

// -------------------------- converters / padders ---------------------------
__global__ __launch_bounds__(256) void conv_w(
    const float* __restrict__ W, unsigned short* __restrict__ Wh,
    unsigned short* __restrict__ Wl, int NP, int KP, int N, int K)
{
  const int i = blockIdx.x * 256 + threadIdx.x;
  if (i >= NP * KP) return;
  const int n = i / KP, k = i % KP;
  const float v = (n < N && k < K) ? W[(size_t)n * K + k] : 0.f;
  const unsigned short h = f2bf(v);
  Wh[i] = h;
  Wl[i] = f2bf(v - bf2f(h));
}

__global__ __launch_bounds__(256) void pad_w4(
    const float* __restrict__ W4, __hip_bfloat16* __restrict__ W4p)
{
  const int i = blockIdx.x * 256 + threadIdx.x;
  if (i >= 896 * 416) return;
  const int n = i / 416, k = i % 416;
  const float v = (n < NIN && k < NH1) ? W4[(size_t)n * NH1 + k] : 0.f;
  W4p[i] = __float2bfloat16(v);
}

__global__ __launch_bounds__(256) void pad_w3(
    const float* __restrict__ W3, __hip_bfloat16* __restrict__ W3p)
{
  const int i = blockIdx.x * 256 + threadIdx.x;
  if (i >= 512 * 224) return;
  const int n = i / 224, k = i % 224;
  const float v = (n < NH1 && k < NH) ? W3[(size_t)n * NH + k] : 0.f;
  W3p[i] = __float2bfloat16(v);
}

// ---------------------------------------------------------------------------
// Quantization: f64 distances from fast z_e; margin < TAU -> flag the SAMPLE.
// Writes emb (f32 output) and emb_bf (bf16 for gemm3).
// ---------------------------------------------------------------------------
__global__ __launch_bounds__(256) void quant_kernel(
    const float* __restrict__ z_e, const float* __restrict__ cb,
    float* __restrict__ emb, unsigned short* __restrict__ ebf,
    unsigned char* __restrict__ sflag)
{
  __shared__ double cs[KD][KD];
  __shared__ double chalf[KD];
  __shared__ unsigned short cbf[KD][KD];
  const int tid = threadIdx.x;
  if (tid < KD * KD) {
    const double c = (double)cb[tid];
    cs[tid / KD][tid % KD] = c;
    cbf[tid / KD][tid % KD] = f2bf((float)c);
  }
  __syncthreads();
  if (tid < KD) {
    double s = 0.0;
    #pragma unroll
    for (int k = 0; k < KD; ++k) s += cs[tid][k] * cs[tid][k];
    chalf[tid] = 0.5 * s;
  }
  __syncthreads();

  const int gi = blockIdx.x * 256 + tid;
  const int b = gi / NG;
  const int g = gi % NG;
  const float* zrow = z_e + (size_t)b * NH + g;
  double v[KD];
  #pragma unroll
  for (int k = 0; k < KD; ++k) v[k] = (double)zrow[k * NG];

  int best = 0; double bt = 1e300, bt2 = 1e300;
  #pragma unroll
  for (int j = 0; j < KD; ++j) {
    double t = chalf[j];
    #pragma unroll
    for (int k = 0; k < KD; ++k) t -= v[k] * cs[j][k];
    if (t < bt) { bt2 = bt; bt = t; best = j; }
    else if (t < bt2) { bt2 = t; }
  }
  float* ep = emb + (size_t)b * NH + g;
  unsigned short* eb = ebf + (size_t)b * NH + g;
  #pragma unroll
  for (int k = 0; k < KD; ++k) {
    ep[k * NG] = (float)cs[best][k];
    eb[k * NG] = cbf[best][k];
  }
  if (bt2 - bt < TAU) sflag[b] = 1;
}

__global__ __launch_bounds__(256) void compact_kernel(
    const unsigned char* __restrict__ sflag, int* __restrict__ scount,
    int* __restrict__ slist)
{
  const int i = blockIdx.x * 256 + threadIdx.x;
  if (i < NB && sflag[i]) slist[atomicAdd(scount, 1)] = i;
}

// ---------------------------------------------------------------------------
// Exact f64 repair, one sample per block (validated R6); rewrites emb+ebf.
// ---------------------------------------------------------------------------
__global__ __launch_bounds__(256) void repair_kernel(
    const float* __restrict__ x, const float* __restrict__ W1,
    const float* __restrict__ b1, const float* __restrict__ W2,
    const float* __restrict__ b2, const float* __restrict__ cb,
    const int* __restrict__ slist, const int* __restrict__ scount,
    float* __restrict__ emb, unsigned short* __restrict__ ebf)
{
  __shared__ double h1s[NH1];
  __shared__ double zs[NH];
  __shared__ double cs[KD][KD];
  __shared__ double chalf[KD];
  const int tid = threadIdx.x;
  const int lane = tid & 63, wv = tid >> 6;
  if (tid < KD * KD) cs[tid / KD][tid % KD] = (double)cb[tid];
  __syncthreads();
  if (tid < KD) {
    double s = 0.0;
    #pragma unroll
    for (int k = 0; k < KD; ++k) s += cs[tid][k] * cs[tid][k];
    chalf[tid] = 0.5 * s;
  }

  int S = *scount; if (S > NB) S = NB;

  for (int si = blockIdx.x; si < S; si += gridDim.x) {
    const int b = slist[si];
    double xr[4][4];
    #pragma unroll
    for (int it = 0; it < 4; ++it) {
      const int c4 = it * 64 + lane;
      if (c4 < 196) {
        float4 v = reinterpret_cast<const float4*>(x + (size_t)b * NIN)[c4];
        xr[it][0] = v.x; xr[it][1] = v.y; xr[it][2] = v.z; xr[it][3] = v.w;
      } else {
        xr[it][0] = xr[it][1] = xr[it][2] = xr[it][3] = 0.0;
      }
    }
    for (int j = wv; j < NH1; j += 4) {
      const float4* wr = reinterpret_cast<const float4*>(W1 + (size_t)j * NIN);
      double s0 = 0, s1 = 0, s2 = 0, s3 = 0;
      #pragma unroll
      for (int it = 0; it < 4; ++it) {
        const int c4 = it * 64 + lane;
        if (c4 < 196) {
          float4 w = wr[c4];
          s0 = fma(xr[it][0], (double)w.x, s0);
          s1 = fma(xr[it][1], (double)w.y, s1);
          s2 = fma(xr[it][2], (double)w.z, s2);
          s3 = fma(xr[it][3], (double)w.w, s3);
        }
      }
      double s = (s0 + s1) + (s2 + s3);
      #pragma unroll
      for (int off = 32; off > 0; off >>= 1) s += __shfl_down(s, off);
      if (lane == 0) { double h = s + (double)b1[j]; h1s[j] = h > 0.0 ? h : 0.0; }
    }
    __syncthreads();
    double hr[2][4];
    #pragma unroll
    for (int it = 0; it < 2; ++it) {
      const int c4 = it * 64 + lane;
      if (c4 < 100) {
        hr[it][0] = h1s[4 * c4 + 0]; hr[it][1] = h1s[4 * c4 + 1];
        hr[it][2] = h1s[4 * c4 + 2]; hr[it][3] = h1s[4 * c4 + 3];
      } else {
        hr[it][0] = hr[it][1] = hr[it][2] = hr[it][3] = 0.0;
      }
    }
    for (int n = wv; n < NH; n += 4) {
      const float4* wr = reinterpret_cast<const float4*>(W2 + (size_t)n * NH1);
      double s0 = 0, s1 = 0, s2 = 0, s3 = 0;
      #pragma unroll
      for (int it = 0; it < 2; ++it) {
        const int c4 = it * 64 + lane;
        if (c4 < 100) {
          float4 w = wr[c4];
          s0 = fma(hr[it][0], (double)w.x, s0);
          s1 = fma(hr[it][1], (double)w.y, s1);
          s2 = fma(hr[it][2], (double)w.z, s2);
          s3 = fma(hr[it][3], (double)w.w, s3);
        }
      }
      double s = (s0 + s1) + (s2 + s3);
      #pragma unroll
      for (int off = 32; off > 0; off >>= 1) s += __shfl_down(s, off);
      if (lane == 0) zs[n] = s + (double)b2[n];
    }
    __syncthreads();
    if (tid < NG) {
      const int g = tid;
      int best = 0; double bt = 1e300;
      #pragma unroll
      for (int j = 0; j < KD; ++j) {
        double t = chalf[j];
        #pragma unroll
        for (int k = 0; k < KD; ++k) t -= zs[k * NG + g] * cs[j][k];
        if (t < bt) { bt = t; best = j; }
      }
      #pragma unroll
      for (int k = 0; k < KD; ++k) {
        const float cv = (float)cs[best][k];
        emb[(size_t)b * NH + k * NG + g] = cv;
        ebf[(size_t)b * NH + k * NG + g] = f2bf(cv);
      }
    }
    __syncthreads();
  }
}

extern "C" void kernel_launch(void* const* d_in, const int* in_sizes, int n_in,
                              void* d_out, int out_size, void* d_ws, size_t ws_size,
                              hipStream_t stream) {
  const float* x  = (const float*)d_in[0];
  const float* W1 = (const float*)d_in[1];
  const float* b1 = (const float*)d_in[2];
  const float* W2 = (const float*)d_in[3];
  const float* b2 = (const float*)d_in[4];
  const float* W3 = (const float*)d_in[5];
  const float* b3 = (const float*)d_in[6];
  const float* W4 = (const float*)d_in[7];
  const float* b4 = (const float*)d_in[8];
  const float* cb = (const float*)d_in[9];

  float* out   = (float*)d_out;
  float* recon = out;                              // NB x 784 (written last)
  float* z_e   = out + (size_t)NB * NIN;           // NB x 200
  float* emb   = z_e + (size_t)NB * NH;            // NB x 200

  unsigned short* h1_lo  = (unsigned short*)emb;   // dead before quant writes emb
  unsigned short* emb_bf = (unsigned short*)recon; // 26.2 MB in dead recon region

  char* ws = (char*)d_ws;
  int*            scount = (int*)ws;                            // 4 B
  unsigned short* zp    = (unsigned short*)(ws + 256);          // 256 B zeros
  unsigned char*  sflag = (unsigned char*)(ws + 4096);          // 64 KB
  __hip_bfloat16* W3p   = (__hip_bfloat16*)(ws + (1u << 20));   // 512x224
  int*            slist = (int*)(ws + (4u << 20));              // 256 KB
  __hip_bfloat16* W4p   = (__hip_bfloat16*)(ws + (6u << 20));   // 896x416
  unsigned short* W1ph  = (unsigned short*)(ws + (7u << 20));   // 512x800
  unsigned short* W1pl  = (unsigned short*)(ws + (8u << 20));
  unsigned short* W2ph  = (unsigned short*)(ws + (9u << 20));   // 256x416
  unsigned short* W2pl  = (unsigned short*)(ws + (10u << 20));
  unsigned short* h1_hi = (unsigned short*)(ws + (16u << 20));  // NB x 400 bf16
  __hip_bfloat16* h3    = (__hip_bfloat16*)(ws + (16u << 20));  // reuses h1_hi (dead)

  dim3 blk(256);
  hipMemsetAsync(ws, 0, 4096 + NB, stream);   // scount + zp + sflag
  conv_w<<<(512 * 800 + 255) / 256, blk, 0, stream>>>(W1, W1ph, W1pl, 512, 800, NH1, NIN);
  conv_w<<<(256 * 416 + 255) / 256, blk, 0, stream>>>(W2, W2ph, W2pl, 256, 416, NH, NH1);
  pad_w4<<<(896 * 416 + 255) / 256, blk, 0, stream>>>(W4, W4p);
  pad_w3<<<(512 * 224 + 255) / 256, blk, 0, stream>>>(W3, W3p);

  // stage 1: h1 = relu(x @ W1^T + b1) -> split bf16 (fused conversion, pipelined)
  gemm1_fused<<<2048, blk, 0, stream>>>(x, W1ph, W1pl, b1, h1_hi, h1_lo);
  // stage 2: z_e = h1 @ W2^T + b2
  gemm2_split<<<1024, blk, 0, stream>>>(h1_hi, h1_lo, W2ph, W2pl, zp, b2, z_e);

  // stage 3: quantize (+bf16 emb), repair borderline samples exactly
  quant_kernel<<<(NB * NG) / 256, blk, 0, stream>>>(z_e, cb, emb, emb_bf, sflag);
  compact_kernel<<<NB / 256, blk, 0, stream>>>(sflag, scount, slist);
  repair_kernel<<<2048, blk, 0, stream>>>(x, W1, b1, W2, b2, cb, slist, scount, emb, emb_bf);

  // stage 4: h3 = relu(emb_bf @ W3p^T + b3) -> bf16 (MFMA)
  gemm3_mfma<<<2048, blk, 0, stream>>>(emb_bf, W3p, b3, h3);
  // stage 5: recon = tanh(h3 @ W4p^T + b4)
  gemm5_mfma<<<3584, blk, 0, stream>>>(h3, W4p, b4, recon);
}

// Round 10
// 595.934 us; speedup vs baseline: 5.1106x; 1.0085x over previous
//
#include <hip/hip_runtime.h>
#include <hip/hip_bf16.h>

#define NB   65536
#define KD   10
#define NG   20
#define NH   200     // KD*NG
#define NH1  400
#define NIN  784

#define TAU 3e-4     // margin below which the sample is recomputed exactly in f64

using short8 = __attribute__((ext_vector_type(8))) short;
using f32x4  = __attribute__((ext_vector_type(4))) float;

__device__ inline float bf2f(unsigned short u) {
  union { unsigned int i; float f; } x; x.i = ((unsigned int)u) << 16; return x.f;
}
__device__ inline unsigned short f2bf(float v) {
  __hip_bfloat16 b = __float2bfloat16(v);
  return *reinterpret_cast<unsigned short*>(&b);
}
// Truncation split: hi = top-16-bits of v (exact AND), lo = RNE(v - hi).
__device__ inline void split2(float v, unsigned short& h, unsigned short& l) {
  union { float f; unsigned int i; } u; u.f = v;
  const unsigned int hbits = u.i & 0xffff0000u;
  h = (unsigned short)(hbits >> 16);
  union { unsigned int i; float f; } w; w.i = hbits;
  l = f2bf(v - w.f);
}
__device__ inline void gload_lds16(const void* g, void* l) {
  __builtin_amdgcn_global_load_lds(
      (const __attribute__((address_space(1))) unsigned int*)g,
      (__attribute__((address_space(3))) unsigned int*)l, 16, 0, 0);
}

// LDS chunk-XOR swizzle (16B granularity within each 64B row of a [128][32] short tile):
//   element (row, kchunk c) stored at chunk position c ^ ((row>>1)&3).
// Staging source permutation (gload_lds linear dest): kswz(lane)
// Fragment read chunk: csw(lane)
#define KSWZ(lane) ((((lane) & 3) ^ (((lane) >> 3) & 3)) * 8)
#define CSW(lane)  (((((lane) >> 4) ^ (((lane) >> 1) & 3))) * 8)

// ---------------------------------------------------------------------------
// Stage 1 fused + pipelined: h1 = relu(x @ W1^T + b1) -> split bf16.
// ---------------------------------------------------------------------------
__global__ __launch_bounds__(256) void gemm1_fused(
    const float* __restrict__ xf,
    const unsigned short* __restrict__ Bhi, const unsigned short* __restrict__ Blo,
    const float* __restrict__ bias,
    unsigned short* __restrict__ Ohi, unsigned short* __restrict__ Olo)
{
  __shared__ __align__(16) short As_hi[2][128][32];
  __shared__ __align__(16) short As_lo[2][128][32];
  __shared__ __align__(16) short Bs_hi[2][128][32];
  __shared__ __align__(16) short Bs_lo[2][128][32];
  const int tid = threadIdx.x;
  const int lane = tid & 63, wid = tid >> 6;
  const int wr = wid >> 1, wc = wid & 1;
  const int bid = blockIdx.x;
  const int sw = (bid & 7) * 256 + (bid >> 3);     // XCD-bijective swizzle
  const int n0 = (sw & 3) * 128;
  const int m0 = (sw >> 2) * 128;
  const int rr = lane >> 2;
  const int kswz = KSWZ(lane);
  const int csw = CSW(lane);
  const int arow = tid >> 3;          // 0..31
  const int wbyte = ((tid & 7) * 8) ^ (((tid >> 4) & 3) << 4);  // swizzled A dest byte
  const int acol = (tid & 7) * 4;     // linear k offset for loads

  f32x4 acc[4][4];
  #pragma unroll
  for (int i = 0; i < 4; ++i)
    #pragma unroll
    for (int j = 0; j < 4; ++j) acc[i][j] = (f32x4){0.f, 0.f, 0.f, 0.f};

  float4 va[4];

  auto loadA = [&](int ks) {
    const int k0 = ks * 32;
    #pragma unroll
    for (int p = 0; p < 4; ++p) {
      const int row = p * 32 + arow;
      const int kk = k0 + acol;
      va[p] = make_float4(0.f, 0.f, 0.f, 0.f);
      if (kk < NIN)
        va[p] = *reinterpret_cast<const float4*>(xf + (size_t)(m0 + row) * NIN + kk);
    }
  };
  auto stageB = [&](int ks, int buf) {
    const int k0 = ks * 32;
    #pragma unroll
    for (int c = 0; c < 4; ++c) {
      const int ch = wid * 4 + c;
      if (ch < 8)
        gload_lds16(Bhi + (size_t)(n0 + ch * 16 + rr) * 800 + k0 + kswz,
                    (char*)&Bs_hi[buf][0][0] + ch * 1024);
      else
        gload_lds16(Blo + (size_t)(n0 + (ch - 8) * 16 + rr) * 800 + k0 + kswz,
                    (char*)&Bs_lo[buf][0][0] + (ch - 8) * 1024);
    }
  };
  auto writeA = [&](int buf) {
    char* bh = (char*)&As_hi[buf][0][0];
    char* bl = (char*)&As_lo[buf][0][0];
    #pragma unroll
    for (int p = 0; p < 4; ++p) {
      const int row = p * 32 + arow;
      const float4 v = va[p];
      short4 h, l;
      split2(v.x, (unsigned short&)h.x, (unsigned short&)l.x);
      split2(v.y, (unsigned short&)h.y, (unsigned short&)l.y);
      split2(v.z, (unsigned short&)h.z, (unsigned short&)l.z);
      split2(v.w, (unsigned short&)h.w, (unsigned short&)l.w);
      *reinterpret_cast<short4*>(bh + row * 64 + wbyte) = h;
      *reinterpret_cast<short4*>(bl + row * 64 + wbyte) = l;
    }
  };

  loadA(0);
  stageB(0, 0);
  writeA(0);
  __syncthreads();

  for (int ks = 0; ks < 25; ++ks) {
    const int cur = ks & 1, nxt = cur ^ 1;
    const bool more = (ks + 1 < 25);
    if (more) {
      loadA(ks + 1);
      stageB(ks + 1, nxt);
    }
    short8 ah[4], al[4], bh[4], bl[4];
    #pragma unroll
    for (int i = 0; i < 4; ++i) {
      ah[i] = *reinterpret_cast<const short8*>(&As_hi[cur][wr * 64 + i * 16 + (lane & 15)][csw]);
      al[i] = *reinterpret_cast<const short8*>(&As_lo[cur][wr * 64 + i * 16 + (lane & 15)][csw]);
      bh[i] = *reinterpret_cast<const short8*>(&Bs_hi[cur][wc * 64 + i * 16 + (lane & 15)][csw]);
      bl[i] = *reinterpret_cast<const short8*>(&Bs_lo[cur][wc * 64 + i * 16 + (lane & 15)][csw]);
    }
    #pragma unroll
    for (int i = 0; i < 4; ++i)
      #pragma unroll
      for (int j = 0; j < 4; ++j) {
        acc[i][j] = __builtin_amdgcn_mfma_f32_16x16x32_bf16(ah[i], bh[j], acc[i][j], 0, 0, 0);
        acc[i][j] = __builtin_amdgcn_mfma_f32_16x16x32_bf16(al[i], bh[j], acc[i][j], 0, 0, 0);
        acc[i][j] = __builtin_amdgcn_mfma_f32_16x16x32_bf16(ah[i], bl[j], acc[i][j], 0, 0, 0);
      }
    if (more) writeA(nxt);
    __syncthreads();
  }

  #pragma unroll
  for (int j = 0; j < 4; ++j) {
    const int n = n0 + wc * 64 + j * 16 + (lane & 15);
    if (n >= NH1) continue;
    const float bn = bias[j * 0 + n];
    #pragma unroll
    for (int i = 0; i < 4; ++i) {
      const int mb = m0 + wr * 64 + i * 16 + (lane >> 4) * 4;
      #pragma unroll
      for (int r = 0; r < 4; ++r) {
        float v = fmaxf(acc[i][j][r] + bn, 0.f);
        unsigned short h, l;
        split2(v, h, l);
        Ohi[(size_t)(mb + r) * NH1 + n] = h;
        Olo[(size_t)(mb + r) * NH1 + n] = l;
      }
    }
  }
}

// ---------------------------------------------------------------------------
// Stage 2: z_e = h1 @ W2^T + b2 (split bf16).
// ---------------------------------------------------------------------------
__global__ __launch_bounds__(256) void gemm2_split(
    const unsigned short* __restrict__ Ahi, const unsigned short* __restrict__ Alo,
    const unsigned short* __restrict__ Bhi, const unsigned short* __restrict__ Blo,
    const unsigned short* __restrict__ zp, const float* __restrict__ bias,
    float* __restrict__ Of)
{
  __shared__ __align__(16) short As_hi[128][32];
  __shared__ __align__(16) short As_lo[128][32];
  __shared__ __align__(16) short Bs_hi[128][32];
  __shared__ __align__(16) short Bs_lo[128][32];
  const int tid = threadIdx.x;
  const int lane = tid & 63, wid = tid >> 6;
  const int wr = wid >> 1, wc = wid & 1;
  const int bid = blockIdx.x;
  const int sw = (bid & 7) * 128 + (bid >> 3);
  const int n0 = (sw & 1) * 128;
  const int m0 = (sw >> 1) * 128;

  const unsigned short* G = (wid == 0) ? Ahi : (wid == 1) ? Alo
                          : (wid == 2) ? Bhi : Blo;
  short* Lt = (wid == 0) ? &As_hi[0][0] : (wid == 1) ? &As_lo[0][0]
            : (wid == 2) ? &Bs_hi[0][0] : &Bs_lo[0][0];
  const bool isA = wid < 2;
  const int rbase = isA ? m0 : n0;
  const int ld = isA ? 400 : 416;
  const int rr = lane >> 2;
  const int kswz = KSWZ(lane);
  const int csw = CSW(lane);

  f32x4 acc[4][4];
  #pragma unroll
  for (int i = 0; i < 4; ++i)
    #pragma unroll
    for (int j = 0; j < 4; ++j) acc[i][j] = (f32x4){0.f, 0.f, 0.f, 0.f};

  for (int ks = 0; ks < 13; ++ks) {
    const int k0 = ks * 32;
    #pragma unroll
    for (int c = 0; c < 8; ++c) {
      const unsigned short* src =
          G + (size_t)(rbase + c * 16 + rr) * ld + k0 + kswz;
      if (isA && (k0 + kswz >= 400)) src = zp;
      gload_lds16(src, (char*)Lt + c * 1024);
    }
    __syncthreads();
    short8 ah[4], al[4], bh[4], bl[4];
    #pragma unroll
    for (int i = 0; i < 4; ++i) {
      ah[i] = *reinterpret_cast<const short8*>(&As_hi[wr * 64 + i * 16 + (lane & 15)][csw]);
      al[i] = *reinterpret_cast<const short8*>(&As_lo[wr * 64 + i * 16 + (lane & 15)][csw]);
      bh[i] = *reinterpret_cast<const short8*>(&Bs_hi[wc * 64 + i * 16 + (lane & 15)][csw]);
      bl[i] = *reinterpret_cast<const short8*>(&Bs_lo[wc * 64 + i * 16 + (lane & 15)][csw]);
    }
    #pragma unroll
    for (int i = 0; i < 4; ++i)
      #pragma unroll
      for (int j = 0; j < 4; ++j) {
        acc[i][j] = __builtin_amdgcn_mfma_f32_16x16x32_bf16(ah[i], bh[j], acc[i][j], 0, 0, 0);
        acc[i][j] = __builtin_amdgcn_mfma_f32_16x16x32_bf16(al[i], bh[j], acc[i][j], 0, 0, 0);
        acc[i][j] = __builtin_amdgcn_mfma_f32_16x16x32_bf16(ah[i], bl[j], acc[i][j], 0, 0, 0);
      }
    __syncthreads();
  }

  #pragma unroll
  for (int j = 0; j < 4; ++j) {
    const int n = n0 + wc * 64 + j * 16 + (lane & 15);
    if (n >= NH) continue;
    const float bn = bias[n];
    #pragma unroll
    for (int i = 0; i < 4; ++i) {
      const int mb = m0 + wr * 64 + i * 16 + (lane >> 4) * 4;
      #pragma unroll
      for (int r = 0; r < 4; ++r)
        Of[(size_t)(mb + r) * NH + n] = acc[i][j][r] + bn;
    }
  }
}

// ---------------------------------------------------------------------------
// Stage 3: h3 = relu(emb_bf @ W3p^T + b3) -> bf16.
// ---------------------------------------------------------------------------
__global__ __launch_bounds__(256) void gemm3_mfma(
    const unsigned short* __restrict__ A,   // emb_bf: NB x 200
    const __hip_bfloat16* __restrict__ Bp,  // W3p: 512 x 224
    const float* __restrict__ bias, __hip_bfloat16* __restrict__ H3)
{
  __shared__ __align__(16) short As[128][32];
  __shared__ __align__(16) short Bs[128][32];
  const int tid = threadIdx.x;
  const int lane = tid & 63, wid = tid >> 6;
  const int wr = wid >> 1, wc = wid & 1;
  const int bid = blockIdx.x;
  const int sw = (bid & 7) * 256 + (bid >> 3);
  const int n0 = (sw & 3) * 128;
  const int m0 = (sw >> 2) * 128;
  const int kswz = KSWZ(lane);
  const int csw = CSW(lane);
  const short* Ag = (const short*)A;
  const short* Bg = (const short*)Bp;
  f32x4 acc[4][4];
  #pragma unroll
  for (int i = 0; i < 4; ++i)
    #pragma unroll
    for (int j = 0; j < 4; ++j) acc[i][j] = (f32x4){0.f, 0.f, 0.f, 0.f};

  for (int k0 = 0; k0 < 224; k0 += 32) {
    #pragma unroll
    for (int c = 0; c < 2; ++c) {
      const int row = c * 64 + wid * 16 + (lane >> 2);
      gload_lds16(Ag + (size_t)(m0 + row) * 200 + k0 + kswz,
                  (char*)&As[0][0] + c * 4096 + wid * 1024);
      gload_lds16(Bg + (size_t)(n0 + row) * 224 + k0 + kswz,
                  (char*)&Bs[0][0] + c * 4096 + wid * 1024);
    }
    __syncthreads();
    short8 af[4], bf[4];
    #pragma unroll
    for (int i = 0; i < 4; ++i)
      af[i] = *reinterpret_cast<const short8*>(&As[wr * 64 + i * 16 + (lane & 15)][csw]);
    #pragma unroll
    for (int j = 0; j < 4; ++j)
      bf[j] = *reinterpret_cast<const short8*>(&Bs[wc * 64 + j * 16 + (lane & 15)][csw]);
    #pragma unroll
    for (int i = 0; i < 4; ++i)
      #pragma unroll
      for (int j = 0; j < 4; ++j)
        acc[i][j] = __builtin_amdgcn_mfma_f32_16x16x32_bf16(af[i], bf[j], acc[i][j], 0, 0, 0);
    __syncthreads();
  }

  #pragma unroll
  for (int j = 0; j < 4; ++j) {
    const int n = n0 + wc * 64 + j * 16 + (lane & 15);
    if (n >= NH1) continue;
    const float bn = bias[n];
    #pragma unroll
    for (int i = 0; i < 4; ++i) {
      const int mb = m0 + wr * 64 + i * 16 + (lane >> 4) * 4;
      #pragma unroll
      for (int r = 0; r < 4; ++r)
        H3[(size_t)(mb + r) * NH1 + n] = __float2bfloat16(fmaxf(acc[i][j][r] + bn, 0.f));
    }
  }
}

// ---------------------------------------------------------------------------
// Stage 5: recon = tanh(h3 @ W4p^T + b4). Fast tanh via exp.
// ---------------------------------------------------------------------------
__global__ __launch_bounds__(256) void gemm5_mfma(
    const __hip_bfloat16* __restrict__ A,   // h3: NB x 400
    const __hip_bfloat16* __restrict__ Bp,  // W4p: 896 x 416
    const float* __restrict__ bias, float* __restrict__ C)
{
  __shared__ __align__(16) short As[128][32];
  __shared__ __align__(16) short Bs[128][32];
  const int tid = threadIdx.x;
  const int lane = tid & 63, wid = tid >> 6;
  const int wr = wid >> 1, wc = wid & 1;
  const int bid = blockIdx.x;
  const int sw = (bid & 7) * 448 + (bid >> 3);
  const int n0 = (sw % 7) * 128;
  const int m0 = (sw / 7) * 128;
  const int kswz = KSWZ(lane);
  const int csw = CSW(lane);
  const short* Ag = (const short*)A;
  const short* Bg = (const short*)Bp;
  f32x4 acc[4][4];
  #pragma unroll
  for (int i = 0; i < 4; ++i)
    #pragma unroll
    for (int j = 0; j < 4; ++j) acc[i][j] = (f32x4){0.f, 0.f, 0.f, 0.f};

  for (int k0 = 0; k0 < 416; k0 += 32) {
    #pragma unroll
    for (int c = 0; c < 2; ++c) {
      const int row = c * 64 + wid * 16 + (lane >> 2);
      gload_lds16(Ag + (size_t)(m0 + row) * 400 + k0 + kswz,
                  (char*)&As[0][0] + c * 4096 + wid * 1024);
      gload_lds16(Bg + (size_t)(n0 + row) * 416 + k0 + kswz,
                  (char*)&Bs[0][0] + c * 4096 + wid * 1024);
    }
    __syncthreads();
    short8 af[4], bf[4];
    #pragma unroll
    for (int i = 0; i < 4; ++i)
      af[i] = *reinterpret_cast<const short8*>(&As[wr * 64 + i * 16 + (lane & 15)][csw]);
    #pragma unroll
    for (int j = 0; j < 4; ++j)
      bf[j] = *reinterpret_cast<const short8*>(&Bs[wc * 64 + j * 16 + (lane & 15)][csw]);
    #pragma unroll
    for (int i = 0; i < 4; ++i)
      #pragma unroll
      for (int j = 0; j < 4; ++j)
        acc[i][j] = __builtin_amdgcn_mfma_f32_16x16x32_bf16(af[i], bf[j], acc[i][j], 0, 0, 0);
    __syncthreads();
  }

  #pragma unroll
  for (int j = 0; j < 4; ++j) {
    const int n = n0 + wc * 64 + j * 16 + (lane & 15);
    if (n >= NIN) continue;
    const float bn = bias[n];
    #pragma unroll
    for (int i = 0; i < 4; ++i) {
      const int mb = m0 + wr * 64 + i * 16 + (lane >> 4) * 4;
      #pragma unroll
      for (int r = 0; r < 4; ++r) {
        const float zv = acc[i][j][r] + bn;
        const float t = __expf(2.0f * zv);
        C[(size_t)(mb + r) * NIN + n] = 1.0f - __fdividef(2.0f, t + 1.0f);
      }
    }
  }
}

// ---------------------------------------------------------------------------
// Merged weight prep: W1/W2 split+pad, W4/W3 bf16+pad.
// ---------------------------------------------------------------------------
__global__ __launch_bounds__(256) void prep_all(
    const float* __restrict__ W1, const float* __restrict__ W2,
    const float* __restrict__ W3, const float* __restrict__ W4,
    unsigned short* __restrict__ W1ph, unsigned short* __restrict__ W1pl,
    unsigned short* __restrict__ W2ph, unsigned short* __restrict__ W2pl,
    __hip_bfloat16* __restrict__ W3p, __hip_bfloat16* __restrict__ W4p)
{
  const int i = blockIdx.x * 256 + threadIdx.x;
  if (i < 409600) {                       // W1p: 512 x 800
    const int n = i / 800, k = i % 800;
    const float v = (n < NH1 && k < NIN) ? W1[(size_t)n * NIN + k] : 0.f;
    unsigned short h, l; split2(v, h, l);
    W1ph[i] = h; W1pl[i] = l;
  } else if (i < 516096) {                // W2p: 256 x 416
    const int j = i - 409600;
    const int n = j / 416, k = j % 416;
    const float v = (n < NH && k < NH1) ? W2[(size_t)n * NH1 + k] : 0.f;
    unsigned short h, l; split2(v, h, l);
    W2ph[j] = h; W2pl[j] = l;
  } else if (i < 888832) {                // W4p: 896 x 416
    const int j = i - 516096;
    const int n = j / 416, k = j % 416;
    const float v = (n < NIN && k < NH1) ? W4[(size_t)n * NH1 + k] : 0.f;
    W4p[j] = __float2bfloat16(v);
  } else if (i < 1003520) {               // W3p: 512 x 224
    const int j = i - 888832;
    const int n = j / 224, k = j % 224;
    const float v = (n < NH1 && k < NH) ? W3[(size_t)n * NH + k] : 0.f;
    W3p[j] = __float2bfloat16(v);
  }
}

// ---------------------------------------------------------------------------
// Quantization: f64 distances from fast z_e; margin < TAU -> flag the SAMPLE.
// ---------------------------------------------------------------------------
__global__ __launch_bounds__(256) void quant_kernel(
    const float* __restrict__ z_e, const float* __restrict__ cb,
    float* __restrict__ emb, unsigned short* __restrict__ ebf,
    unsigned char* __restrict__ sflag)
{
  __shared__ double cs[KD][KD];
  __shared__ double chalf[KD];
  __shared__ unsigned short cbf[KD][KD];
  const int tid = threadIdx.x;
  if (tid < KD * KD) {
    const double c = (double)cb[tid];
    cs[tid / KD][tid % KD] = c;
    cbf[tid / KD][tid % KD] = f2bf((float)c);
  }
  __syncthreads();
  if (tid < KD) {
    double s = 0.0;
    #pragma unroll
    for (int k = 0; k < KD; ++k) s += cs[tid][k] * cs[tid][k];
    chalf[tid] = 0.5 * s;
  }
  __syncthreads();

  const int gi = blockIdx.x * 256 + tid;
  const int b = gi / NG;
  const int g = gi % NG;
  const float* zrow = z_e + (size_t)b * NH + g;
  double v[KD];
  #pragma unroll
  for (int k = 0; k < KD; ++k) v[k] = (double)zrow[k * NG];

  int best = 0; double bt = 1e300, bt2 = 1e300;
  #pragma unroll
  for (int j = 0; j < KD; ++j) {
    double t = chalf[j];
    #pragma unroll
    for (int k = 0; k < KD; ++k) t -= v[k] * cs[j][k];
    if (t < bt) { bt2 = bt; bt = t; best = j; }
    else if (t < bt2) { bt2 = t; }
  }
  float* ep = emb + (size_t)b * NH + g;
  unsigned short* eb = ebf + (size_t)b * NH + g;
  #pragma unroll
  for (int k = 0; k < KD; ++k) {
    ep[k * NG] = (float)cs[best][k];
    eb[k * NG] = cbf[best][k];
  }
  if (bt2 - bt < TAU) sflag[b] = 1;
}

__global__ __launch_bounds__(256) void compact_kernel(
    const unsigned char* __restrict__ sflag, int* __restrict__ scount,
    int* __restrict__ slist)
{
  const int i = blockIdx.x * 256 + threadIdx.x;
  if (i < NB && sflag[i]) slist[atomicAdd(scount, 1)] = i;
}

// ---------------------------------------------------------------------------
// Exact f64 repair, one sample per block; rewrites emb + ebf.
// ---------------------------------------------------------------------------
__global__ __launch_bounds__(256) void repair_kernel(
    const float* __restrict__ x, const float* __restrict__ W1,
    const float* __restrict__ b1, const float* __restrict__ W2,
    const float* __restrict__ b2, const float* __restrict__ cb,
    const int* __restrict__ slist, const int* __restrict__ scount,
    float* __restrict__ emb, unsigned short* __restrict__ ebf)
{
  __shared__ double h1s[NH1];
  __shared__ double zs[NH];
  __shared__ double cs[KD][KD];
  __shared__ double chalf[KD];
  const int tid = threadIdx.x;
  const int lane = tid & 63, wv = tid >> 6;
  if (tid < KD * KD) cs[tid / KD][tid % KD] = (double)cb[tid];
  __syncthreads();
  if (tid < KD) {
    double s = 0.0;
    #pragma unroll
    for (int k = 0; k < KD; ++k) s += cs[tid][k] * cs[tid][k];
    chalf[tid] = 0.5 * s;
  }

  int S = *scount; if (S > NB) S = NB;

  for (int si = blockIdx.x; si < S; si += gridDim.x) {
    const int b = slist[si];
    double xr[4][4];
    #pragma unroll
    for (int it = 0; it < 4; ++it) {
      const int c4 = it * 64 + lane;
      if (c4 < 196) {
        float4 v = reinterpret_cast<const float4*>(x + (size_t)b * NIN)[c4];
        xr[it][0] = v.x; xr[it][1] = v.y; xr[it][2] = v.z; xr[it][3] = v.w;
      } else {
        xr[it][0] = xr[it][1] = xr[it][2] = xr[it][3] = 0.0;
      }
    }
    for (int j = wv; j < NH1; j += 4) {
      const float4* wr = reinterpret_cast<const float4*>(W1 + (size_t)j * NIN);
      double s0 = 0, s1 = 0, s2 = 0, s3 = 0;
      #pragma unroll
      for (int it = 0; it < 4; ++it) {
        const int c4 = it * 64 + lane;
        if (c4 < 196) {
          float4 w = wr[c4];
          s0 = fma(xr[it][0], (double)w.x, s0);
          s1 = fma(xr[it][1], (double)w.y, s1);
          s2 = fma(xr[it][2], (double)w.z, s2);
          s3 = fma(xr[it][3], (double)w.w, s3);
        }
      }
      double s = (s0 + s1) + (s2 + s3);
      #pragma unroll
      for (int off = 32; off > 0; off >>= 1) s += __shfl_down(s, off);
      if (lane == 0) { double h = s + (double)b1[j]; h1s[j] = h > 0.0 ? h : 0.0; }
    }
    __syncthreads();
    double hr[2][4];
    #pragma unroll
    for (int it = 0; it < 2; ++it) {
      const int c4 = it * 64 + lane;
      if (c4 < 100) {
        hr[it][0] = h1s[4 * c4 + 0]; hr[it][1] = h1s[4 * c4 + 1];
        hr[it][2] = h1s[4 * c4 + 2]; hr[it][3] = h1s[4 * c4 + 3];
      } else {
        hr[it][0] = hr[it][1] = hr[it][2] = hr[it][3] = 0.0;
      }
    }
    for (int n = wv; n < NH; n += 4) {
      const float4* wr = reinterpret_cast<const float4*>(W2 + (size_t)n * NH1);
      double s0 = 0, s1 = 0, s2 = 0, s3 = 0;
      #pragma unroll
      for (int it = 0; it < 2; ++it) {
        const int c4 = it * 64 + lane;
        if (c4 < 100) {
          float4 w = wr[c4];
          s0 = fma(hr[it][0], (double)w.x, s0);
          s1 = fma(hr[it][1], (double)w.y, s1);
          s2 = fma(hr[it][2], (double)w.z, s2);
          s3 = fma(hr[it][3], (double)w.w, s3);
        }
      }
      double s = (s0 + s1) + (s2 + s3);
      #pragma unroll
      for (int off = 32; off > 0; off >>= 1) s += __shfl_down(s, off);
      if (lane == 0) zs[n] = s + (double)b2[n];
    }
    __syncthreads();
    if (tid < NG) {
      const int g = tid;
      int best = 0; double bt = 1e300;
      #pragma unroll
      for (int j = 0; j < KD; ++j) {
        double t = chalf[j];
        #pragma unroll
        for (int k = 0; k < KD; ++k) t -= zs[k * NG + g] * cs[j][k];
        if (t < bt) { bt = t; best = j; }
      }
      #pragma unroll
      for (int k = 0; k < KD; ++k) {
        const float cv = (float)cs[best][k];
        emb[(size_t)b * NH + k * NG + g] = cv;
        ebf[(size_t)b * NH + k * NG + g] = f2bf(cv);
      }
    }
    __syncthreads();
  }
}

extern "C" void kernel_launch(void* const* d_in, const int* in_sizes, int n_in,
                              void* d_out, int out_size, void* d_ws, size_t ws_size,
                              hipStream_t stream) {
  const float* x  = (const float*)d_in[0];
  const float* W1 = (const float*)d_in[1];
  const float* b1 = (const float*)d_in[2];
  const float* W2 = (const float*)d_in[3];
  const float* b2 = (const float*)d_in[4];
  const float* W3 = (const float*)d_in[5];
  const float* b3 = (const float*)d_in[6];
  const float* W4 = (const float*)d_in[7];
  const float* b4 = (const float*)d_in[8];
  const float* cb = (const float*)d_in[9];

  float* out   = (float*)d_out;
  float* recon = out;                              // NB x 784 (written last)
  float* z_e   = out + (size_t)NB * NIN;           // NB x 200
  float* emb   = z_e + (size_t)NB * NH;            // NB x 200

  unsigned short* h1_lo  = (unsigned short*)emb;   // dead before quant writes emb
  unsigned short* emb_bf = (unsigned short*)recon; // dead recon region

  char* ws = (char*)d_ws;
  int*            scount = (int*)ws;                            // 4 B
  unsigned short* zp    = (unsigned short*)(ws + 256);          // 256 B zeros
  unsigned char*  sflag = (unsigned char*)(ws + 4096);          // 64 KB
  __hip_bfloat16* W3p   = (__hip_bfloat16*)(ws + (1u << 20));   // 512x224
  int*            slist = (int*)(ws + (4u << 20));              // 256 KB
  __hip_bfloat16* W4p   = (__hip_bfloat16*)(ws + (6u << 20));   // 896x416
  unsigned short* W1ph  = (unsigned short*)(ws + (7u << 20));   // 512x800
  unsigned short* W1pl  = (unsigned short*)(ws + (9u << 20));
  unsigned short* W2ph  = (unsigned short*)(ws + (11u << 20));  // 256x416
  unsigned short* W2pl  = (unsigned short*)(ws + (12u << 20));
  unsigned short* h1_hi = (unsigned short*)(ws + (16u << 20));  // NB x 400 bf16
  __hip_bfloat16* h3    = (__hip_bfloat16*)(ws + (16u << 20));  // reuses h1_hi (dead)

  dim3 blk(256);
  hipMemsetAsync(ws, 0, 4096 + NB, stream);   // scount + zp + sflag
  prep_all<<<3920, blk, 0, stream>>>(W1, W2, W3, W4, W1ph, W1pl, W2ph, W2pl, W3p, W4p);

  // stage 1: h1 = relu(x @ W1^T + b1) -> split bf16
  gemm1_fused<<<2048, blk, 0, stream>>>(x, W1ph, W1pl, b1, h1_hi, h1_lo);
  // stage 2: z_e = h1 @ W2^T + b2
  gemm2_split<<<1024, blk, 0, stream>>>(h1_hi, h1_lo, W2ph, W2pl, zp, b2, z_e);

  // stage 3: quantize (+bf16 emb), repair borderline samples exactly
  quant_kernel<<<(NB * NG) / 256, blk, 0, stream>>>(z_e, cb, emb, emb_bf, sflag);
  compact_kernel<<<NB / 256, blk, 0, stream>>>(sflag, scount, slist);
  repair_kernel<<<2048, blk, 0, stream>>>(x, W1, b1, W2, b2, cb, slist, scount, emb, emb_bf);

  // stage 4: h3 = relu(emb_bf @ W3p^T + b3) -> bf16
  gemm3_mfma<<<2048, blk, 0, stream>>>(emb_bf, W3p, b3, h3);
  // stage 5: recon = tanh(h3 @ W4p^T + b4)
  gemm5_mfma<<<3584, blk, 0, stream>>>(h3, W4p, b4, recon);
}